// Round 16
// baseline (730.861 us; speedup 1.0000x reference)
//
#include <hip/hip_runtime.h>
#include <hip/hip_fp16.h>
#include <cmath>

#define DEVI static __device__ __forceinline__

constexpr int HIDn = 128, OUTn = 64;
constexpr int NCn = 50000, NDn = 50000, En = 400000;

typedef __attribute__((ext_vector_type(8))) short bf16x8;
typedef __attribute__((ext_vector_type(4))) float f32x4;

// monotonic float->uint mapping for atomicMax on floats (handles signs)
DEVI unsigned fmap(float f) {
  int i = __float_as_int(f);
  return (i < 0) ? ~((unsigned)i) : (((unsigned)i) | 0x80000000u);
}
DEVI float fdecode(unsigned u) {
  int i = (u & 0x80000000u) ? (int)(u & 0x7fffffffu) : (int)(~u);
  return __int_as_float(i);
}

DEVI float tanh_fast(float x) {           // 1 - 2/(e^{2x}+1); saturates correctly
  float e = __expf(2.f * x);
  return 1.f - __fdividef(2.f, e + 1.f);
}

DEVI unsigned short f2bf(float x) {       // fp32 -> bf16 RNE
  unsigned u = __float_as_uint(x);
  return (unsigned short)((u + 0x7FFFu + ((u >> 16) & 1u)) >> 16);
}
DEVI float bf2f(unsigned short h) {
  unsigned u = ((unsigned)h) << 16;
  return __uint_as_float(u);
}

// ---- vectorized 8-wide A-row load + fused transform (value-based) -------
// MODE: 0=plain, 1=elu(x), 2=elu(w2*a+w3*b).  base must be 16B-aligned.
template<int MODE>
DEVI void loadrow8(float* __restrict__ tmp,
                   const float* __restrict__ A, const float* __restrict__ A2,
                   float w2, float w3, size_t base)
{
  const float4* p = (const float4*)(A + base);
  float4 u0 = p[0], u1 = p[1];
  float v[8] = {u0.x, u0.y, u0.z, u0.w, u1.x, u1.y, u1.z, u1.w};
  if (MODE == 2) {
    const float4* q = (const float4*)(A2 + base);
    float4 t0 = q[0], t1 = q[1];
    float vb[8] = {t0.x, t0.y, t0.z, t0.w, t1.x, t1.y, t1.z, t1.w};
    #pragma unroll
    for (int i = 0; i < 8; ++i) v[i] = w2 * v[i] + w3 * vb[i];
  }
  if (MODE >= 1) {
    #pragma unroll
    for (int i = 0; i < 8; ++i) v[i] = (v[i] > 0.f) ? v[i] : (__expf(v[i]) - 1.f);
  }
  #pragma unroll
  for (int i = 0; i < 8; ++i) tmp[i] = v[i];
}

template<int MODE>
DEVI bf16x8 packrow8(const float* __restrict__ A, const float* __restrict__ A2,
                     float w2, float w3, size_t base)
{
  float t[8];
  loadrow8<MODE>(t, A, A2, w2, w3, base);
  bf16x8 r;
  #pragma unroll
  for (int i = 0; i < 8; ++i) r[i] = (short)f2bf(t[i]);
  return r;
}

// load + transform + split into hi/lo bf16 (a ~= hi + lo)
template<int MODE>
DEVI void splitrow8(const float* __restrict__ A, const float* __restrict__ A2,
                    float w2, float w3, size_t base, bf16x8& hi, bf16x8& lo)
{
  float t[8];
  loadrow8<MODE>(t, A, A2, w2, w3, base);
  #pragma unroll
  for (int i = 0; i < 8; ++i) {
    unsigned short h = f2bf(t[i]);
    hi[i] = (short)h;
    lo[i] = (short)f2bf(t[i] - bf2f(h));
  }
}

// ====== MFMA GEMM: C[N,128] = xform(A)[N,KI] @ W[KI,128] + b =============
// Verified fragment scheme: A lane(m+16b): A[row0+m][ks*32+b*8+j];
// B from Wt[col][k] contiguous; C/D col=lane&15, row=(lane>>4)*4+r.
// 3-term hi/lo split for ~fp32 accuracy. OUT16: store __half.
template<int KI, int MODE, int OUT16>
__global__ __launch_bounds__(256)
void gemm_mfma(const float* __restrict__ A, const float* __restrict__ A2,
               const float* __restrict__ wv,
               const unsigned short* __restrict__ Wh, const unsigned short* __restrict__ Wl,
               const float* __restrict__ bias, void* __restrict__ Cv, int N)
{
  constexpr int NK = KI / 32;
  float w2 = 0.f, w3 = 0.f;
  if (MODE == 2) { w2 = wv[2]; w3 = wv[3]; }
  const int tid = threadIdx.x;
  const int w = tid >> 6, lane = tid & 63;
  const int row0 = (blockIdx.x * 4 + w) * 16;
  const int m = lane & 15, b4 = lane >> 4;
  const int arow = row0 + m;
  const bool rok = arow < N;

  const bf16x8 zfr = {0, 0, 0, 0, 0, 0, 0, 0};
  bf16x8 ah[NK], al[NK];
  #pragma unroll
  for (int ks = 0; ks < NK; ++ks) {
    if (rok) {
      splitrow8<MODE>(A, A2, w2, w3, (size_t)arow * KI + ks * 32 + b4 * 8, ah[ks], al[ks]);
    } else {
      ah[ks] = zfr;
      al[ks] = zfr;
    }
  }

  #pragma unroll
  for (int t = 0; t < 8; ++t) {
    const int col = t * 16 + m;
    f32x4 acc = {0.f, 0.f, 0.f, 0.f};
    const unsigned short* ph = Wh + (size_t)col * KI + b4 * 8;
    const unsigned short* pl = Wl + (size_t)col * KI + b4 * 8;
    #pragma unroll
    for (int ks = 0; ks < NK; ++ks) {
      bf16x8 bh = *(const bf16x8*)(ph + ks * 32);
      bf16x8 bl = *(const bf16x8*)(pl + ks * 32);
      acc = __builtin_amdgcn_mfma_f32_16x16x32_bf16(ah[ks], bh, acc, 0, 0, 0);
      acc = __builtin_amdgcn_mfma_f32_16x16x32_bf16(al[ks], bh, acc, 0, 0, 0);
      acc = __builtin_amdgcn_mfma_f32_16x16x32_bf16(ah[ks], bl, acc, 0, 0, 0);
    }
    const float bc = bias[col];
    #pragma unroll
    for (int r = 0; r < 4; ++r) {
      const int row = row0 + b4 * 4 + r;
      if (row < N) {
        float v = acc[r] + bc;
        if (OUT16) ((__half*)Cv)[(size_t)row * 128 + col] = __float2half(v);
        else       ((float*)Cv)[(size_t)row * 128 + col] = v;
      }
    }
  }
}

// ---- all six per-(node,head) attention dots (reads h, fp16 or fp32) -----
DEVI float dot4f(float4 a, float4 b) { return a.x*b.x + a.y*b.y + a.z*b.z + a.w*b.w; }

template<int HALF>
DEVI void loadrow32h(const void* base, size_t off, float* v)
{
  if (HALF) {
    const __half* p = (const __half*)base + off;
    #pragma unroll
    for (int i = 0; i < 4; ++i) {
      float4 raw = *(const float4*)(p + i * 8);     // 8 halves
      const __half2* h2 = (const __half2*)&raw;
      #pragma unroll
      for (int j = 0; j < 4; ++j) {
        float2 f = __half22float2(h2[j]);
        v[i * 8 + j * 2]     = f.x;
        v[i * 8 + j * 2 + 1] = f.y;
      }
    }
  } else {
    const float* p = (const float*)base + off;
    #pragma unroll
    for (int i = 0; i < 8; ++i) {
      float4 u = *(const float4*)(p + i * 4);
      v[i * 4] = u.x; v[i * 4 + 1] = u.y; v[i * 4 + 2] = u.z; v[i * 4 + 3] = u.w;
    }
  }
}

template<int HALF>
__global__ void dot6(const void* __restrict__ hc, const void* __restrict__ hd,
                     const float* __restrict__ ascc, const float* __restrict__ adcc,
                     const float* __restrict__ asdc, const float* __restrict__ addc,
                     const float* __restrict__ ascd, const float* __restrict__ adcd,
                     float* __restrict__ scc, float* __restrict__ dcc,
                     float* __restrict__ ddc, float* __restrict__ scd,
                     float* __restrict__ sdc, float* __restrict__ dcd, int N)
{
  int idx = blockIdx.x * blockDim.x + threadIdx.x;
  if (idx >= N * 4) return;
  int n = idx >> 2, hh = idx & 3;
  float hv[32], dv[32];
  loadrow32h<HALF>(hc, (size_t)n * HIDn + hh * 32, hv);
  loadrow32h<HALF>(hd, (size_t)n * HIDn + hh * 32, dv);
  const float4* a1 = (const float4*)(ascc + hh * 32);
  const float4* a2 = (const float4*)(adcc + hh * 32);
  const float4* a3 = (const float4*)(addc + hh * 32);
  const float4* a4 = (const float4*)(ascd + hh * 32);
  const float4* a5 = (const float4*)(asdc + hh * 32);
  const float4* a6 = (const float4*)(adcd + hh * 32);
  float s1 = 0, s2 = 0, s3 = 0, s4 = 0, t1 = 0, t2 = 0;
  #pragma unroll
  for (int i = 0; i < 8; ++i) {
    float4 hq = make_float4(hv[i*4], hv[i*4+1], hv[i*4+2], hv[i*4+3]);
    s1 += dot4f(hq, a1[i]);
    s2 += dot4f(hq, a2[i]);
    s3 += dot4f(hq, a3[i]);
    s4 += dot4f(hq, a4[i]);
    float4 dq = make_float4(dv[i*4], dv[i*4+1], dv[i*4+2], dv[i*4+3]);
    t1 += dot4f(dq, a5[i]);
    t2 += dot4f(dq, a6[i]);
  }
  scc[idx] = s1; dcc[idx] = s2; ddc[idx] = s3;
  scd[idx] = s4; sdc[idx] = t1; dcd[idx] = t2;
}

// ================= CSR build, all 3 graphs batched =======================
__global__ void hist3(const int* __restrict__ ei0, const int* __restrict__ ei1,
                      const int* __restrict__ ei2, int* __restrict__ tmpBase)
{
  int gid = blockIdx.x * blockDim.x + threadIdx.x;
  if (gid >= 3 * En) return;
  int g = gid / En, e = gid - g * En;
  const int* ei = (g == 0) ? ei0 : (g == 1) ? ei1 : ei2;
  atomicAdd(&tmpBase[g * 50000 + ei[En + e]], 1);
}

__global__ void scan3(const int* __restrict__ tmpBase, int* __restrict__ offsBase)
{
  const int n = 50000;
  const int* deg = tmpBase + blockIdx.x * 50000;
  int* offs = offsBase + blockIdx.x * 50004;
  __shared__ int wsum[16];
  __shared__ int carry_sh;
  int tid = threadIdx.x;
  if (tid == 0) { carry_sh = 0; offs[0] = 0; }
  __syncthreads();
  const int nw = blockDim.x >> 6;
  int lane = tid & 63, w = tid >> 6;
  for (int base = 0; base < n; base += blockDim.x) {
    int i = base + tid;
    int v = (i < n) ? deg[i] : 0;
    int x = v;
    #pragma unroll
    for (int off = 1; off < 64; off <<= 1) {
      int y = __shfl_up(x, off);
      if (lane >= off) x += y;
    }
    if (lane == 63) wsum[w] = x;
    __syncthreads();
    if (tid == 0) {
      int s = carry_sh;
      for (int ww = 0; ww < nw; ++ww) { int t = wsum[ww]; wsum[ww] = s; s += t; }
      carry_sh = s;
    }
    __syncthreads();
    if (i < n) offs[i + 1] = wsum[w] + x;
    __syncthreads();
  }
}

__global__ void fill3(const int* __restrict__ ei0, const int* __restrict__ ei1,
                      const int* __restrict__ ei2, const int* __restrict__ offsBase,
                      int* __restrict__ cursorBase, int* __restrict__ elistBase)
{
  int gid = blockIdx.x * blockDim.x + threadIdx.x;
  if (gid >= 3 * En) return;
  int g = gid / En, e = gid - g * En;
  const int* ei = (g == 0) ? ei0 : (g == 1) ? ei1 : ei2;
  const int* offs = offsBase + g * 50004;
  int* cursor = cursorBase + g * 50000;
  int* elist = elistBase + (size_t)g * En;
  int s = ei[e], d = ei[En + e];
  int p = atomicAdd(&cursor[d], 1);
  elist[offs[d] + p] = s;
}

// ---- W transpose+cast single-plane: W[128][KO] fp32 -> Wt[KO][128] bf16 -
__global__ void wtrans(const float* __restrict__ W, unsigned short* __restrict__ Wt, int KO)
{
  int idx = blockIdx.x * 256 + threadIdx.x;
  if (idx >= 128 * KO) return;
  int k = idx / KO, c = idx - k * KO;
  Wt[(size_t)c * 128 + k] = f2bf(W[idx]);
}

// ---- W transpose+split: W[KI][128] fp32 -> Wh/Wl[128][KI] bf16 ----------
__global__ void wtrans_split(const float* __restrict__ W,
                             unsigned short* __restrict__ Wh,
                             unsigned short* __restrict__ Wl, int KI)
{
  int idx = blockIdx.x * 256 + threadIdx.x;
  if (idx >= KI * 128) return;
  int k = idx >> 7, c = idx & 127;
  float v = W[idx];
  unsigned short h = f2bf(v);
  Wh[(size_t)c * KI + k] = h;
  Wl[(size_t)c * KI + k] = f2bf(v - bf2f(h));
}

// ==== FUSED edge attention (CSR, fp16 h, lane-specialized softmax) =======
struct EdgeOp {
  const int* offs; const int* elist;
  const float* sdot; const float* ddot;
  const __half* hsrc; float* out;
};

DEVI void csr_att_body(const EdgeOp& op, int dst, int lane)
{
  const int i0 = op.offs[dst], i1 = op.offs[dst + 1];
  const int hB = lane >> 4;
  const float ddv = op.ddot[dst * 4 + hB];
  const __half* hsrc = op.hsrc;
  const float* sdot = op.sdot;
  const int* el = op.elist;
  const int wsel = lane & 48;
  float den = 0.f, a0 = 0.f, a1 = 0.f;

  for (int base = i0; base < i1; base += 16) {
    int i = base + (lane & 15);
    int s_ = 0;
    float w = 0.f;
    if (i < i1) {
      s_ = el[i];
      float lv = sdot[s_ * 4 + hB] + ddv;
      lv = fminf(fmaxf(lv, 0.2f * lv), 80.f);
      w = __expf(lv);
    }
    float g = w;
    g += __shfl_xor(g, 1);
    g += __shfl_xor(g, 2);
    g += __shfl_xor(g, 4);
    g += __shfl_xor(g, 8);
    den += g;

    const int rem = min(16, i1 - base);
    int j = 0;
    for (; j + 2 <= rem; j += 2) {
      int sA = __shfl(s_, j);
      int sB = __shfl(s_, j + 1);
      float wA = __shfl(w, wsel | j);
      float wB = __shfl(w, wsel | (j + 1));
      float2 hA = __half22float2(*(const __half2*)(hsrc + (size_t)sA * HIDn + lane * 2));
      float2 hBv = __half22float2(*(const __half2*)(hsrc + (size_t)sB * HIDn + lane * 2));
      a0 += hA.x * wA + hBv.x * wB;
      a1 += hA.y * wA + hBv.y * wB;
    }
    if (j < rem) {
      int sA = __shfl(s_, j);
      float wA = __shfl(w, wsel | j);
      float2 hA = __half22float2(*(const __half2*)(hsrc + (size_t)sA * HIDn + lane * 2));
      a0 += hA.x * wA;
      a1 += hA.y * wA;
    }
  }
  float dinv = __fdividef(1.f, den + 1e-16f);
  float2 o2;
  o2.x = fmaxf(a0 * dinv, 0.f);
  o2.y = fmaxf(a1 * dinv, 0.f);
  *(float2*)(op.out + (size_t)dst * HIDn + lane * 2) = o2;
}

__global__ __launch_bounds__(256)
void csr_att3(EdgeOp op0, EdgeOp op1, EdgeOp op2, int Ndst)
{
  int wave = (blockIdx.x * 256 + threadIdx.x) >> 6;
  if (wave >= Ndst) return;
  const int lane = threadIdx.x & 63;
  if (blockIdx.y == 0)      csr_att_body(op0, wave, lane);
  else if (blockIdx.y == 1) csr_att_body(op1, wave, lane);
  else                      csr_att_body(op2, wave, lane);
}

// ---- fallback path (atomic scatter, fp32 h), used only if ws too small --
__global__ void edge_logit_max(const int* __restrict__ ei,
                               const float* __restrict__ sdot,
                               const float* __restrict__ ddot,
                               unsigned* __restrict__ m)
{
  int e = blockIdx.x * blockDim.x + threadIdx.x;
  if (e >= En) return;
  int s = ei[e], d = ei[En + e];
  #pragma unroll
  for (int hh = 0; hh < 4; ++hh) {
    float l = sdot[s * 4 + hh] + ddot[d * 4 + hh];
    l = (l > 0.f) ? l : 0.2f * l;
    atomicMax(&m[d * 4 + hh], fmap(l));
  }
}

__global__ void edge_exp_sum(const int* __restrict__ ei,
                             const float* __restrict__ sdot,
                             const float* __restrict__ ddot,
                             const unsigned* __restrict__ m,
                             float* __restrict__ sden,
                             float* __restrict__ ebuf)
{
  int e = blockIdx.x * blockDim.x + threadIdx.x;
  if (e >= En) return;
  int s = ei[e], d = ei[En + e];
  #pragma unroll
  for (int hh = 0; hh < 4; ++hh) {
    float l = sdot[s * 4 + hh] + ddot[d * 4 + hh];
    l = (l > 0.f) ? l : 0.2f * l;
    float ex = expf(fminf(l - fdecode(m[d * 4 + hh]), 0.f));
    ebuf[e * 4 + hh] = ex;
    atomicAdd(&sden[d * 4 + hh], ex);
  }
}

__global__ __launch_bounds__(256)
void edge_scatter(const int* __restrict__ ei, const float* __restrict__ hsrc,
                  const float* __restrict__ ebuf, const float* __restrict__ sden,
                  float* __restrict__ out)
{
  int gid  = blockIdx.x * 256 + threadIdx.x;
  int e    = gid >> 6;
  if (e >= En) return;
  int lane = gid & 63;
  int s = ei[e], d = ei[En + e];
  #pragma unroll
  for (int half = 0; half < 2; ++half) {
    int c  = lane + half * 64;
    int hh = c >> 5;
    float alpha = ebuf[e * 4 + hh] / (sden[d * 4 + hh] + 1e-16f);
    atomicAdd(&out[(size_t)d * HIDn + c], hsrc[(size_t)s * HIDn + c] * alpha);
  }
}

__global__ void relu_k(float* __restrict__ x, int n)
{
  int i = blockIdx.x * blockDim.x + threadIdx.x;
  if (i < n) x[i] = fmaxf(x[i], 0.f);
}

// ---- semantic-attention score via MFMA bf16 -----------------------------
__global__ __launch_bounds__(256)
void score_mfma(const float* __restrict__ oA, const float* __restrict__ oB,
                const unsigned short* __restrict__ kWt,
                const float* __restrict__ kb, const float* __restrict__ q,
                int N, float* __restrict__ slots)
{
  __shared__ float partw[4];
  const float* o = blockIdx.y ? oB : oA;
  const int tid = threadIdx.x;
  const int w = tid >> 6, lane = tid & 63;
  const int row0 = (blockIdx.x * 4 + w) * 16;
  const int m = lane & 15, b = lane >> 4;
  const int arow = row0 + m;
  const bool rok = arow < N;

  const bf16x8 zfr = {0, 0, 0, 0, 0, 0, 0, 0};
  bf16x8 afr[4];
  {
    const size_t base = (size_t)arow * 128;
    #pragma unroll
    for (int ks = 0; ks < 4; ++ks) {
      if (rok) afr[ks] = packrow8<0>(o, nullptr, 0.f, 0.f, base + ks * 32 + b * 8);
      else     afr[ks] = zfr;
    }
  }

  float sum = 0.f;
  #pragma unroll
  for (int t = 0; t < 8; ++t) {
    f32x4 acc = {0.f, 0.f, 0.f, 0.f};
    const int col = t * 16 + m;
    const unsigned short* bp = kWt + (size_t)col * 128 + b * 8;
    #pragma unroll
    for (int ks = 0; ks < 4; ++ks)
      acc = __builtin_amdgcn_mfma_f32_16x16x32_bf16(afr[ks], *(const bf16x8*)(bp + ks * 32), acc, 0, 0, 0);
    const float qc = q[col], kbc = kb[col];
    #pragma unroll
    for (int r = 0; r < 4; ++r) {
      int row = row0 + b * 4 + r;
      if (row < N) sum += qc * tanh_fast(acc[r] + kbc);
    }
  }
  #pragma unroll
  for (int off = 32; off > 0; off >>= 1) sum += __shfl_down(sum, off);
  if (lane == 0) partw[w] = sum;
  __syncthreads();
  if (tid == 0)
    atomicAdd(&slots[blockIdx.y],
              (partw[0] + partw[1] + partw[2] + partw[3]) * (1.f / (float)N));
}

__global__ void softmax2_kernel(float* sb)   // sb[0],sb[1] -> weights sb[2],sb[3]
{
  float s0 = sb[0], s1 = sb[1];
  float mx = fmaxf(s0, s1);
  float e0 = expf(s0 - mx), e1 = expf(s1 - mx);
  float inv = 1.f / (e0 + e1);
  sb[2] = e0 * inv;
  sb[3] = e1 * inv;
}

// ---- final projection via MFMA bf16 (+ optional L2 norm) ----------------
template<int MODE, bool NORM>
__global__ __launch_bounds__(256)
void proj_mfma(const float* __restrict__ fa, const float* __restrict__ fb,
               const float* __restrict__ wv,
               const unsigned short* __restrict__ pWt, const float* __restrict__ pb,
               float* __restrict__ out, int N)
{
  float w2 = 0.f, w3 = 0.f;
  if (MODE == 2) { w2 = wv[2]; w3 = wv[3]; }
  const int tid = threadIdx.x;
  const int w = tid >> 6, lane = tid & 63;
  const int row0 = (blockIdx.x * 4 + w) * 16;
  const int m = lane & 15, b = lane >> 4;
  const int arow = row0 + m;
  const bool rok = arow < N;

  const bf16x8 zfr = {0, 0, 0, 0, 0, 0, 0, 0};
  bf16x8 afr[4];
  {
    const size_t base = (size_t)arow * 128;
    #pragma unroll
    for (int ks = 0; ks < 4; ++ks) {
      if (rok) afr[ks] = packrow8<MODE>(fa, fb, w2, w3, base + ks * 32 + b * 8);
      else     afr[ks] = zfr;
    }
  }

  f32x4 accs[4];
  float pbc[4];
  #pragma unroll
  for (int t = 0; t < 4; ++t) {
    f32x4 acc = {0.f, 0.f, 0.f, 0.f};
    const int col = t * 16 + m;
    const unsigned short* bp = pWt + (size_t)col * 128 + b * 8;
    #pragma unroll
    for (int ks = 0; ks < 4; ++ks)
      acc = __builtin_amdgcn_mfma_f32_16x16x32_bf16(afr[ks], *(const bf16x8*)(bp + ks * 32), acc, 0, 0, 0);
    accs[t] = acc;
    pbc[t] = pb[col];
  }

  #pragma unroll
  for (int r = 0; r < 4; ++r) {
    const int row = row0 + b * 4 + r;
    float v[4];
    #pragma unroll
    for (int t = 0; t < 4; ++t) v[t] = accs[t][r] + pbc[t];
    if (NORM) {
      float ss = v[0]*v[0] + v[1]*v[1] + v[2]*v[2] + v[3]*v[3];
      ss += __shfl_xor(ss, 1);
      ss += __shfl_xor(ss, 2);
      ss += __shfl_xor(ss, 4);
      ss += __shfl_xor(ss, 8);
      float inv = 1.f / fmaxf(sqrtf(ss), 1e-12f);
      #pragma unroll
      for (int t = 0; t < 4; ++t) v[t] *= inv;
    }
    if (row < N) {
      #pragma unroll
      for (int t = 0; t < 4; ++t)
        out[(size_t)row * OUTn + t * 16 + m] = v[t];
    }
  }
}

// ---- fallback edge-op dispatcher ----------------------------------------
static void run_edge_fb(hipStream_t stream, const int* ei,
                        const float* sdot, const float* ddot, const float* hsrc,
                        float* outb, int Ndst,
                        unsigned* mbuf, float* sden, float* ebuf)
{
  hipMemsetAsync(mbuf, 0, (size_t)Ndst * 4 * sizeof(unsigned), stream);
  edge_logit_max<<<(En + 255) / 256, 256, 0, stream>>>(ei, sdot, ddot, mbuf);
  hipMemsetAsync(sden, 0, (size_t)Ndst * 4 * sizeof(float), stream);
  edge_exp_sum<<<(En + 255) / 256, 256, 0, stream>>>(ei, sdot, ddot, mbuf, sden, ebuf);
  hipMemsetAsync(outb, 0, (size_t)Ndst * HIDn * sizeof(float), stream);
  edge_scatter<<<((size_t)En * 64 + 255) / 256, 256, 0, stream>>>(ei, hsrc, ebuf, sden, outb);
  relu_k<<<((size_t)Ndst * HIDn + 255) / 256, 256, 0, stream>>>(outb, Ndst * HIDn);
}

extern "C" void kernel_launch(void* const* d_in, const int* in_sizes, int n_in,
                              void* d_out, int out_size, void* d_ws, size_t ws_size,
                              hipStream_t stream)
{
  const float* xc    = (const float*)d_in[0];
  const float* xd    = (const float*)d_in[1];
  const int*   ei_cc = (const int*)d_in[2];
  const int*   ei_dc = (const int*)d_in[3];
  const int*   ei_cd = (const int*)d_in[4];
  const float* W1c = (const float*)d_in[5];  const float* b1c = (const float*)d_in[6];
  const float* W1d = (const float*)d_in[7];  const float* b1d = (const float*)d_in[8];
  const float* a1s_cc = (const float*)d_in[9];  const float* a1d_cc = (const float*)d_in[10];
  const float* a1s_dc = (const float*)d_in[11]; const float* a1d_dc = (const float*)d_in[12];
  const float* a1s_cd = (const float*)d_in[13]; const float* a1d_cd = (const float*)d_in[14];
  const float* k1W = (const float*)d_in[15]; const float* k1b = (const float*)d_in[16];
  const float* q1  = (const float*)d_in[17];
  const float* W2c = (const float*)d_in[18]; const float* b2c = (const float*)d_in[19];
  const float* W2d = (const float*)d_in[20]; const float* b2d = (const float*)d_in[21];
  const float* a2s_cc = (const float*)d_in[22]; const float* a2d_cc = (const float*)d_in[23];
  const float* a2s_dc = (const float*)d_in[24]; const float* a2d_dc = (const float*)d_in[25];
  const float* a2s_cd = (const float*)d_in[26]; const float* a2d_cd = (const float*)d_in[27];
  const float* k2W = (const float*)d_in[28]; const float* k2b = (const float*)d_in[29];
  const float* q2  = (const float*)d_in[30];
  const float* pW  = (const float*)d_in[31]; const float* pb  = (const float*)d_in[32];

  // ---------------- workspace layout (fp32) ----------------
  float* ws = (float*)d_ws;
  const size_t NB = (size_t)NCn * HIDn;
  float* B0 = ws;            // h buffers (fp16 in CSR mode, fp32 in fallback)
  float* B1 = ws + NB;
  float* B2 = ws + 2 * NB;
  float* B3 = ws + 3 * NB;
  float* B4 = ws + 4 * NB;
  float* sml = ws + 5 * NB;
  float* scc = sml;
  float* dcc = sml + 200000;
  float* ddc = sml + 400000;
  float* scd = sml + 600000;
  float* sdc = sml + 800000;
  float* dcd = sml + 1000000;
  float* scoreB = sml + 1200000;
  float* R0 = sml + 1200016;
  int*  R0i = (int*)R0;
  int*  offsBase  = R0i;                                   // 150,012 ints
  int*  elistBase = R0i + 150012;                          // 1,200,000 ints
  int*  tmpBase   = R0i + 1350012;                         // 150,000 ints
  unsigned short* kW1t = (unsigned short*)(R0i + 1500012); // 16384 halves
  unsigned short* kW2t = (unsigned short*)(R0i + 1508204); // 16384 halves
  unsigned short* pWt  = (unsigned short*)(R0i + 1516396); // 8192 halves
  unsigned short* W1cH = (unsigned short*)(R0i + 1520492); // 32768 halves
  unsigned short* W1cL = (unsigned short*)(R0i + 1536876);
  unsigned short* W1dH = (unsigned short*)(R0i + 1553260);
  unsigned short* W1dL = (unsigned short*)(R0i + 1569644);
  unsigned short* W2cH = (unsigned short*)(R0i + 1586028); // 16384 halves
  unsigned short* W2cL = (unsigned short*)(R0i + 1594220);
  unsigned short* W2dH = (unsigned short*)(R0i + 1602412);
  unsigned short* W2dL = (unsigned short*)(R0i + 1610604); // end 1,618,796 ints
  // fallback temps overlay (over CSR region)
  unsigned* mbuf = (unsigned*)R0;
  float*    sden = R0 + 200000;
  float*    ebuf = R0 + 400000;

  const size_t REQ_FLOATS = 5 * NB + 1200016 + 1618796;    // 34,818,812 fl = 139.3 MB
  const bool useCsr = ws_size >= REQ_FLOATS * sizeof(float);

  if (useCsr) {
    hipMemsetAsync(tmpBase, 0, 150000 * sizeof(int), stream);
    hist3<<<(3 * En + 255) / 256, 256, 0, stream>>>(ei_cc, ei_dc, ei_cd, tmpBase);
    scan3<<<3, 1024, 0, stream>>>(tmpBase, offsBase);
    hipMemsetAsync(tmpBase, 0, 150000 * sizeof(int), stream);
    fill3<<<(3 * En + 255) / 256, 256, 0, stream>>>(ei_cc, ei_dc, ei_cd,
                                                    offsBase, tmpBase, elistBase);
  }
  // weight prep: bf16 transposes/splits
  wtrans<<<(128 * 128 + 255) / 256, 256, 0, stream>>>(k1W, kW1t, 128);
  wtrans<<<(128 * 128 + 255) / 256, 256, 0, stream>>>(k2W, kW2t, 128);
  wtrans<<<(128 * 64 + 255) / 256, 256, 0, stream>>>(pW, pWt, 64);
  wtrans_split<<<(256 * 128 + 255) / 256, 256, 0, stream>>>(W1c, W1cH, W1cL, 256);
  wtrans_split<<<(256 * 128 + 255) / 256, 256, 0, stream>>>(W1d, W1dH, W1dL, 256);
  wtrans_split<<<(128 * 128 + 255) / 256, 256, 0, stream>>>(W2c, W2cH, W2cL, 128);
  wtrans_split<<<(128 * 128 + 255) / 256, 256, 0, stream>>>(W2d, W2dH, W2dL, 128);

  hipMemsetAsync(scoreB, 0, 8 * sizeof(float), stream);

  const int NT64 = (NCn + 63) / 64;
  const int dotGrid = (NCn * 4 + 255) / 256;
  const int* offs0 = offsBase;
  const int* offs1 = offsBase + 50004;
  const int* offs2 = offsBase + 100008;
  const int* el0 = elistBase;
  const int* el1 = elistBase + En;
  const int* el2 = elistBase + 2 * (size_t)En;

  auto edge_layer = [&](void* hc, void* hd, float* oCC, float* oDC, float* oCD) {
    if (useCsr) {
      EdgeOp o0{offs0, el0, scc, dcc, (const __half*)hc, oCC};
      EdgeOp o1{offs1, el1, sdc, ddc, (const __half*)hd, oDC};
      EdgeOp o2{offs2, el2, scd, dcd, (const __half*)hc, oCD};
      csr_att3<<<dim3((NCn + 3) / 4, 3), 256, 0, stream>>>(o0, o1, o2, NCn);
    } else {
      run_edge_fb(stream, ei_cc, scc, dcc, (const float*)hc, oCC, NCn, mbuf, sden, ebuf);
      run_edge_fb(stream, ei_dc, sdc, ddc, (const float*)hd, oDC, NCn, mbuf, sden, ebuf);
      run_edge_fb(stream, ei_cd, scd, dcd, (const float*)hc, oCD, NDn, mbuf, sden, ebuf);
    }
  };

  if (useCsr) {
    // ---------------- layer 1 (MFMA gemm, h in fp16) ----------------
    gemm_mfma<256, 0, 1><<<NT64, 256, 0, stream>>>(xc, nullptr, nullptr, W1cH, W1cL, b1c, B0, NCn);
    gemm_mfma<256, 0, 1><<<NT64, 256, 0, stream>>>(xd, nullptr, nullptr, W1dH, W1dL, b1d, B1, NDn);
    dot6<1><<<dotGrid, 256, 0, stream>>>(B0, B1, a1s_cc, a1d_cc, a1s_dc, a1d_dc, a1s_cd, a1d_cd,
                                         scc, dcc, ddc, scd, sdc, dcd, NCn);
    edge_layer(B0, B1, B2, B3, B4);
    score_mfma<<<dim3(NT64, 2), 256, 0, stream>>>(B2, B3, kW1t, k1b, q1, NCn, scoreB);
    softmax2_kernel<<<1, 1, 0, stream>>>(scoreB);

    // ---------------- layer 2 ----------------
    gemm_mfma<128, 2, 1><<<NT64, 256, 0, stream>>>(B2, B3, scoreB, W2cH, W2cL, b2c, B0, NCn);
    gemm_mfma<128, 1, 1><<<NT64, 256, 0, stream>>>(B4, nullptr, nullptr, W2dH, W2dL, b2d, B1, NDn);
    dot6<1><<<dotGrid, 256, 0, stream>>>(B0, B1, a2s_cc, a2d_cc, a2s_dc, a2d_dc, a2s_cd, a2d_cd,
                                         scc, dcc, ddc, scd, sdc, dcd, NCn);
    edge_layer(B0, B1, B2, B3, B4);
    score_mfma<<<dim3(NT64, 2), 256, 0, stream>>>(B2, B3, kW2t, k2b, q2, NCn, scoreB + 4);
    softmax2_kernel<<<1, 1, 0, stream>>>(scoreB + 4);
  } else {
    // ---------------- fp32-h fallback ----------------
    gemm_mfma<256, 0, 0><<<NT64, 256, 0, stream>>>(xc, nullptr, nullptr, W1cH, W1cL, b1c, B0, NCn);
    gemm_mfma<256, 0, 0><<<NT64, 256, 0, stream>>>(xd, nullptr, nullptr, W1dH, W1dL, b1d, B1, NDn);
    dot6<0><<<dotGrid, 256, 0, stream>>>(B0, B1, a1s_cc, a1d_cc, a1s_dc, a1d_dc, a1s_cd, a1d_cd,
                                         scc, dcc, ddc, scd, sdc, dcd, NCn);
    edge_layer(B0, B1, B2, B3, B4);
    score_mfma<<<dim3(NT64, 2), 256, 0, stream>>>(B2, B3, kW1t, k1b, q1, NCn, scoreB);
    softmax2_kernel<<<1, 1, 0, stream>>>(scoreB);

    gemm_mfma<128, 2, 0><<<NT64, 256, 0, stream>>>(B2, B3, scoreB, W2cH, W2cL, b2c, B0, NCn);
    gemm_mfma<128, 1, 0><<<NT64, 256, 0, stream>>>(B4, nullptr, nullptr, W2dH, W2dL, b2d, B1, NDn);
    dot6<0><<<dotGrid, 256, 0, stream>>>(B0, B1, a2s_cc, a2d_cc, a2s_dc, a2d_dc, a2s_cd, a2d_cd,
                                         scc, dcc, ddc, scd, sdc, dcd, NCn);
    edge_layer(B0, B1, B2, B3, B4);
    score_mfma<<<dim3(NT64, 2), 256, 0, stream>>>(B2, B3, kW2t, k2b, q2, NCn, scoreB + 4);
    softmax2_kernel<<<1, 1, 0, stream>>>(scoreB + 4);
  }

  // ---------------- projection (+combine/elu fused, MFMA) ----------------
  proj_mfma<2, true ><<<NT64, 256, 0, stream>>>(B2, B3, scoreB + 4, pWt, pb, (float*)d_out, NCn);
  proj_mfma<1, false><<<NT64, 256, 0, stream>>>(B4, nullptr, nullptr, pWt, pb,
                                                (float*)d_out + (size_t)NCn * OUTn, NDn);
}

// Round 17
// 618.873 us; speedup vs baseline: 1.1810x; 1.1810x over previous
//
#include <hip/hip_runtime.h>
#include <hip/hip_fp16.h>
#include <cmath>

#define DEVI static __device__ __forceinline__

constexpr int HIDn = 128, OUTn = 64;
constexpr int NCn = 50000, NDn = 50000, En = 400000;

typedef __attribute__((ext_vector_type(8))) short bf16x8;
typedef __attribute__((ext_vector_type(4))) float f32x4;

// monotonic float->uint mapping for atomicMax on floats (handles signs)
DEVI unsigned fmap(float f) {
  int i = __float_as_int(f);
  return (i < 0) ? ~((unsigned)i) : (((unsigned)i) | 0x80000000u);
}
DEVI float fdecode(unsigned u) {
  int i = (u & 0x80000000u) ? (int)(u & 0x7fffffffu) : (int)(~u);
  return __int_as_float(i);
}

DEVI float tanh_fast(float x) {           // 1 - 2/(e^{2x}+1); saturates correctly
  float e = __expf(2.f * x);
  return 1.f - __fdividef(2.f, e + 1.f);
}

DEVI unsigned short f2bf(float x) {       // fp32 -> bf16 RNE
  unsigned u = __float_as_uint(x);
  return (unsigned short)((u + 0x7FFFu + ((u >> 16) & 1u)) >> 16);
}
DEVI float bf2f(unsigned short h) {
  unsigned u = ((unsigned)h) << 16;
  return __uint_as_float(u);
}

// ---- vectorized 8-wide A-row load + fused transform (value-based) -------
// MODE: 0=plain, 1=elu(x), 2=elu(w2*a+w3*b).  base must be 16B-aligned.
template<int MODE>
DEVI void loadrow8(float* __restrict__ tmp,
                   const float* __restrict__ A, const float* __restrict__ A2,
                   float w2, float w3, size_t base)
{
  const float4* p = (const float4*)(A + base);
  float4 u0 = p[0], u1 = p[1];
  float v[8] = {u0.x, u0.y, u0.z, u0.w, u1.x, u1.y, u1.z, u1.w};
  if (MODE == 2) {
    const float4* q = (const float4*)(A2 + base);
    float4 t0 = q[0], t1 = q[1];
    float vb[8] = {t0.x, t0.y, t0.z, t0.w, t1.x, t1.y, t1.z, t1.w};
    #pragma unroll
    for (int i = 0; i < 8; ++i) v[i] = w2 * v[i] + w3 * vb[i];
  }
  if (MODE >= 1) {
    #pragma unroll
    for (int i = 0; i < 8; ++i) v[i] = (v[i] > 0.f) ? v[i] : (__expf(v[i]) - 1.f);
  }
  #pragma unroll
  for (int i = 0; i < 8; ++i) tmp[i] = v[i];
}

template<int MODE>
DEVI bf16x8 packrow8(const float* __restrict__ A, const float* __restrict__ A2,
                     float w2, float w3, size_t base)
{
  float t[8];
  loadrow8<MODE>(t, A, A2, w2, w3, base);
  bf16x8 r;
  #pragma unroll
  for (int i = 0; i < 8; ++i) r[i] = (short)f2bf(t[i]);
  return r;
}

// ====== MFMA GEMM with LDS staging: C[N,128]=xform(A)@W + b ==============
// 4 waves, 64-row tile, K chunked by 32. A and B(hi/lo) staged in LDS
// (coalesced); fragments read from LDS. 3-term hi/lo split (~fp32 acc).
template<int KI, int MODE, int OUT16>
__global__ __launch_bounds__(256)
void gemm_mfma(const float* __restrict__ A, const float* __restrict__ A2,
               const float* __restrict__ wv,
               const unsigned short* __restrict__ Wh, const unsigned short* __restrict__ Wl,
               const float* __restrict__ bias, void* __restrict__ Cv, int N)
{
  __shared__ float As[64][36];            // 9216 B  (rows 144B, 16B-aligned)
  __shared__ unsigned short Bh[128][40];  // 10240 B (rows 80B, 16B-aligned)
  __shared__ unsigned short Bl[128][40];  // 10240 B
  float w2 = 0.f, w3 = 0.f;
  if (MODE == 2) { w2 = wv[2]; w3 = wv[3]; }
  const int tid = threadIdx.x;
  const int w = tid >> 6, lane = tid & 63;
  const int m = lane & 15, b4 = lane >> 4;
  const int row0 = blockIdx.x * 64;
  const int row0w = row0 + w * 16;

  f32x4 acc[8];
  #pragma unroll
  for (int t = 0; t < 8; ++t) acc[t] = (f32x4){0.f, 0.f, 0.f, 0.f};

  for (int k0 = 0; k0 < KI; k0 += 32) {
    { // stage A: 64 rows x 32 k, coalesced, fused transform
      const int r = tid >> 2, kq = (tid & 3) << 3;
      const int row = row0 + r;
      float tmp[8];
      if (row < N) {
        loadrow8<MODE>(tmp, A, A2, w2, w3, (size_t)row * KI + k0 + kq);
      } else {
        #pragma unroll
        for (int i = 0; i < 8; ++i) tmp[i] = 0.f;
      }
      *(float4*)&As[r][kq]     = make_float4(tmp[0], tmp[1], tmp[2], tmp[3]);
      *(float4*)&As[r][kq + 4] = make_float4(tmp[4], tmp[5], tmp[6], tmp[7]);
    }
    { // stage B: 128 cols x 32 k, both planes, coalesced
      const int c = tid >> 1, kq = (tid & 1) << 4;
      const float4* ph = (const float4*)(Wh + (size_t)c * KI + k0 + kq);
      const float4* pl = (const float4*)(Wl + (size_t)c * KI + k0 + kq);
      *(float4*)&Bh[c][kq]     = ph[0];
      *(float4*)&Bh[c][kq + 8] = ph[1];
      *(float4*)&Bl[c][kq]     = pl[0];
      *(float4*)&Bl[c][kq + 8] = pl[1];
    }
    __syncthreads();

    // A fragment for this lane: row (row0w+m), k-slot b4*8+j; split hi/lo
    bf16x8 ah, al;
    {
      const float* ap = &As[w * 16 + m][b4 * 8];
      float4 u0 = *(const float4*)ap;
      float4 u1 = *(const float4*)(ap + 4);
      float t8[8] = {u0.x, u0.y, u0.z, u0.w, u1.x, u1.y, u1.z, u1.w};
      #pragma unroll
      for (int i = 0; i < 8; ++i) {
        unsigned short h = f2bf(t8[i]);
        ah[i] = (short)h;
        al[i] = (short)f2bf(t8[i] - bf2f(h));
      }
    }
    #pragma unroll
    for (int t = 0; t < 8; ++t) {
      const int col = t * 16 + m;
      bf16x8 bh = *(const bf16x8*)&Bh[col][b4 * 8];
      bf16x8 bl = *(const bf16x8*)&Bl[col][b4 * 8];
      acc[t] = __builtin_amdgcn_mfma_f32_16x16x32_bf16(ah, bh, acc[t], 0, 0, 0);
      acc[t] = __builtin_amdgcn_mfma_f32_16x16x32_bf16(al, bh, acc[t], 0, 0, 0);
      acc[t] = __builtin_amdgcn_mfma_f32_16x16x32_bf16(ah, bl, acc[t], 0, 0, 0);
    }
    __syncthreads();
  }

  // epilogue: C/D layout col=lane&15, row=(lane>>4)*4+r (verified)
  #pragma unroll
  for (int t = 0; t < 8; ++t) {
    const int col = t * 16 + m;
    const float bc = bias[col];
    #pragma unroll
    for (int r = 0; r < 4; ++r) {
      const int row = row0w + b4 * 4 + r;
      if (row < N) {
        float v = acc[t][r] + bc;
        if (OUT16) ((__half*)Cv)[(size_t)row * 128 + col] = __float2half(v);
        else       ((float*)Cv)[(size_t)row * 128 + col] = v;
      }
    }
  }
}

// ---- all six per-(node,head) attention dots (reads h, fp16 or fp32) -----
DEVI float dot4f(float4 a, float4 b) { return a.x*b.x + a.y*b.y + a.z*b.z + a.w*b.w; }

template<int HALF>
DEVI void loadrow32h(const void* base, size_t off, float* v)
{
  if (HALF) {
    const __half* p = (const __half*)base + off;
    #pragma unroll
    for (int i = 0; i < 4; ++i) {
      float4 raw = *(const float4*)(p + i * 8);     // 8 halves
      const __half2* h2 = (const __half2*)&raw;
      #pragma unroll
      for (int j = 0; j < 4; ++j) {
        float2 f = __half22float2(h2[j]);
        v[i * 8 + j * 2]     = f.x;
        v[i * 8 + j * 2 + 1] = f.y;
      }
    }
  } else {
    const float* p = (const float*)base + off;
    #pragma unroll
    for (int i = 0; i < 8; ++i) {
      float4 u = *(const float4*)(p + i * 4);
      v[i * 4] = u.x; v[i * 4 + 1] = u.y; v[i * 4 + 2] = u.z; v[i * 4 + 3] = u.w;
    }
  }
}

template<int HALF>
__global__ void dot6(const void* __restrict__ hc, const void* __restrict__ hd,
                     const float* __restrict__ ascc, const float* __restrict__ adcc,
                     const float* __restrict__ asdc, const float* __restrict__ addc,
                     const float* __restrict__ ascd, const float* __restrict__ adcd,
                     float* __restrict__ scc, float* __restrict__ dcc,
                     float* __restrict__ ddc, float* __restrict__ scd,
                     float* __restrict__ sdc, float* __restrict__ dcd, int N)
{
  int idx = blockIdx.x * blockDim.x + threadIdx.x;
  if (idx >= N * 4) return;
  int n = idx >> 2, hh = idx & 3;
  float hv[32], dv[32];
  loadrow32h<HALF>(hc, (size_t)n * HIDn + hh * 32, hv);
  loadrow32h<HALF>(hd, (size_t)n * HIDn + hh * 32, dv);
  const float4* a1 = (const float4*)(ascc + hh * 32);
  const float4* a2 = (const float4*)(adcc + hh * 32);
  const float4* a3 = (const float4*)(addc + hh * 32);
  const float4* a4 = (const float4*)(ascd + hh * 32);
  const float4* a5 = (const float4*)(asdc + hh * 32);
  const float4* a6 = (const float4*)(adcd + hh * 32);
  float s1 = 0, s2 = 0, s3 = 0, s4 = 0, t1 = 0, t2 = 0;
  #pragma unroll
  for (int i = 0; i < 8; ++i) {
    float4 hq = make_float4(hv[i*4], hv[i*4+1], hv[i*4+2], hv[i*4+3]);
    s1 += dot4f(hq, a1[i]);
    s2 += dot4f(hq, a2[i]);
    s3 += dot4f(hq, a3[i]);
    s4 += dot4f(hq, a4[i]);
    float4 dq = make_float4(dv[i*4], dv[i*4+1], dv[i*4+2], dv[i*4+3]);
    t1 += dot4f(dq, a5[i]);
    t2 += dot4f(dq, a6[i]);
  }
  scc[idx] = s1; dcc[idx] = s2; ddc[idx] = s3;
  scd[idx] = s4; sdc[idx] = t1; dcd[idx] = t2;
}

// ================= CSR build, all 3 graphs batched =======================
__global__ void hist3(const int* __restrict__ ei0, const int* __restrict__ ei1,
                      const int* __restrict__ ei2, int* __restrict__ tmpBase)
{
  int gid = blockIdx.x * blockDim.x + threadIdx.x;
  if (gid >= 3 * En) return;
  int g = gid / En, e = gid - g * En;
  const int* ei = (g == 0) ? ei0 : (g == 1) ? ei1 : ei2;
  atomicAdd(&tmpBase[g * 50000 + ei[En + e]], 1);
}

__global__ void scan3(const int* __restrict__ tmpBase, int* __restrict__ offsBase)
{
  const int n = 50000;
  const int* deg = tmpBase + blockIdx.x * 50000;
  int* offs = offsBase + blockIdx.x * 50004;
  __shared__ int wsum[16];
  __shared__ int carry_sh;
  int tid = threadIdx.x;
  if (tid == 0) { carry_sh = 0; offs[0] = 0; }
  __syncthreads();
  const int nw = blockDim.x >> 6;
  int lane = tid & 63, w = tid >> 6;
  for (int base = 0; base < n; base += blockDim.x) {
    int i = base + tid;
    int v = (i < n) ? deg[i] : 0;
    int x = v;
    #pragma unroll
    for (int off = 1; off < 64; off <<= 1) {
      int y = __shfl_up(x, off);
      if (lane >= off) x += y;
    }
    if (lane == 63) wsum[w] = x;
    __syncthreads();
    if (tid == 0) {
      int s = carry_sh;
      for (int ww = 0; ww < nw; ++ww) { int t = wsum[ww]; wsum[ww] = s; s += t; }
      carry_sh = s;
    }
    __syncthreads();
    if (i < n) offs[i + 1] = wsum[w] + x;
    __syncthreads();
  }
}

__global__ void fill3(const int* __restrict__ ei0, const int* __restrict__ ei1,
                      const int* __restrict__ ei2, const int* __restrict__ offsBase,
                      int* __restrict__ cursorBase, int* __restrict__ elistBase)
{
  int gid = blockIdx.x * blockDim.x + threadIdx.x;
  if (gid >= 3 * En) return;
  int g = gid / En, e = gid - g * En;
  const int* ei = (g == 0) ? ei0 : (g == 1) ? ei1 : ei2;
  const int* offs = offsBase + g * 50004;
  int* cursor = cursorBase + g * 50000;
  int* elist = elistBase + (size_t)g * En;
  int s = ei[e], d = ei[En + e];
  int p = atomicAdd(&cursor[d], 1);
  elist[offs[d] + p] = s;
}

// ---- W transpose+cast single-plane: W[128][KO] fp32 -> Wt[KO][128] bf16 -
__global__ void wtrans(const float* __restrict__ W, unsigned short* __restrict__ Wt, int KO)
{
  int idx = blockIdx.x * 256 + threadIdx.x;
  if (idx >= 128 * KO) return;
  int k = idx / KO, c = idx - k * KO;
  Wt[(size_t)c * 128 + k] = f2bf(W[idx]);
}

// ---- W transpose+split: W[KI][128] fp32 -> Wh/Wl[128][KI] bf16 ----------
__global__ void wtrans_split(const float* __restrict__ W,
                             unsigned short* __restrict__ Wh,
                             unsigned short* __restrict__ Wl, int KI)
{
  int idx = blockIdx.x * 256 + threadIdx.x;
  if (idx >= KI * 128) return;
  int k = idx >> 7, c = idx & 127;
  float v = W[idx];
  unsigned short h = f2bf(v);
  Wh[(size_t)c * KI + k] = h;
  Wl[(size_t)c * KI + k] = f2bf(v - bf2f(h));
}

// ==== FUSED edge attention (CSR, fp16 h, lane-specialized softmax) =======
struct EdgeOp {
  const int* offs; const int* elist;
  const float* sdot; const float* ddot;
  const __half* hsrc; float* out;
};

DEVI void csr_att_body(const EdgeOp& op, int dst, int lane)
{
  const int i0 = op.offs[dst], i1 = op.offs[dst + 1];
  const int hB = lane >> 4;
  const float ddv = op.ddot[dst * 4 + hB];
  const __half* hsrc = op.hsrc;
  const float* sdot = op.sdot;
  const int* el = op.elist;
  const int wsel = lane & 48;
  float den = 0.f, a0 = 0.f, a1 = 0.f;

  for (int base = i0; base < i1; base += 16) {
    int i = base + (lane & 15);
    int s_ = 0;
    float w = 0.f;
    if (i < i1) {
      s_ = el[i];
      float lv = sdot[s_ * 4 + hB] + ddv;
      lv = fminf(fmaxf(lv, 0.2f * lv), 80.f);
      w = __expf(lv);
    }
    float g = w;
    g += __shfl_xor(g, 1);
    g += __shfl_xor(g, 2);
    g += __shfl_xor(g, 4);
    g += __shfl_xor(g, 8);
    den += g;

    const int rem = min(16, i1 - base);
    int j = 0;
    for (; j + 2 <= rem; j += 2) {
      int sA = __shfl(s_, j);
      int sB = __shfl(s_, j + 1);
      float wA = __shfl(w, wsel | j);
      float wB = __shfl(w, wsel | (j + 1));
      float2 hA = __half22float2(*(const __half2*)(hsrc + (size_t)sA * HIDn + lane * 2));
      float2 hBv = __half22float2(*(const __half2*)(hsrc + (size_t)sB * HIDn + lane * 2));
      a0 += hA.x * wA + hBv.x * wB;
      a1 += hA.y * wA + hBv.y * wB;
    }
    if (j < rem) {
      int sA = __shfl(s_, j);
      float wA = __shfl(w, wsel | j);
      float2 hA = __half22float2(*(const __half2*)(hsrc + (size_t)sA * HIDn + lane * 2));
      a0 += hA.x * wA;
      a1 += hA.y * wA;
    }
  }
  float dinv = __fdividef(1.f, den + 1e-16f);
  float2 o2;
  o2.x = fmaxf(a0 * dinv, 0.f);
  o2.y = fmaxf(a1 * dinv, 0.f);
  *(float2*)(op.out + (size_t)dst * HIDn + lane * 2) = o2;
}

__global__ __launch_bounds__(256)
void csr_att3(EdgeOp op0, EdgeOp op1, EdgeOp op2, int Ndst)
{
  int wave = (blockIdx.x * 256 + threadIdx.x) >> 6;
  if (wave >= Ndst) return;
  const int lane = threadIdx.x & 63;
  if (blockIdx.y == 0)      csr_att_body(op0, wave, lane);
  else if (blockIdx.y == 1) csr_att_body(op1, wave, lane);
  else                      csr_att_body(op2, wave, lane);
}

// ---- fallback path (atomic scatter, fp32 h), used only if ws too small --
__global__ void edge_logit_max(const int* __restrict__ ei,
                               const float* __restrict__ sdot,
                               const float* __restrict__ ddot,
                               unsigned* __restrict__ m)
{
  int e = blockIdx.x * blockDim.x + threadIdx.x;
  if (e >= En) return;
  int s = ei[e], d = ei[En + e];
  #pragma unroll
  for (int hh = 0; hh < 4; ++hh) {
    float l = sdot[s * 4 + hh] + ddot[d * 4 + hh];
    l = (l > 0.f) ? l : 0.2f * l;
    atomicMax(&m[d * 4 + hh], fmap(l));
  }
}

__global__ void edge_exp_sum(const int* __restrict__ ei,
                             const float* __restrict__ sdot,
                             const float* __restrict__ ddot,
                             const unsigned* __restrict__ m,
                             float* __restrict__ sden,
                             float* __restrict__ ebuf)
{
  int e = blockIdx.x * blockDim.x + threadIdx.x;
  if (e >= En) return;
  int s = ei[e], d = ei[En + e];
  #pragma unroll
  for (int hh = 0; hh < 4; ++hh) {
    float l = sdot[s * 4 + hh] + ddot[d * 4 + hh];
    l = (l > 0.f) ? l : 0.2f * l;
    float ex = expf(fminf(l - fdecode(m[d * 4 + hh]), 0.f));
    ebuf[e * 4 + hh] = ex;
    atomicAdd(&sden[d * 4 + hh], ex);
  }
}

__global__ __launch_bounds__(256)
void edge_scatter(const int* __restrict__ ei, const float* __restrict__ hsrc,
                  const float* __restrict__ ebuf, const float* __restrict__ sden,
                  float* __restrict__ out)
{
  int gid  = blockIdx.x * 256 + threadIdx.x;
  int e    = gid >> 6;
  if (e >= En) return;
  int lane = gid & 63;
  int s = ei[e], d = ei[En + e];
  #pragma unroll
  for (int half = 0; half < 2; ++half) {
    int c  = lane + half * 64;
    int hh = c >> 5;
    float alpha = ebuf[e * 4 + hh] / (sden[d * 4 + hh] + 1e-16f);
    atomicAdd(&out[(size_t)d * HIDn + c], hsrc[(size_t)s * HIDn + c] * alpha);
  }
}

__global__ void relu_k(float* __restrict__ x, int n)
{
  int i = blockIdx.x * blockDim.x + threadIdx.x;
  if (i < n) x[i] = fmaxf(x[i], 0.f);
}

// ---- semantic-attention score via MFMA bf16 -----------------------------
__global__ __launch_bounds__(256)
void score_mfma(const float* __restrict__ oA, const float* __restrict__ oB,
                const unsigned short* __restrict__ kWt,
                const float* __restrict__ kb, const float* __restrict__ q,
                int N, float* __restrict__ slots)
{
  __shared__ float partw[4];
  const float* o = blockIdx.y ? oB : oA;
  const int tid = threadIdx.x;
  const int w = tid >> 6, lane = tid & 63;
  const int row0 = (blockIdx.x * 4 + w) * 16;
  const int m = lane & 15, b = lane >> 4;
  const int arow = row0 + m;
  const bool rok = arow < N;

  const bf16x8 zfr = {0, 0, 0, 0, 0, 0, 0, 0};
  bf16x8 afr[4];
  {
    const size_t base = (size_t)arow * 128;
    #pragma unroll
    for (int ks = 0; ks < 4; ++ks) {
      if (rok) afr[ks] = packrow8<0>(o, nullptr, 0.f, 0.f, base + ks * 32 + b * 8);
      else     afr[ks] = zfr;
    }
  }

  float sum = 0.f;
  #pragma unroll
  for (int t = 0; t < 8; ++t) {
    f32x4 acc = {0.f, 0.f, 0.f, 0.f};
    const int col = t * 16 + m;
    const unsigned short* bp = kWt + (size_t)col * 128 + b * 8;
    #pragma unroll
    for (int ks = 0; ks < 4; ++ks)
      acc = __builtin_amdgcn_mfma_f32_16x16x32_bf16(afr[ks], *(const bf16x8*)(bp + ks * 32), acc, 0, 0, 0);
    const float qc = q[col], kbc = kb[col];
    #pragma unroll
    for (int r = 0; r < 4; ++r) {
      int row = row0 + b * 4 + r;
      if (row < N) sum += qc * tanh_fast(acc[r] + kbc);
    }
  }
  #pragma unroll
  for (int off = 32; off > 0; off >>= 1) sum += __shfl_down(sum, off);
  if (lane == 0) partw[w] = sum;
  __syncthreads();
  if (tid == 0)
    atomicAdd(&slots[blockIdx.y],
              (partw[0] + partw[1] + partw[2] + partw[3]) * (1.f / (float)N));
}

__global__ void softmax2_kernel(float* sb)   // sb[0],sb[1] -> weights sb[2],sb[3]
{
  float s0 = sb[0], s1 = sb[1];
  float mx = fmaxf(s0, s1);
  float e0 = expf(s0 - mx), e1 = expf(s1 - mx);
  float inv = 1.f / (e0 + e1);
  sb[2] = e0 * inv;
  sb[3] = e1 * inv;
}

// ---- final projection via MFMA bf16 (+ optional L2 norm) ----------------
template<int MODE, bool NORM>
__global__ __launch_bounds__(256)
void proj_mfma(const float* __restrict__ fa, const float* __restrict__ fb,
               const float* __restrict__ wv,
               const unsigned short* __restrict__ pWt, const float* __restrict__ pb,
               float* __restrict__ out, int N)
{
  float w2 = 0.f, w3 = 0.f;
  if (MODE == 2) { w2 = wv[2]; w3 = wv[3]; }
  const int tid = threadIdx.x;
  const int w = tid >> 6, lane = tid & 63;
  const int row0 = (blockIdx.x * 4 + w) * 16;
  const int m = lane & 15, b = lane >> 4;
  const int arow = row0 + m;
  const bool rok = arow < N;

  const bf16x8 zfr = {0, 0, 0, 0, 0, 0, 0, 0};
  bf16x8 afr[4];
  {
    const size_t base = (size_t)arow * 128;
    #pragma unroll
    for (int ks = 0; ks < 4; ++ks) {
      if (rok) afr[ks] = packrow8<MODE>(fa, fb, w2, w3, base + ks * 32 + b * 8);
      else     afr[ks] = zfr;
    }
  }

  f32x4 accs[4];
  float pbc[4];
  #pragma unroll
  for (int t = 0; t < 4; ++t) {
    f32x4 acc = {0.f, 0.f, 0.f, 0.f};
    const int col = t * 16 + m;
    const unsigned short* bp = pWt + (size_t)col * 128 + b * 8;
    #pragma unroll
    for (int ks = 0; ks < 4; ++ks)
      acc = __builtin_amdgcn_mfma_f32_16x16x32_bf16(afr[ks], *(const bf16x8*)(bp + ks * 32), acc, 0, 0, 0);
    accs[t] = acc;
    pbc[t] = pb[col];
  }

  #pragma unroll
  for (int r = 0; r < 4; ++r) {
    const int row = row0 + b * 4 + r;
    float v[4];
    #pragma unroll
    for (int t = 0; t < 4; ++t) v[t] = accs[t][r] + pbc[t];
    if (NORM) {
      float ss = v[0]*v[0] + v[1]*v[1] + v[2]*v[2] + v[3]*v[3];
      ss += __shfl_xor(ss, 1);
      ss += __shfl_xor(ss, 2);
      ss += __shfl_xor(ss, 4);
      ss += __shfl_xor(ss, 8);
      float inv = 1.f / fmaxf(sqrtf(ss), 1e-12f);
      #pragma unroll
      for (int t = 0; t < 4; ++t) v[t] *= inv;
    }
    if (row < N) {
      #pragma unroll
      for (int t = 0; t < 4; ++t)
        out[(size_t)row * OUTn + t * 16 + m] = v[t];
    }
  }
}

// ---- fallback edge-op dispatcher ----------------------------------------
static void run_edge_fb(hipStream_t stream, const int* ei,
                        const float* sdot, const float* ddot, const float* hsrc,
                        float* outb, int Ndst,
                        unsigned* mbuf, float* sden, float* ebuf)
{
  hipMemsetAsync(mbuf, 0, (size_t)Ndst * 4 * sizeof(unsigned), stream);
  edge_logit_max<<<(En + 255) / 256, 256, 0, stream>>>(ei, sdot, ddot, mbuf);
  hipMemsetAsync(sden, 0, (size_t)Ndst * 4 * sizeof(float), stream);
  edge_exp_sum<<<(En + 255) / 256, 256, 0, stream>>>(ei, sdot, ddot, mbuf, sden, ebuf);
  hipMemsetAsync(outb, 0, (size_t)Ndst * HIDn * sizeof(float), stream);
  edge_scatter<<<((size_t)En * 64 + 255) / 256, 256, 0, stream>>>(ei, hsrc, ebuf, sden, outb);
  relu_k<<<((size_t)Ndst * HIDn + 255) / 256, 256, 0, stream>>>(outb, Ndst * HIDn);
}

extern "C" void kernel_launch(void* const* d_in, const int* in_sizes, int n_in,
                              void* d_out, int out_size, void* d_ws, size_t ws_size,
                              hipStream_t stream)
{
  const float* xc    = (const float*)d_in[0];
  const float* xd    = (const float*)d_in[1];
  const int*   ei_cc = (const int*)d_in[2];
  const int*   ei_dc = (const int*)d_in[3];
  const int*   ei_cd = (const int*)d_in[4];
  const float* W1c = (const float*)d_in[5];  const float* b1c = (const float*)d_in[6];
  const float* W1d = (const float*)d_in[7];  const float* b1d = (const float*)d_in[8];
  const float* a1s_cc = (const float*)d_in[9];  const float* a1d_cc = (const float*)d_in[10];
  const float* a1s_dc = (const float*)d_in[11]; const float* a1d_dc = (const float*)d_in[12];
  const float* a1s_cd = (const float*)d_in[13]; const float* a1d_cd = (const float*)d_in[14];
  const float* k1W = (const float*)d_in[15]; const float* k1b = (const float*)d_in[16];
  const float* q1  = (const float*)d_in[17];
  const float* W2c = (const float*)d_in[18]; const float* b2c = (const float*)d_in[19];
  const float* W2d = (const float*)d_in[20]; const float* b2d = (const float*)d_in[21];
  const float* a2s_cc = (const float*)d_in[22]; const float* a2d_cc = (const float*)d_in[23];
  const float* a2s_dc = (const float*)d_in[24]; const float* a2d_dc = (const float*)d_in[25];
  const float* a2s_cd = (const float*)d_in[26]; const float* a2d_cd = (const float*)d_in[27];
  const float* k2W = (const float*)d_in[28]; const float* k2b = (const float*)d_in[29];
  const float* q2  = (const float*)d_in[30];
  const float* pW  = (const float*)d_in[31]; const float* pb  = (const float*)d_in[32];

  // ---------------- workspace layout (fp32) ----------------
  float* ws = (float*)d_ws;
  const size_t NB = (size_t)NCn * HIDn;
  float* B0 = ws;            // h buffers (fp16 in CSR mode, fp32 in fallback)
  float* B1 = ws + NB;
  float* B2 = ws + 2 * NB;
  float* B3 = ws + 3 * NB;
  float* B4 = ws + 4 * NB;
  float* sml = ws + 5 * NB;
  float* scc = sml;
  float* dcc = sml + 200000;
  float* ddc = sml + 400000;
  float* scd = sml + 600000;
  float* sdc = sml + 800000;
  float* dcd = sml + 1000000;
  float* scoreB = sml + 1200000;
  float* R0 = sml + 1200016;
  int*  R0i = (int*)R0;
  int*  offsBase  = R0i;                                   // 150,012 ints
  int*  elistBase = R0i + 150012;                          // 1,200,000 ints
  int*  tmpBase   = R0i + 1350012;                         // 150,000 ints
  unsigned short* kW1t = (unsigned short*)(R0i + 1500012); // 16384 halves
  unsigned short* kW2t = (unsigned short*)(R0i + 1508204); // 16384 halves
  unsigned short* pWt  = (unsigned short*)(R0i + 1516396); // 8192 halves
  unsigned short* W1cH = (unsigned short*)(R0i + 1520492); // 32768 halves
  unsigned short* W1cL = (unsigned short*)(R0i + 1536876);
  unsigned short* W1dH = (unsigned short*)(R0i + 1553260);
  unsigned short* W1dL = (unsigned short*)(R0i + 1569644);
  unsigned short* W2cH = (unsigned short*)(R0i + 1586028); // 16384 halves
  unsigned short* W2cL = (unsigned short*)(R0i + 1594220);
  unsigned short* W2dH = (unsigned short*)(R0i + 1602412);
  unsigned short* W2dL = (unsigned short*)(R0i + 1610604); // end 1,618,796 ints
  // fallback temps overlay (over CSR region)
  unsigned* mbuf = (unsigned*)R0;
  float*    sden = R0 + 200000;
  float*    ebuf = R0 + 400000;

  const size_t REQ_FLOATS = 5 * NB + 1200016 + 1618796;    // 34,818,812 fl = 139.3 MB
  const bool useCsr = ws_size >= REQ_FLOATS * sizeof(float);

  if (useCsr) {
    hipMemsetAsync(tmpBase, 0, 150000 * sizeof(int), stream);
    hist3<<<(3 * En + 255) / 256, 256, 0, stream>>>(ei_cc, ei_dc, ei_cd, tmpBase);
    scan3<<<3, 1024, 0, stream>>>(tmpBase, offsBase);
    hipMemsetAsync(tmpBase, 0, 150000 * sizeof(int), stream);
    fill3<<<(3 * En + 255) / 256, 256, 0, stream>>>(ei_cc, ei_dc, ei_cd,
                                                    offsBase, tmpBase, elistBase);
  }
  // weight prep: bf16 transposes/splits
  wtrans<<<(128 * 128 + 255) / 256, 256, 0, stream>>>(k1W, kW1t, 128);
  wtrans<<<(128 * 128 + 255) / 256, 256, 0, stream>>>(k2W, kW2t, 128);
  wtrans<<<(128 * 64 + 255) / 256, 256, 0, stream>>>(pW, pWt, 64);
  wtrans_split<<<(256 * 128 + 255) / 256, 256, 0, stream>>>(W1c, W1cH, W1cL, 256);
  wtrans_split<<<(256 * 128 + 255) / 256, 256, 0, stream>>>(W1d, W1dH, W1dL, 256);
  wtrans_split<<<(128 * 128 + 255) / 256, 256, 0, stream>>>(W2c, W2cH, W2cL, 128);
  wtrans_split<<<(128 * 128 + 255) / 256, 256, 0, stream>>>(W2d, W2dH, W2dL, 128);

  hipMemsetAsync(scoreB, 0, 8 * sizeof(float), stream);

  const int NT64 = (NCn + 63) / 64;
  const int dotGrid = (NCn * 4 + 255) / 256;
  const int* offs0 = offsBase;
  const int* offs1 = offsBase + 50004;
  const int* offs2 = offsBase + 100008;
  const int* el0 = elistBase;
  const int* el1 = elistBase + En;
  const int* el2 = elistBase + 2 * (size_t)En;

  auto edge_layer = [&](void* hc, void* hd, float* oCC, float* oDC, float* oCD) {
    if (useCsr) {
      EdgeOp o0{offs0, el0, scc, dcc, (const __half*)hc, oCC};
      EdgeOp o1{offs1, el1, sdc, ddc, (const __half*)hd, oDC};
      EdgeOp o2{offs2, el2, scd, dcd, (const __half*)hc, oCD};
      csr_att3<<<dim3((NCn + 3) / 4, 3), 256, 0, stream>>>(o0, o1, o2, NCn);
    } else {
      run_edge_fb(stream, ei_cc, scc, dcc, (const float*)hc, oCC, NCn, mbuf, sden, ebuf);
      run_edge_fb(stream, ei_dc, sdc, ddc, (const float*)hd, oDC, NCn, mbuf, sden, ebuf);
      run_edge_fb(stream, ei_cd, scd, dcd, (const float*)hc, oCD, NDn, mbuf, sden, ebuf);
    }
  };

  if (useCsr) {
    // ---------------- layer 1 (MFMA gemm, h in fp16) ----------------
    gemm_mfma<256, 0, 1><<<NT64, 256, 0, stream>>>(xc, nullptr, nullptr, W1cH, W1cL, b1c, B0, NCn);
    gemm_mfma<256, 0, 1><<<NT64, 256, 0, stream>>>(xd, nullptr, nullptr, W1dH, W1dL, b1d, B1, NDn);
    dot6<1><<<dotGrid, 256, 0, stream>>>(B0, B1, a1s_cc, a1d_cc, a1s_dc, a1d_dc, a1s_cd, a1d_cd,
                                         scc, dcc, ddc, scd, sdc, dcd, NCn);
    edge_layer(B0, B1, B2, B3, B4);
    score_mfma<<<dim3(NT64, 2), 256, 0, stream>>>(B2, B3, kW1t, k1b, q1, NCn, scoreB);
    softmax2_kernel<<<1, 1, 0, stream>>>(scoreB);

    // ---------------- layer 2 ----------------
    gemm_mfma<128, 2, 1><<<NT64, 256, 0, stream>>>(B2, B3, scoreB, W2cH, W2cL, b2c, B0, NCn);
    gemm_mfma<128, 1, 1><<<NT64, 256, 0, stream>>>(B4, nullptr, nullptr, W2dH, W2dL, b2d, B1, NDn);
    dot6<1><<<dotGrid, 256, 0, stream>>>(B0, B1, a2s_cc, a2d_cc, a2s_dc, a2d_dc, a2s_cd, a2d_cd,
                                         scc, dcc, ddc, scd, sdc, dcd, NCn);
    edge_layer(B0, B1, B2, B3, B4);
    score_mfma<<<dim3(NT64, 2), 256, 0, stream>>>(B2, B3, kW2t, k2b, q2, NCn, scoreB + 4);
    softmax2_kernel<<<1, 1, 0, stream>>>(scoreB + 4);
  } else {
    // ---------------- fp32-h fallback ----------------
    gemm_mfma<256, 0, 0><<<NT64, 256, 0, stream>>>(xc, nullptr, nullptr, W1cH, W1cL, b1c, B0, NCn);
    gemm_mfma<256, 0, 0><<<NT64, 256, 0, stream>>>(xd, nullptr, nullptr, W1dH, W1dL, b1d, B1, NDn);
    dot6<0><<<dotGrid, 256, 0, stream>>>(B0, B1, a1s_cc, a1d_cc, a1s_dc, a1d_dc, a1s_cd, a1d_cd,
                                         scc, dcc, ddc, scd, sdc, dcd, NCn);
    edge_layer(B0, B1, B2, B3, B4);
    score_mfma<<<dim3(NT64, 2), 256, 0, stream>>>(B2, B3, kW1t, k1b, q1, NCn, scoreB);
    softmax2_kernel<<<1, 1, 0, stream>>>(scoreB);

    gemm_mfma<128, 2, 0><<<NT64, 256, 0, stream>>>(B2, B3, scoreB, W2cH, W2cL, b2c, B0, NCn);
    gemm_mfma<128, 1, 0><<<NT64, 256, 0, stream>>>(B4, nullptr, nullptr, W2dH, W2dL, b2d, B1, NDn);
    dot6<0><<<dotGrid, 256, 0, stream>>>(B0, B1, a2s_cc, a2d_cc, a2s_dc, a2d_dc, a2s_cd, a2d_cd,
                                         scc, dcc, ddc, scd, sdc, dcd, NCn);
    edge_layer(B0, B1, B2, B3, B4);
    score_mfma<<<dim3(NT64, 2), 256, 0, stream>>>(B2, B3, kW2t, k2b, q2, NCn, scoreB + 4);
    softmax2_kernel<<<1, 1, 0, stream>>>(scoreB + 4);
  }

  // ---------------- projection (+combine/elu fused, MFMA) ----------------
  proj_mfma<2, true ><<<NT64, 256, 0, stream>>>(B2, B3, scoreB + 4, pWt, pb, (float*)d_out, NCn);
  proj_mfma<1, false><<<NT64, 256, 0, stream>>>(B4, nullptr, nullptr, pWt, pb,
                                                (float*)d_out + (size_t)NCn * OUTn, NDn);
}

// Round 18
// 538.486 us; speedup vs baseline: 1.3573x; 1.1493x over previous
//
#include <hip/hip_runtime.h>
#include <hip/hip_fp16.h>
#include <cmath>

#define DEVI static __device__ __forceinline__

constexpr int HIDn = 128, OUTn = 64;
constexpr int NCn = 50000, NDn = 50000, En = 400000;
constexpr int SCAN_N = 150000, SCAN_BLK = 1024;
constexpr int SCAN_NB = (SCAN_N + SCAN_BLK - 1) / SCAN_BLK;   // 147

typedef __attribute__((ext_vector_type(8))) short bf16x8;
typedef __attribute__((ext_vector_type(4))) float f32x4;

// monotonic float->uint mapping for atomicMax on floats (handles signs)
DEVI unsigned fmap(float f) {
  int i = __float_as_int(f);
  return (i < 0) ? ~((unsigned)i) : (((unsigned)i) | 0x80000000u);
}
DEVI float fdecode(unsigned u) {
  int i = (u & 0x80000000u) ? (int)(u & 0x7fffffffu) : (int)(~u);
  return __int_as_float(i);
}

DEVI float tanh_fast(float x) {           // 1 - 2/(e^{2x}+1); saturates correctly
  float e = __expf(2.f * x);
  return 1.f - __fdividef(2.f, e + 1.f);
}

DEVI unsigned short f2bf(float x) {       // fp32 -> bf16 RNE
  unsigned u = __float_as_uint(x);
  return (unsigned short)((u + 0x7FFFu + ((u >> 16) & 1u)) >> 16);
}
DEVI float bf2f(unsigned short h) {
  unsigned u = ((unsigned)h) << 16;
  return __uint_as_float(u);
}

// ---- vectorized 8-wide A-row load + fused transform (value-based) -------
// MODE: 0=plain, 1=elu(x), 2=elu(w2*a+w3*b). HALF: input dtype fp16.
template<int MODE, int HALF>
DEVI void loadrow8(float* __restrict__ tmp,
                   const void* __restrict__ A, const void* __restrict__ A2,
                   float w2, float w3, size_t base)
{
  float v[8];
  if (HALF) {
    float4 raw = *(const float4*)((const __half*)A + base);
    const __half2* h2 = (const __half2*)&raw;
    #pragma unroll
    for (int j = 0; j < 4; ++j) {
      float2 f = __half22float2(h2[j]);
      v[2 * j] = f.x; v[2 * j + 1] = f.y;
    }
  } else {
    const float4* p = (const float4*)((const float*)A + base);
    float4 u0 = p[0], u1 = p[1];
    v[0] = u0.x; v[1] = u0.y; v[2] = u0.z; v[3] = u0.w;
    v[4] = u1.x; v[5] = u1.y; v[6] = u1.z; v[7] = u1.w;
  }
  if (MODE == 2) {
    float vb[8];
    if (HALF) {
      float4 raw = *(const float4*)((const __half*)A2 + base);
      const __half2* h2 = (const __half2*)&raw;
      #pragma unroll
      for (int j = 0; j < 4; ++j) {
        float2 f = __half22float2(h2[j]);
        vb[2 * j] = f.x; vb[2 * j + 1] = f.y;
      }
    } else {
      const float4* q = (const float4*)((const float*)A2 + base);
      float4 t0 = q[0], t1 = q[1];
      vb[0] = t0.x; vb[1] = t0.y; vb[2] = t0.z; vb[3] = t0.w;
      vb[4] = t1.x; vb[5] = t1.y; vb[6] = t1.z; vb[7] = t1.w;
    }
    #pragma unroll
    for (int i = 0; i < 8; ++i) v[i] = w2 * v[i] + w3 * vb[i];
  }
  if (MODE >= 1) {
    #pragma unroll
    for (int i = 0; i < 8; ++i) v[i] = (v[i] > 0.f) ? v[i] : (__expf(v[i]) - 1.f);
  }
  #pragma unroll
  for (int i = 0; i < 8; ++i) tmp[i] = v[i];
}

template<int MODE, int HALF>
DEVI bf16x8 packrow8(const void* __restrict__ A, const void* __restrict__ A2,
                     float w2, float w3, size_t base)
{
  float t[8];
  loadrow8<MODE, HALF>(t, A, A2, w2, w3, base);
  bf16x8 r;
  #pragma unroll
  for (int i = 0; i < 8; ++i) r[i] = (short)f2bf(t[i]);
  return r;
}

// ====== MFMA GEMM with LDS staging: C[N,128]=xform(A)@W + b ==============
// 4 waves, 64-row tile, K chunked by 32; 3-term hi/lo split (~fp32 acc).
template<int KI, int MODE, int IN16, int OUT16>
__global__ __launch_bounds__(256)
void gemm_mfma(const void* __restrict__ A, const void* __restrict__ A2,
               const float* __restrict__ wv,
               const unsigned short* __restrict__ Wh, const unsigned short* __restrict__ Wl,
               const float* __restrict__ bias, void* __restrict__ Cv, int N)
{
  __shared__ float As[64][36];
  __shared__ unsigned short Bh[128][40];
  __shared__ unsigned short Bl[128][40];
  float w2 = 0.f, w3 = 0.f;
  if (MODE == 2) { w2 = wv[2]; w3 = wv[3]; }
  const int tid = threadIdx.x;
  const int w = tid >> 6, lane = tid & 63;
  const int m = lane & 15, b4 = lane >> 4;
  const int row0 = blockIdx.x * 64;
  const int row0w = row0 + w * 16;

  f32x4 acc[8];
  #pragma unroll
  for (int t = 0; t < 8; ++t) acc[t] = (f32x4){0.f, 0.f, 0.f, 0.f};

  for (int k0 = 0; k0 < KI; k0 += 32) {
    {
      const int r = tid >> 2, kq = (tid & 3) << 3;
      const int row = row0 + r;
      float tmp[8];
      if (row < N) {
        loadrow8<MODE, IN16>(tmp, A, A2, w2, w3, (size_t)row * KI + k0 + kq);
      } else {
        #pragma unroll
        for (int i = 0; i < 8; ++i) tmp[i] = 0.f;
      }
      *(float4*)&As[r][kq]     = make_float4(tmp[0], tmp[1], tmp[2], tmp[3]);
      *(float4*)&As[r][kq + 4] = make_float4(tmp[4], tmp[5], tmp[6], tmp[7]);
    }
    {
      const int c = tid >> 1, kq = (tid & 1) << 4;
      const float4* ph = (const float4*)(Wh + (size_t)c * KI + k0 + kq);
      const float4* pl = (const float4*)(Wl + (size_t)c * KI + k0 + kq);
      *(float4*)&Bh[c][kq]     = ph[0];
      *(float4*)&Bh[c][kq + 8] = ph[1];
      *(float4*)&Bl[c][kq]     = pl[0];
      *(float4*)&Bl[c][kq + 8] = pl[1];
    }
    __syncthreads();

    bf16x8 ah, al;
    {
      const float* ap = &As[w * 16 + m][b4 * 8];
      float4 u0 = *(const float4*)ap;
      float4 u1 = *(const float4*)(ap + 4);
      float t8[8] = {u0.x, u0.y, u0.z, u0.w, u1.x, u1.y, u1.z, u1.w};
      #pragma unroll
      for (int i = 0; i < 8; ++i) {
        unsigned short h = f2bf(t8[i]);
        ah[i] = (short)h;
        al[i] = (short)f2bf(t8[i] - bf2f(h));
      }
    }
    #pragma unroll
    for (int t = 0; t < 8; ++t) {
      const int col = t * 16 + m;
      bf16x8 bh = *(const bf16x8*)&Bh[col][b4 * 8];
      bf16x8 bl = *(const bf16x8*)&Bl[col][b4 * 8];
      acc[t] = __builtin_amdgcn_mfma_f32_16x16x32_bf16(ah, bh, acc[t], 0, 0, 0);
      acc[t] = __builtin_amdgcn_mfma_f32_16x16x32_bf16(al, bh, acc[t], 0, 0, 0);
      acc[t] = __builtin_amdgcn_mfma_f32_16x16x32_bf16(ah, bl, acc[t], 0, 0, 0);
    }
    __syncthreads();
  }

  #pragma unroll
  for (int t = 0; t < 8; ++t) {
    const int col = t * 16 + m;
    const float bc = bias[col];
    #pragma unroll
    for (int r = 0; r < 4; ++r) {
      const int row = row0w + b4 * 4 + r;
      if (row < N) {
        float v = acc[t][r] + bc;
        if (OUT16) ((__half*)Cv)[(size_t)row * 128 + col] = __float2half(v);
        else       ((float*)Cv)[(size_t)row * 128 + col] = v;
      }
    }
  }
}

// ---- all six per-(node,head) attention dots (reads h, fp16 or fp32) -----
DEVI float dot4f(float4 a, float4 b) { return a.x*b.x + a.y*b.y + a.z*b.z + a.w*b.w; }

template<int HALF>
__global__ void dot6(const void* __restrict__ hc, const void* __restrict__ hd,
                     const float* __restrict__ ascc, const float* __restrict__ adcc,
                     const float* __restrict__ asdc, const float* __restrict__ addc,
                     const float* __restrict__ ascd, const float* __restrict__ adcd,
                     float* __restrict__ scc, float* __restrict__ dcc,
                     float* __restrict__ ddc, float* __restrict__ scd,
                     float* __restrict__ sdc, float* __restrict__ dcd, int N)
{
  int idx = blockIdx.x * blockDim.x + threadIdx.x;
  if (idx >= N * 4) return;
  int n = idx >> 2, hh = idx & 3;
  float hv[32], dv[32];
  #pragma unroll
  for (int i = 0; i < 4; ++i) {
    loadrow8<0, HALF>(hv + i * 8, hc, nullptr, 0.f, 0.f, (size_t)n * HIDn + hh * 32 + i * 8);
    loadrow8<0, HALF>(dv + i * 8, hd, nullptr, 0.f, 0.f, (size_t)n * HIDn + hh * 32 + i * 8);
  }
  const float4* a1 = (const float4*)(ascc + hh * 32);
  const float4* a2 = (const float4*)(adcc + hh * 32);
  const float4* a3 = (const float4*)(addc + hh * 32);
  const float4* a4 = (const float4*)(ascd + hh * 32);
  const float4* a5 = (const float4*)(asdc + hh * 32);
  const float4* a6 = (const float4*)(adcd + hh * 32);
  float s1 = 0, s2 = 0, s3 = 0, s4 = 0, t1 = 0, t2 = 0;
  #pragma unroll
  for (int i = 0; i < 8; ++i) {
    float4 hq = make_float4(hv[i*4], hv[i*4+1], hv[i*4+2], hv[i*4+3]);
    s1 += dot4f(hq, a1[i]);
    s2 += dot4f(hq, a2[i]);
    s3 += dot4f(hq, a3[i]);
    s4 += dot4f(hq, a4[i]);
    float4 dq = make_float4(dv[i*4], dv[i*4+1], dv[i*4+2], dv[i*4+3]);
    t1 += dot4f(dq, a5[i]);
    t2 += dot4f(dq, a6[i]);
  }
  scc[idx] = s1; dcc[idx] = s2; ddc[idx] = s3;
  scd[idx] = s4; sdc[idx] = t1; dcd[idx] = t2;
}

// ================= CSR build: hist + 3-pass scan + fill ==================
__global__ void hist3(const int* __restrict__ ei0, const int* __restrict__ ei1,
                      const int* __restrict__ ei2, int* __restrict__ deg)
{
  int gid = blockIdx.x * blockDim.x + threadIdx.x;
  if (gid >= 3 * En) return;
  int g = gid / En, e = gid - g * En;
  const int* ei = (g == 0) ? ei0 : (g == 1) ? ei1 : ei2;
  atomicAdd(&deg[g * 50000 + ei[En + e]], 1);
}

__global__ void scan_pass1(const int* __restrict__ deg, int* __restrict__ incl,
                           int* __restrict__ bsum)
{
  __shared__ int wsum[16];
  int tid = threadIdx.x;
  int gid = blockIdx.x * SCAN_BLK + tid;
  int v = (gid < SCAN_N) ? deg[gid] : 0;
  int lane = tid & 63, w = tid >> 6;
  int x = v;
  #pragma unroll
  for (int off = 1; off < 64; off <<= 1) {
    int y = __shfl_up(x, off);
    if (lane >= off) x += y;
  }
  if (lane == 63) wsum[w] = x;
  __syncthreads();
  if (tid == 0) {
    int s = 0;
    #pragma unroll
    for (int ww = 0; ww < 16; ++ww) { int t = wsum[ww]; wsum[ww] = s; s += t; }
    bsum[blockIdx.x] = s;
  }
  __syncthreads();
  x += wsum[w];
  if (gid < SCAN_N) incl[gid] = x;
}

__global__ void scan_pass2(int* __restrict__ bsum, int nb)
{
  __shared__ int wsum[16];
  int tid = threadIdx.x;
  int v = (tid < nb) ? bsum[tid] : 0;
  int lane = tid & 63, w = tid >> 6;
  int x = v;
  #pragma unroll
  for (int off = 1; off < 64; off <<= 1) {
    int y = __shfl_up(x, off);
    if (lane >= off) x += y;
  }
  if (lane == 63) wsum[w] = x;
  __syncthreads();
  if (tid == 0) {
    int s = 0;
    #pragma unroll
    for (int ww = 0; ww < 16; ++ww) { int t = wsum[ww]; wsum[ww] = s; s += t; }
  }
  __syncthreads();
  x += wsum[w];
  if (tid < nb) bsum[tid] = x - v;
}

__global__ void scan_pass3(const int* __restrict__ incl, const int* __restrict__ bsum,
                           int* __restrict__ offs)
{
  int gid = blockIdx.x * SCAN_BLK + threadIdx.x;
  if (gid == 0) offs[0] = 0;
  if (gid < SCAN_N) offs[gid + 1] = incl[gid] + bsum[gid / SCAN_BLK];
}

__global__ void fill3(const int* __restrict__ ei0, const int* __restrict__ ei1,
                      const int* __restrict__ ei2, const int* __restrict__ offs,
                      int* __restrict__ cursor, int* __restrict__ elist)
{
  int gid = blockIdx.x * blockDim.x + threadIdx.x;
  if (gid >= 3 * En) return;
  int g = gid / En, e = gid - g * En;
  const int* ei = (g == 0) ? ei0 : (g == 1) ? ei1 : ei2;
  int s = ei[e], d = g * 50000 + ei[En + e];
  int p = atomicAdd(&cursor[d], 1);
  elist[offs[d] + p] = s;
}

// ---- single weight-prep kernel: all transposes/casts/splits -------------
__global__ void wprep(const float* __restrict__ k1W, const float* __restrict__ k2W,
                      const float* __restrict__ pW,
                      const float* __restrict__ W1c, const float* __restrict__ W1d,
                      const float* __restrict__ W2c, const float* __restrict__ W2d,
                      unsigned short* kW1t, unsigned short* kW2t, unsigned short* pWt,
                      unsigned short* W1cH, unsigned short* W1cL,
                      unsigned short* W1dH, unsigned short* W1dL,
                      unsigned short* W2cH, unsigned short* W2cL,
                      unsigned short* W2dH, unsigned short* W2dL)
{
  int gid = blockIdx.x * 256 + threadIdx.x;
  if (gid < 16384) {
    int k = gid >> 7, c = gid & 127;
    kW1t[(size_t)c * 128 + k] = f2bf(k1W[gid]);
  } else if (gid < 32768) {
    int i = gid - 16384, k = i >> 7, c = i & 127;
    kW2t[(size_t)c * 128 + k] = f2bf(k2W[i]);
  } else if (gid < 40960) {
    int i = gid - 32768, k = i / 64, c = i - k * 64;
    pWt[(size_t)c * 128 + k] = f2bf(pW[i]);
  } else if (gid < 73728) {
    int i = gid - 40960, k = i >> 7, c = i & 127;
    float v = W1c[i]; unsigned short h = f2bf(v);
    W1cH[(size_t)c * 256 + k] = h;
    W1cL[(size_t)c * 256 + k] = f2bf(v - bf2f(h));
  } else if (gid < 106496) {
    int i = gid - 73728, k = i >> 7, c = i & 127;
    float v = W1d[i]; unsigned short h = f2bf(v);
    W1dH[(size_t)c * 256 + k] = h;
    W1dL[(size_t)c * 256 + k] = f2bf(v - bf2f(h));
  } else if (gid < 122880) {
    int i = gid - 106496, k = i >> 7, c = i & 127;
    float v = W2c[i]; unsigned short h = f2bf(v);
    W2cH[(size_t)c * 128 + k] = h;
    W2cL[(size_t)c * 128 + k] = f2bf(v - bf2f(h));
  } else if (gid < 139264) {
    int i = gid - 122880, k = i >> 7, c = i & 127;
    float v = W2d[i]; unsigned short h = f2bf(v);
    W2dH[(size_t)c * 128 + k] = h;
    W2dL[(size_t)c * 128 + k] = f2bf(v - bf2f(h));
  }
}

// ==== FUSED edge attention (CSR, fp16 h, lane-specialized softmax) =======
struct EdgeOp {
  const int* offs; const int* elist;
  const float* sdot; const float* ddot;
  const __half* hsrc; __half* out;
};

DEVI void csr_att_body(const EdgeOp& op, int dst, int lane)
{
  const int i0 = op.offs[dst], i1 = op.offs[dst + 1];
  const int hB = lane >> 4;
  const float ddv = op.ddot[dst * 4 + hB];
  const __half* hsrc = op.hsrc;
  const float* sdot = op.sdot;
  const int* el = op.elist;
  const int wsel = lane & 48;
  float den = 0.f, a0 = 0.f, a1 = 0.f;

  for (int base = i0; base < i1; base += 16) {
    int i = base + (lane & 15);
    int s_ = 0;
    float w = 0.f;
    if (i < i1) {
      s_ = el[i];
      float lv = sdot[s_ * 4 + hB] + ddv;
      lv = fminf(fmaxf(lv, 0.2f * lv), 80.f);
      w = __expf(lv);
    }
    float g = w;
    g += __shfl_xor(g, 1);
    g += __shfl_xor(g, 2);
    g += __shfl_xor(g, 4);
    g += __shfl_xor(g, 8);
    den += g;

    const int rem = min(16, i1 - base);
    int j = 0;
    for (; j + 2 <= rem; j += 2) {
      int sA = __shfl(s_, j);
      int sB = __shfl(s_, j + 1);
      float wA = __shfl(w, wsel | j);
      float wB = __shfl(w, wsel | (j + 1));
      float2 hA = __half22float2(*(const __half2*)(hsrc + (size_t)sA * HIDn + lane * 2));
      float2 hBv = __half22float2(*(const __half2*)(hsrc + (size_t)sB * HIDn + lane * 2));
      a0 += hA.x * wA + hBv.x * wB;
      a1 += hA.y * wA + hBv.y * wB;
    }
    if (j < rem) {
      int sA = __shfl(s_, j);
      float wA = __shfl(w, wsel | j);
      float2 hA = __half22float2(*(const __half2*)(hsrc + (size_t)sA * HIDn + lane * 2));
      a0 += hA.x * wA;
      a1 += hA.y * wA;
    }
  }
  float dinv = __fdividef(1.f, den + 1e-16f);
  __half2 o2 = __floats2half2_rn(fmaxf(a0 * dinv, 0.f), fmaxf(a1 * dinv, 0.f));
  *(__half2*)(op.out + (size_t)dst * HIDn + lane * 2) = o2;
}

__global__ __launch_bounds__(256)
void csr_att3(EdgeOp op0, EdgeOp op1, EdgeOp op2, int Ndst)
{
  int wave = (blockIdx.x * 256 + threadIdx.x) >> 6;
  if (wave >= Ndst) return;
  const int lane = threadIdx.x & 63;
  if (blockIdx.y == 0)      csr_att_body(op0, wave, lane);
  else if (blockIdx.y == 1) csr_att_body(op1, wave, lane);
  else                      csr_att_body(op2, wave, lane);
}

// ---- fallback path (atomic scatter, fp32 h), used only if ws too small --
__global__ void edge_logit_max(const int* __restrict__ ei,
                               const float* __restrict__ sdot,
                               const float* __restrict__ ddot,
                               unsigned* __restrict__ m)
{
  int e = blockIdx.x * blockDim.x + threadIdx.x;
  if (e >= En) return;
  int s = ei[e], d = ei[En + e];
  #pragma unroll
  for (int hh = 0; hh < 4; ++hh) {
    float l = sdot[s * 4 + hh] + ddot[d * 4 + hh];
    l = (l > 0.f) ? l : 0.2f * l;
    atomicMax(&m[d * 4 + hh], fmap(l));
  }
}

__global__ void edge_exp_sum(const int* __restrict__ ei,
                             const float* __restrict__ sdot,
                             const float* __restrict__ ddot,
                             const unsigned* __restrict__ m,
                             float* __restrict__ sden,
                             float* __restrict__ ebuf)
{
  int e = blockIdx.x * blockDim.x + threadIdx.x;
  if (e >= En) return;
  int s = ei[e], d = ei[En + e];
  #pragma unroll
  for (int hh = 0; hh < 4; ++hh) {
    float l = sdot[s * 4 + hh] + ddot[d * 4 + hh];
    l = (l > 0.f) ? l : 0.2f * l;
    float ex = expf(fminf(l - fdecode(m[d * 4 + hh]), 0.f));
    ebuf[e * 4 + hh] = ex;
    atomicAdd(&sden[d * 4 + hh], ex);
  }
}

__global__ __launch_bounds__(256)
void edge_scatter(const int* __restrict__ ei, const float* __restrict__ hsrc,
                  const float* __restrict__ ebuf, const float* __restrict__ sden,
                  float* __restrict__ out)
{
  int gid  = blockIdx.x * 256 + threadIdx.x;
  int e    = gid >> 6;
  if (e >= En) return;
  int lane = gid & 63;
  int s = ei[e], d = ei[En + e];
  #pragma unroll
  for (int half = 0; half < 2; ++half) {
    int c  = lane + half * 64;
    int hh = c >> 5;
    float alpha = ebuf[e * 4 + hh] / (sden[d * 4 + hh] + 1e-16f);
    atomicAdd(&out[(size_t)d * HIDn + c], hsrc[(size_t)s * HIDn + c] * alpha);
  }
}

__global__ void relu_k(float* __restrict__ x, int n)
{
  int i = blockIdx.x * blockDim.x + threadIdx.x;
  if (i < n) x[i] = fmaxf(x[i], 0.f);
}

// ---- semantic-attention score via MFMA bf16 -----------------------------
template<int IN16>
__global__ __launch_bounds__(256)
void score_mfma(const void* __restrict__ oA, const void* __restrict__ oB,
                const unsigned short* __restrict__ kWt,
                const float* __restrict__ kb, const float* __restrict__ q,
                int N, float* __restrict__ slots)
{
  __shared__ float partw[4];
  const void* o = blockIdx.y ? oB : oA;
  const int tid = threadIdx.x;
  const int w = tid >> 6, lane = tid & 63;
  const int row0 = (blockIdx.x * 4 + w) * 16;
  const int m = lane & 15, b = lane >> 4;
  const int arow = row0 + m;
  const bool rok = arow < N;

  const bf16x8 zfr = {0, 0, 0, 0, 0, 0, 0, 0};
  bf16x8 afr[4];
  {
    const size_t base = (size_t)arow * 128;
    #pragma unroll
    for (int ks = 0; ks < 4; ++ks) {
      if (rok) afr[ks] = packrow8<0, IN16>(o, nullptr, 0.f, 0.f, base + ks * 32 + b * 8);
      else     afr[ks] = zfr;
    }
  }

  float sum = 0.f;
  #pragma unroll
  for (int t = 0; t < 8; ++t) {
    f32x4 acc = {0.f, 0.f, 0.f, 0.f};
    const int col = t * 16 + m;
    const unsigned short* bp = kWt + (size_t)col * 128 + b * 8;
    #pragma unroll
    for (int ks = 0; ks < 4; ++ks)
      acc = __builtin_amdgcn_mfma_f32_16x16x32_bf16(afr[ks], *(const bf16x8*)(bp + ks * 32), acc, 0, 0, 0);
    const float qc = q[col], kbc = kb[col];
    #pragma unroll
    for (int r = 0; r < 4; ++r) {
      int row = row0 + b * 4 + r;
      if (row < N) sum += qc * tanh_fast(acc[r] + kbc);
    }
  }
  #pragma unroll
  for (int off = 32; off > 0; off >>= 1) sum += __shfl_down(sum, off);
  if (lane == 0) partw[w] = sum;
  __syncthreads();
  if (tid == 0)
    atomicAdd(&slots[blockIdx.y],
              (partw[0] + partw[1] + partw[2] + partw[3]) * (1.f / (float)N));
}

__global__ void softmax2_kernel(float* sb)   // sb[0],sb[1] -> weights sb[2],sb[3]
{
  float s0 = sb[0], s1 = sb[1];
  float mx = fmaxf(s0, s1);
  float e0 = expf(s0 - mx), e1 = expf(s1 - mx);
  float inv = 1.f / (e0 + e1);
  sb[2] = e0 * inv;
  sb[3] = e1 * inv;
}

// ---- final projection via MFMA bf16 (+ optional L2 norm) ----------------
template<int MODE, bool NORM, int IN16>
__global__ __launch_bounds__(256)
void proj_mfma(const void* __restrict__ fa, const void* __restrict__ fb,
               const float* __restrict__ wv,
               const unsigned short* __restrict__ pWt, const float* __restrict__ pb,
               float* __restrict__ out, int N)
{
  float w2 = 0.f, w3 = 0.f;
  if (MODE == 2) { w2 = wv[2]; w3 = wv[3]; }
  const int tid = threadIdx.x;
  const int w = tid >> 6, lane = tid & 63;
  const int row0 = (blockIdx.x * 4 + w) * 16;
  const int m = lane & 15, b = lane >> 4;
  const int arow = row0 + m;
  const bool rok = arow < N;

  const bf16x8 zfr = {0, 0, 0, 0, 0, 0, 0, 0};
  bf16x8 afr[4];
  {
    const size_t base = (size_t)arow * 128;
    #pragma unroll
    for (int ks = 0; ks < 4; ++ks) {
      if (rok) afr[ks] = packrow8<MODE, IN16>(fa, fb, w2, w3, base + ks * 32 + b * 8);
      else     afr[ks] = zfr;
    }
  }

  f32x4 accs[4];
  float pbc[4];
  #pragma unroll
  for (int t = 0; t < 4; ++t) {
    f32x4 acc = {0.f, 0.f, 0.f, 0.f};
    const int col = t * 16 + m;
    const unsigned short* bp = pWt + (size_t)col * 128 + b * 8;
    #pragma unroll
    for (int ks = 0; ks < 4; ++ks)
      acc = __builtin_amdgcn_mfma_f32_16x16x32_bf16(afr[ks], *(const bf16x8*)(bp + ks * 32), acc, 0, 0, 0);
    accs[t] = acc;
    pbc[t] = pb[col];
  }

  #pragma unroll
  for (int r = 0; r < 4; ++r) {
    const int row = row0 + b * 4 + r;
    float v[4];
    #pragma unroll
    for (int t = 0; t < 4; ++t) v[t] = accs[t][r] + pbc[t];
    if (NORM) {
      float ss = v[0]*v[0] + v[1]*v[1] + v[2]*v[2] + v[3]*v[3];
      ss += __shfl_xor(ss, 1);
      ss += __shfl_xor(ss, 2);
      ss += __shfl_xor(ss, 4);
      ss += __shfl_xor(ss, 8);
      float inv = 1.f / fmaxf(sqrtf(ss), 1e-12f);
      #pragma unroll
      for (int t = 0; t < 4; ++t) v[t] *= inv;
    }
    if (row < N) {
      #pragma unroll
      for (int t = 0; t < 4; ++t)
        out[(size_t)row * OUTn + t * 16 + m] = v[t];
    }
  }
}

// ---- fallback edge-op dispatcher ----------------------------------------
static void run_edge_fb(hipStream_t stream, const int* ei,
                        const float* sdot, const float* ddot, const float* hsrc,
                        float* outb, int Ndst,
                        unsigned* mbuf, float* sden, float* ebuf)
{
  hipMemsetAsync(mbuf, 0, (size_t)Ndst * 4 * sizeof(unsigned), stream);
  edge_logit_max<<<(En + 255) / 256, 256, 0, stream>>>(ei, sdot, ddot, mbuf);
  hipMemsetAsync(sden, 0, (size_t)Ndst * 4 * sizeof(float), stream);
  edge_exp_sum<<<(En + 255) / 256, 256, 0, stream>>>(ei, sdot, ddot, mbuf, sden, ebuf);
  hipMemsetAsync(outb, 0, (size_t)Ndst * HIDn * sizeof(float), stream);
  edge_scatter<<<((size_t)En * 64 + 255) / 256, 256, 0, stream>>>(ei, hsrc, ebuf, sden, outb);
  relu_k<<<((size_t)Ndst * HIDn + 255) / 256, 256, 0, stream>>>(outb, Ndst * HIDn);
}

extern "C" void kernel_launch(void* const* d_in, const int* in_sizes, int n_in,
                              void* d_out, int out_size, void* d_ws, size_t ws_size,
                              hipStream_t stream)
{
  const float* xc    = (const float*)d_in[0];
  const float* xd    = (const float*)d_in[1];
  const int*   ei_cc = (const int*)d_in[2];
  const int*   ei_dc = (const int*)d_in[3];
  const int*   ei_cd = (const int*)d_in[4];
  const float* W1c = (const float*)d_in[5];  const float* b1c = (const float*)d_in[6];
  const float* W1d = (const float*)d_in[7];  const float* b1d = (const float*)d_in[8];
  const float* a1s_cc = (const float*)d_in[9];  const float* a1d_cc = (const float*)d_in[10];
  const float* a1s_dc = (const float*)d_in[11]; const float* a1d_dc = (const float*)d_in[12];
  const float* a1s_cd = (const float*)d_in[13]; const float* a1d_cd = (const float*)d_in[14];
  const float* k1W = (const float*)d_in[15]; const float* k1b = (const float*)d_in[16];
  const float* q1  = (const float*)d_in[17];
  const float* W2c = (const float*)d_in[18]; const float* b2c = (const float*)d_in[19];
  const float* W2d = (const float*)d_in[20]; const float* b2d = (const float*)d_in[21];
  const float* a2s_cc = (const float*)d_in[22]; const float* a2d_cc = (const float*)d_in[23];
  const float* a2s_dc = (const float*)d_in[24]; const float* a2d_dc = (const float*)d_in[25];
  const float* a2s_cd = (const float*)d_in[26]; const float* a2d_cd = (const float*)d_in[27];
  const float* k2W = (const float*)d_in[28]; const float* k2b = (const float*)d_in[29];
  const float* q2  = (const float*)d_in[30];
  const float* pW  = (const float*)d_in[31]; const float* pb  = (const float*)d_in[32];

  // ---------------- workspace layout ----------------
  float* ws = (float*)d_ws;
  const size_t NB = (size_t)NCn * HIDn;
  float* B0 = ws;            // node buffers (fp16 in CSR mode, fp32 fallback)
  float* B1 = ws + NB;
  float* B2 = ws + 2 * NB;
  float* B3 = ws + 3 * NB;
  float* B4 = ws + 4 * NB;
  float* sml = ws + 5 * NB;
  float* scc = sml;
  float* dcc = sml + 200000;
  float* ddc = sml + 400000;
  float* scd = sml + 600000;
  float* sdc = sml + 800000;
  float* dcd = sml + 1000000;
  float* scoreB = sml + 1200000;
  float* R0 = sml + 1200016;
  int*  R0i = (int*)R0;
  int*  offsBase  = R0i;                   // 150,004 ints (global offs)
  int*  elistBase = R0i + 150004;          // 1,200,000 ints (combined)
  int*  degBase   = R0i + 1350004;         // 150,000
  int*  cursorBase= R0i + 1500004;         // 150,000 (adjacent -> single memset)
  int*  inclBase  = R0i + 1650004;         // 150,000
  int*  bsumBase  = R0i + 1800004;         // 1,024
  unsigned short* kW1t = (unsigned short*)(R0i + 1801028);
  unsigned short* kW2t = (unsigned short*)(R0i + 1809220);
  unsigned short* pWt  = (unsigned short*)(R0i + 1817412);
  unsigned short* W1cH = (unsigned short*)(R0i + 1821508);
  unsigned short* W1cL = (unsigned short*)(R0i + 1837892);
  unsigned short* W1dH = (unsigned short*)(R0i + 1854276);
  unsigned short* W1dL = (unsigned short*)(R0i + 1870660);
  unsigned short* W2cH = (unsigned short*)(R0i + 1887044);
  unsigned short* W2cL = (unsigned short*)(R0i + 1895236);
  unsigned short* W2dH = (unsigned short*)(R0i + 1903428);
  unsigned short* W2dL = (unsigned short*)(R0i + 1911620);  // end 1,919,812 ints
  // fallback temps overlay (over CSR region)
  unsigned* mbuf = (unsigned*)R0;
  float*    sden = R0 + 200000;
  float*    ebuf = R0 + 400000;

  const size_t REQ_FLOATS = 5 * NB + 1200016 + 1919812;     // 35,119,828 fl = 140.5 MB
  const bool useCsr = ws_size >= REQ_FLOATS * sizeof(float);

  if (useCsr) {
    hipMemsetAsync(degBase, 0, 300000 * sizeof(int), stream);   // deg + cursor
    hist3<<<(3 * En + 255) / 256, 256, 0, stream>>>(ei_cc, ei_dc, ei_cd, degBase);
    scan_pass1<<<SCAN_NB, SCAN_BLK, 0, stream>>>(degBase, inclBase, bsumBase);
    scan_pass2<<<1, SCAN_BLK, 0, stream>>>(bsumBase, SCAN_NB);
    scan_pass3<<<SCAN_NB, SCAN_BLK, 0, stream>>>(inclBase, bsumBase, offsBase);
    fill3<<<(3 * En + 255) / 256, 256, 0, stream>>>(ei_cc, ei_dc, ei_cd,
                                                    offsBase, cursorBase, elistBase);
  }
  wprep<<<(139264 + 255) / 256, 256, 0, stream>>>(k1W, k2W, pW, W1c, W1d, W2c, W2d,
                                                  kW1t, kW2t, pWt,
                                                  W1cH, W1cL, W1dH, W1dL,
                                                  W2cH, W2cL, W2dH, W2dL);

  hipMemsetAsync(scoreB, 0, 8 * sizeof(float), stream);

  const int NT64 = (NCn + 63) / 64;
  const int dotGrid = (NCn * 4 + 255) / 256;
  const int* offs0 = offsBase;
  const int* offs1 = offsBase + 50000;
  const int* offs2 = offsBase + 100000;

  auto edge_layer = [&](void* hc, void* hd, void* oCC, void* oDC, void* oCD) {
    if (useCsr) {
      EdgeOp o0{offs0, elistBase, scc, dcc, (const __half*)hc, (__half*)oCC};
      EdgeOp o1{offs1, elistBase, sdc, ddc, (const __half*)hd, (__half*)oDC};
      EdgeOp o2{offs2, elistBase, scd, dcd, (const __half*)hc, (__half*)oCD};
      csr_att3<<<dim3((NCn + 3) / 4, 3), 256, 0, stream>>>(o0, o1, o2, NCn);
    } else {
      run_edge_fb(stream, ei_cc, scc, dcc, (const float*)hc, (float*)oCC, NCn, mbuf, sden, ebuf);
      run_edge_fb(stream, ei_dc, sdc, ddc, (const float*)hd, (float*)oDC, NCn, mbuf, sden, ebuf);
      run_edge_fb(stream, ei_cd, scd, dcd, (const float*)hc, (float*)oCD, NDn, mbuf, sden, ebuf);
    }
  };

  if (useCsr) {
    // ---------------- layer 1 (all node buffers fp16) ----------------
    gemm_mfma<256, 0, 0, 1><<<NT64, 256, 0, stream>>>(xc, nullptr, nullptr, W1cH, W1cL, b1c, B0, NCn);
    gemm_mfma<256, 0, 0, 1><<<NT64, 256, 0, stream>>>(xd, nullptr, nullptr, W1dH, W1dL, b1d, B1, NDn);
    dot6<1><<<dotGrid, 256, 0, stream>>>(B0, B1, a1s_cc, a1d_cc, a1s_dc, a1d_dc, a1s_cd, a1d_cd,
                                         scc, dcc, ddc, scd, sdc, dcd, NCn);
    edge_layer(B0, B1, B2, B3, B4);
    score_mfma<1><<<dim3(NT64, 2), 256, 0, stream>>>(B2, B3, kW1t, k1b, q1, NCn, scoreB);
    softmax2_kernel<<<1, 1, 0, stream>>>(scoreB);

    // ---------------- layer 2 ----------------
    gemm_mfma<128, 2, 1, 1><<<NT64, 256, 0, stream>>>(B2, B3, scoreB, W2cH, W2cL, b2c, B0, NCn);
    gemm_mfma<128, 1, 1, 1><<<NT64, 256, 0, stream>>>(B4, nullptr, nullptr, W2dH, W2dL, b2d, B1, NDn);
    dot6<1><<<dotGrid, 256, 0, stream>>>(B0, B1, a2s_cc, a2d_cc, a2s_dc, a2d_dc, a2s_cd, a2d_cd,
                                         scc, dcc, ddc, scd, sdc, dcd, NCn);
    edge_layer(B0, B1, B2, B3, B4);
    score_mfma<1><<<dim3(NT64, 2), 256, 0, stream>>>(B2, B3, kW2t, k2b, q2, NCn, scoreB + 4);
    softmax2_kernel<<<1, 1, 0, stream>>>(scoreB + 4);

    // ---------------- projection ----------------
    proj_mfma<2, true , 1><<<NT64, 256, 0, stream>>>(B2, B3, scoreB + 4, pWt, pb, (float*)d_out, NCn);
    proj_mfma<1, false, 1><<<NT64, 256, 0, stream>>>(B4, nullptr, nullptr, pWt, pb,
                                                     (float*)d_out + (size_t)NCn * OUTn, NDn);
  } else {
    // ---------------- fp32 fallback ----------------
    gemm_mfma<256, 0, 0, 0><<<NT64, 256, 0, stream>>>(xc, nullptr, nullptr, W1cH, W1cL, b1c, B0, NCn);
    gemm_mfma<256, 0, 0, 0><<<NT64, 256, 0, stream>>>(xd, nullptr, nullptr, W1dH, W1dL, b1d, B1, NDn);
    dot6<0><<<dotGrid, 256, 0, stream>>>(B0, B1, a1s_cc, a1d_cc, a1s_dc, a1d_dc, a1s_cd, a1d_cd,
                                         scc, dcc, ddc, scd, sdc, dcd, NCn);
    edge_layer(B0, B1, B2, B3, B4);
    score_mfma<0><<<dim3(NT64, 2), 256, 0, stream>>>(B2, B3, kW1t, k1b, q1, NCn, scoreB);
    softmax2_kernel<<<1, 1, 0, stream>>>(scoreB);

    gemm_mfma<128, 2, 0, 0><<<NT64, 256, 0, stream>>>(B2, B3, scoreB, W2cH, W2cL, b2c, B0, NCn);
    gemm_mfma<128, 1, 0, 0><<<NT64, 256, 0, stream>>>(B4, nullptr, nullptr, W2dH, W2dL, b2d, B1, NDn);
    dot6<0><<<dotGrid, 256, 0, stream>>>(B0, B1, a2s_cc, a2d_cc, a2s_dc, a2d_dc, a2s_cd, a2d_cd,
                                         scc, dcc, ddc, scd, sdc, dcd, NCn);
    edge_layer(B0, B1, B2, B3, B4);
    score_mfma<0><<<dim3(NT64, 2), 256, 0, stream>>>(B2, B3, kW2t, k2b, q2, NCn, scoreB + 4);
    softmax2_kernel<<<1, 1, 0, stream>>>(scoreB + 4);

    proj_mfma<2, true , 0><<<NT64, 256, 0, stream>>>(B2, B3, scoreB + 4, pWt, pb, (float*)d_out, NCn);
    proj_mfma<1, false, 0><<<NT64, 256, 0, stream>>>(B4, nullptr, nullptr, pWt, pb,
                                                     (float*)d_out + (size_t)NCn * OUTn, NDn);
  }
}

// Round 19
// 506.063 us; speedup vs baseline: 1.4442x; 1.0641x over previous
//
#include <hip/hip_runtime.h>
#include <hip/hip_fp16.h>
#include <cmath>

#define DEVI static __device__ __forceinline__

constexpr int HIDn = 128, OUTn = 64;
constexpr int NCn = 50000, NDn = 50000, En = 400000;
constexpr int SCAN_N = 150000, SCAN_BLK = 1024;
constexpr int SCAN_NB = (SCAN_N + SCAN_BLK - 1) / SCAN_BLK;   // 147

typedef __attribute__((ext_vector_type(8))) short bf16x8;
typedef __attribute__((ext_vector_type(4))) float f32x4;

// monotonic float->uint mapping for atomicMax on floats (handles signs)
DEVI unsigned fmap(float f) {
  int i = __float_as_int(f);
  return (i < 0) ? ~((unsigned)i) : (((unsigned)i) | 0x80000000u);
}
DEVI float fdecode(unsigned u) {
  int i = (u & 0x80000000u) ? (int)(u & 0x7fffffffu) : (int)(~u);
  return __int_as_float(i);
}

DEVI float tanh_fast(float x) {           // 1 - 2/(e^{2x}+1); saturates correctly
  float e = __expf(2.f * x);
  return 1.f - __fdividef(2.f, e + 1.f);
}

DEVI unsigned short f2bf(float x) {       // fp32 -> bf16 RNE
  unsigned u = __float_as_uint(x);
  return (unsigned short)((u + 0x7FFFu + ((u >> 16) & 1u)) >> 16);
}
DEVI float bf2f(unsigned short h) {
  unsigned u = ((unsigned)h) << 16;
  return __uint_as_float(u);
}

// ---- vectorized 8-wide A-row load + fused transform (value-based) -------
// MODE: 0=plain, 1=elu(x), 2=elu(w2*a+w3*b). HALF: input dtype fp16.
template<int MODE, int HALF>
DEVI void loadrow8(float* __restrict__ tmp,
                   const void* __restrict__ A, const void* __restrict__ A2,
                   float w2, float w3, size_t base)
{
  float v[8];
  if (HALF) {
    float4 raw = *(const float4*)((const __half*)A + base);
    const __half2* h2 = (const __half2*)&raw;
    #pragma unroll
    for (int j = 0; j < 4; ++j) {
      float2 f = __half22float2(h2[j]);
      v[2 * j] = f.x; v[2 * j + 1] = f.y;
    }
  } else {
    const float4* p = (const float4*)((const float*)A + base);
    float4 u0 = p[0], u1 = p[1];
    v[0] = u0.x; v[1] = u0.y; v[2] = u0.z; v[3] = u0.w;
    v[4] = u1.x; v[5] = u1.y; v[6] = u1.z; v[7] = u1.w;
  }
  if (MODE == 2) {
    float vb[8];
    if (HALF) {
      float4 raw = *(const float4*)((const __half*)A2 + base);
      const __half2* h2 = (const __half2*)&raw;
      #pragma unroll
      for (int j = 0; j < 4; ++j) {
        float2 f = __half22float2(h2[j]);
        vb[2 * j] = f.x; vb[2 * j + 1] = f.y;
      }
    } else {
      const float4* q = (const float4*)((const float*)A2 + base);
      float4 t0 = q[0], t1 = q[1];
      vb[0] = t0.x; vb[1] = t0.y; vb[2] = t0.z; vb[3] = t0.w;
      vb[4] = t1.x; vb[5] = t1.y; vb[6] = t1.z; vb[7] = t1.w;
    }
    #pragma unroll
    for (int i = 0; i < 8; ++i) v[i] = w2 * v[i] + w3 * vb[i];
  }
  if (MODE >= 1) {
    #pragma unroll
    for (int i = 0; i < 8; ++i) v[i] = (v[i] > 0.f) ? v[i] : (__expf(v[i]) - 1.f);
  }
  #pragma unroll
  for (int i = 0; i < 8; ++i) tmp[i] = v[i];
}

template<int MODE, int HALF>
DEVI bf16x8 packrow8(const void* __restrict__ A, const void* __restrict__ A2,
                     float w2, float w3, size_t base)
{
  float t[8];
  loadrow8<MODE, HALF>(t, A, A2, w2, w3, base);
  bf16x8 r;
  #pragma unroll
  for (int i = 0; i < 8; ++i) r[i] = (short)f2bf(t[i]);
  return r;
}

// ====== merged MFMA GEMM (c & d paths) + fused attention dots ============
// grid (ceil(N/64), 2). y=0: xform<MODEc>(Ac[,Ac2]) @ Wc -> Cc, 4 dots.
//                       y=1: xform<MODEd>(Ad) @ Wd -> Cd, 2 dots.
// LDS-staged, 3-term hi/lo bf16 split (~fp32 accuracy).
template<int KI, int MODEc, int MODEd, int IN16, int OUT16>
__global__ __launch_bounds__(256)
void gemm2_mfma(const void* __restrict__ Ac, const void* __restrict__ Ac2,
                const float* __restrict__ wv,
                const unsigned short* __restrict__ WcH, const unsigned short* __restrict__ WcL,
                const float* __restrict__ bc, void* __restrict__ Cc,
                const void* __restrict__ Ad,
                const unsigned short* __restrict__ WdH, const unsigned short* __restrict__ WdL,
                const float* __restrict__ bd, void* __restrict__ Cd,
                int N,
                const float* __restrict__ avc0, const float* __restrict__ avc1,
                const float* __restrict__ avc2, const float* __restrict__ avc3,
                const float* __restrict__ avd0, const float* __restrict__ avd1,
                float* __restrict__ doc0, float* __restrict__ doc1,
                float* __restrict__ doc2, float* __restrict__ doc3,
                float* __restrict__ dod0, float* __restrict__ dod1)
{
  __shared__ float As[64][36];
  __shared__ unsigned short Bh[128][40];
  __shared__ unsigned short Bl[128][40];
  const bool isC = (blockIdx.y == 0);
  const void* A  = isC ? Ac : Ad;
  const void* A2 = isC ? Ac2 : nullptr;
  const unsigned short* Wh = isC ? WcH : WdH;
  const unsigned short* Wl = isC ? WcL : WdL;
  const float* bias = isC ? bc : bd;
  void* Cv = isC ? Cc : Cd;
  float w2 = 0.f, w3 = 0.f;
  if (MODEc == 2) { if (isC) { w2 = wv[2]; w3 = wv[3]; } }

  const int tid = threadIdx.x;
  const int w = tid >> 6, lane = tid & 63;
  const int m = lane & 15, b4 = lane >> 4;
  const int row0 = blockIdx.x * 64;
  const int row0w = row0 + w * 16;

  f32x4 acc[8];
  #pragma unroll
  for (int t = 0; t < 8; ++t) acc[t] = (f32x4){0.f, 0.f, 0.f, 0.f};

  for (int k0 = 0; k0 < KI; k0 += 32) {
    {
      const int r = tid >> 2, kq = (tid & 3) << 3;
      const int row = row0 + r;
      float tmp[8];
      if (row < N) {
        if (isC) loadrow8<MODEc, IN16>(tmp, A, A2, w2, w3, (size_t)row * KI + k0 + kq);
        else     loadrow8<MODEd, IN16>(tmp, A, nullptr, 0.f, 0.f, (size_t)row * KI + k0 + kq);
      } else {
        #pragma unroll
        for (int i = 0; i < 8; ++i) tmp[i] = 0.f;
      }
      *(float4*)&As[r][kq]     = make_float4(tmp[0], tmp[1], tmp[2], tmp[3]);
      *(float4*)&As[r][kq + 4] = make_float4(tmp[4], tmp[5], tmp[6], tmp[7]);
    }
    {
      const int c = tid >> 1, kq = (tid & 1) << 4;
      const float4* ph = (const float4*)(Wh + (size_t)c * KI + k0 + kq);
      const float4* pl = (const float4*)(Wl + (size_t)c * KI + k0 + kq);
      *(float4*)&Bh[c][kq]     = ph[0];
      *(float4*)&Bh[c][kq + 8] = ph[1];
      *(float4*)&Bl[c][kq]     = pl[0];
      *(float4*)&Bl[c][kq + 8] = pl[1];
    }
    __syncthreads();

    bf16x8 ah, al;
    {
      const float* ap = &As[w * 16 + m][b4 * 8];
      float4 u0 = *(const float4*)ap;
      float4 u1 = *(const float4*)(ap + 4);
      float t8[8] = {u0.x, u0.y, u0.z, u0.w, u1.x, u1.y, u1.z, u1.w};
      #pragma unroll
      for (int i = 0; i < 8; ++i) {
        unsigned short h = f2bf(t8[i]);
        ah[i] = (short)h;
        al[i] = (short)f2bf(t8[i] - bf2f(h));
      }
    }
    #pragma unroll
    for (int t = 0; t < 8; ++t) {
      const int col = t * 16 + m;
      bf16x8 bh = *(const bf16x8*)&Bh[col][b4 * 8];
      bf16x8 bl = *(const bf16x8*)&Bl[col][b4 * 8];
      acc[t] = __builtin_amdgcn_mfma_f32_16x16x32_bf16(ah, bh, acc[t], 0, 0, 0);
      acc[t] = __builtin_amdgcn_mfma_f32_16x16x32_bf16(al, bh, acc[t], 0, 0, 0);
      acc[t] = __builtin_amdgcn_mfma_f32_16x16x32_bf16(ah, bl, acc[t], 0, 0, 0);
    }
    __syncthreads();
  }

  // ---- epilogue: bias + C store ----
  float bt[8];
  #pragma unroll
  for (int t = 0; t < 8; ++t) bt[t] = bias[t * 16 + m];

  #pragma unroll
  for (int t = 0; t < 8; ++t) {
    const int col = t * 16 + m;
    #pragma unroll
    for (int r = 0; r < 4; ++r) {
      const int row = row0w + b4 * 4 + r;
      if (row < N) {
        float v = acc[t][r] + bt[t];
        if (OUT16) ((__half*)Cv)[(size_t)row * 128 + col] = __float2half(v);
        else       ((float*)Cv)[(size_t)row * 128 + col] = v;
      }
    }
  }

  // ---- fused attention dots: per (row, head) reduce over 16 m-lanes ----
  const float* avp[4];
  float* dop[4];
  int nv;
  if (isC) {
    avp[0] = avc0; avp[1] = avc1; avp[2] = avc2; avp[3] = avc3;
    dop[0] = doc0; dop[1] = doc1; dop[2] = doc2; dop[3] = doc3; nv = 4;
  } else {
    avp[0] = avd0; avp[1] = avd1; avp[2] = avd0; avp[3] = avd1;
    dop[0] = dod0; dop[1] = dod1; dop[2] = dod0; dop[3] = dod1; nv = 2;
  }
  float avv[4][8];
  #pragma unroll
  for (int v = 0; v < 4; ++v) {
    if (v < nv) {
      #pragma unroll
      for (int t = 0; t < 8; ++t) avv[v][t] = avp[v][t * 16 + m];
    }
  }
  #pragma unroll
  for (int h = 0; h < 4; ++h) {
    #pragma unroll
    for (int v = 0; v < 4; ++v) {
      if (v < nv) {
        #pragma unroll
        for (int r = 0; r < 4; ++r) {
          float p = (acc[2 * h][r] + bt[2 * h]) * avv[v][2 * h]
                  + (acc[2 * h + 1][r] + bt[2 * h + 1]) * avv[v][2 * h + 1];
          p += __shfl_xor(p, 1);
          p += __shfl_xor(p, 2);
          p += __shfl_xor(p, 4);
          p += __shfl_xor(p, 8);
          if (m == 0) {
            const int row = row0w + b4 * 4 + r;
            if (row < N) dop[v][(size_t)row * 4 + h] = p;
          }
        }
      }
    }
  }
}

// ================= CSR build: hist + 3-pass scan + fill ==================
__global__ void hist3(const int* __restrict__ ei0, const int* __restrict__ ei1,
                      const int* __restrict__ ei2, int* __restrict__ deg)
{
  int gid = blockIdx.x * blockDim.x + threadIdx.x;
  if (gid >= 3 * En) return;
  int g = gid / En, e = gid - g * En;
  const int* ei = (g == 0) ? ei0 : (g == 1) ? ei1 : ei2;
  atomicAdd(&deg[g * 50000 + ei[En + e]], 1);
}

__global__ void scan_pass1(const int* __restrict__ deg, int* __restrict__ incl,
                           int* __restrict__ bsum)
{
  __shared__ int wsum[16];
  int tid = threadIdx.x;
  int gid = blockIdx.x * SCAN_BLK + tid;
  int v = (gid < SCAN_N) ? deg[gid] : 0;
  int lane = tid & 63, w = tid >> 6;
  int x = v;
  #pragma unroll
  for (int off = 1; off < 64; off <<= 1) {
    int y = __shfl_up(x, off);
    if (lane >= off) x += y;
  }
  if (lane == 63) wsum[w] = x;
  __syncthreads();
  if (tid == 0) {
    int s = 0;
    #pragma unroll
    for (int ww = 0; ww < 16; ++ww) { int t = wsum[ww]; wsum[ww] = s; s += t; }
    bsum[blockIdx.x] = s;
  }
  __syncthreads();
  x += wsum[w];
  if (gid < SCAN_N) incl[gid] = x;
}

__global__ void scan_pass2(int* __restrict__ bsum, int nb)
{
  __shared__ int wsum[16];
  int tid = threadIdx.x;
  int v = (tid < nb) ? bsum[tid] : 0;
  int lane = tid & 63, w = tid >> 6;
  int x = v;
  #pragma unroll
  for (int off = 1; off < 64; off <<= 1) {
    int y = __shfl_up(x, off);
    if (lane >= off) x += y;
  }
  if (lane == 63) wsum[w] = x;
  __syncthreads();
  if (tid == 0) {
    int s = 0;
    #pragma unroll
    for (int ww = 0; ww < 16; ++ww) { int t = wsum[ww]; wsum[ww] = s; s += t; }
  }
  __syncthreads();
  x += wsum[w];
  if (tid < nb) bsum[tid] = x - v;
}

__global__ void scan_pass3(const int* __restrict__ incl, const int* __restrict__ bsum,
                           int* __restrict__ offs)
{
  int gid = blockIdx.x * SCAN_BLK + threadIdx.x;
  if (gid == 0) offs[0] = 0;
  if (gid < SCAN_N) offs[gid + 1] = incl[gid] + bsum[gid / SCAN_BLK];
}

__global__ void fill3(const int* __restrict__ ei0, const int* __restrict__ ei1,
                      const int* __restrict__ ei2, const int* __restrict__ offs,
                      int* __restrict__ cursor, int* __restrict__ elist)
{
  int gid = blockIdx.x * blockDim.x + threadIdx.x;
  if (gid >= 3 * En) return;
  int g = gid / En, e = gid - g * En;
  const int* ei = (g == 0) ? ei0 : (g == 1) ? ei1 : ei2;
  int s = ei[e], d = g * 50000 + ei[En + e];
  int p = atomicAdd(&cursor[d], 1);
  elist[offs[d] + p] = s;
}

// ---- single weight-prep kernel: all transposes/casts/splits -------------
__global__ void wprep(const float* __restrict__ k1W, const float* __restrict__ k2W,
                      const float* __restrict__ pW,
                      const float* __restrict__ W1c, const float* __restrict__ W1d,
                      const float* __restrict__ W2c, const float* __restrict__ W2d,
                      unsigned short* kW1t, unsigned short* kW2t, unsigned short* pWt,
                      unsigned short* W1cH, unsigned short* W1cL,
                      unsigned short* W1dH, unsigned short* W1dL,
                      unsigned short* W2cH, unsigned short* W2cL,
                      unsigned short* W2dH, unsigned short* W2dL)
{
  int gid = blockIdx.x * 256 + threadIdx.x;
  if (gid < 16384) {
    int k = gid >> 7, c = gid & 127;
    kW1t[(size_t)c * 128 + k] = f2bf(k1W[gid]);
  } else if (gid < 32768) {
    int i = gid - 16384, k = i >> 7, c = i & 127;
    kW2t[(size_t)c * 128 + k] = f2bf(k2W[i]);
  } else if (gid < 40960) {
    int i = gid - 32768, k = i / 64, c = i - k * 64;
    pWt[(size_t)c * 128 + k] = f2bf(pW[i]);
  } else if (gid < 73728) {
    int i = gid - 40960, k = i >> 7, c = i & 127;
    float v = W1c[i]; unsigned short h = f2bf(v);
    W1cH[(size_t)c * 256 + k] = h;
    W1cL[(size_t)c * 256 + k] = f2bf(v - bf2f(h));
  } else if (gid < 106496) {
    int i = gid - 73728, k = i >> 7, c = i & 127;
    float v = W1d[i]; unsigned short h = f2bf(v);
    W1dH[(size_t)c * 256 + k] = h;
    W1dL[(size_t)c * 256 + k] = f2bf(v - bf2f(h));
  } else if (gid < 122880) {
    int i = gid - 106496, k = i >> 7, c = i & 127;
    float v = W2c[i]; unsigned short h = f2bf(v);
    W2cH[(size_t)c * 128 + k] = h;
    W2cL[(size_t)c * 128 + k] = f2bf(v - bf2f(h));
  } else if (gid < 139264) {
    int i = gid - 122880, k = i >> 7, c = i & 127;
    float v = W2d[i]; unsigned short h = f2bf(v);
    W2dH[(size_t)c * 128 + k] = h;
    W2dL[(size_t)c * 128 + k] = f2bf(v - bf2f(h));
  }
}

// ==== FUSED edge attention (CSR, fp16 h, lane-specialized softmax) =======
struct EdgeOp {
  const int* offs; const int* elist;
  const float* sdot; const float* ddot;
  const __half* hsrc; __half* out;
};

DEVI void csr_att_body(const EdgeOp& op, int dst, int lane)
{
  const int i0 = op.offs[dst], i1 = op.offs[dst + 1];
  const int hB = lane >> 4;
  const float ddv = op.ddot[dst * 4 + hB];
  const __half* hsrc = op.hsrc;
  const float* sdot = op.sdot;
  const int* el = op.elist;
  const int wsel = lane & 48;
  float den = 0.f, a0 = 0.f, a1 = 0.f;

  for (int base = i0; base < i1; base += 16) {
    int i = base + (lane & 15);
    int s_ = 0;
    float w = 0.f;
    if (i < i1) {
      s_ = el[i];
      float lv = sdot[s_ * 4 + hB] + ddv;
      lv = fminf(fmaxf(lv, 0.2f * lv), 80.f);
      w = __expf(lv);
    }
    float g = w;
    g += __shfl_xor(g, 1);
    g += __shfl_xor(g, 2);
    g += __shfl_xor(g, 4);
    g += __shfl_xor(g, 8);
    den += g;

    const int rem = min(16, i1 - base);
    int j = 0;
    for (; j + 2 <= rem; j += 2) {
      int sA = __shfl(s_, j);
      int sB = __shfl(s_, j + 1);
      float wA = __shfl(w, wsel | j);
      float wB = __shfl(w, wsel | (j + 1));
      float2 hA = __half22float2(*(const __half2*)(hsrc + (size_t)sA * HIDn + lane * 2));
      float2 hBv = __half22float2(*(const __half2*)(hsrc + (size_t)sB * HIDn + lane * 2));
      a0 += hA.x * wA + hBv.x * wB;
      a1 += hA.y * wA + hBv.y * wB;
    }
    if (j < rem) {
      int sA = __shfl(s_, j);
      float wA = __shfl(w, wsel | j);
      float2 hA = __half22float2(*(const __half2*)(hsrc + (size_t)sA * HIDn + lane * 2));
      a0 += hA.x * wA;
      a1 += hA.y * wA;
    }
  }
  float dinv = __fdividef(1.f, den + 1e-16f);
  __half2 o2 = __floats2half2_rn(fmaxf(a0 * dinv, 0.f), fmaxf(a1 * dinv, 0.f));
  *(__half2*)(op.out + (size_t)dst * HIDn + lane * 2) = o2;
}

__global__ __launch_bounds__(256)
void csr_att3(EdgeOp op0, EdgeOp op1, EdgeOp op2, int Ndst)
{
  int wave = (blockIdx.x * 256 + threadIdx.x) >> 6;
  if (wave >= Ndst) return;
  const int lane = threadIdx.x & 63;
  if (blockIdx.y == 0)      csr_att_body(op0, wave, lane);
  else if (blockIdx.y == 1) csr_att_body(op1, wave, lane);
  else                      csr_att_body(op2, wave, lane);
}

// ---- fallback path (atomic scatter, fp32 h), used only if ws too small --
__global__ void edge_logit_max(const int* __restrict__ ei,
                               const float* __restrict__ sdot,
                               const float* __restrict__ ddot,
                               unsigned* __restrict__ m)
{
  int e = blockIdx.x * blockDim.x + threadIdx.x;
  if (e >= En) return;
  int s = ei[e], d = ei[En + e];
  #pragma unroll
  for (int hh = 0; hh < 4; ++hh) {
    float l = sdot[s * 4 + hh] + ddot[d * 4 + hh];
    l = (l > 0.f) ? l : 0.2f * l;
    atomicMax(&m[d * 4 + hh], fmap(l));
  }
}

__global__ void edge_exp_sum(const int* __restrict__ ei,
                             const float* __restrict__ sdot,
                             const float* __restrict__ ddot,
                             const unsigned* __restrict__ m,
                             float* __restrict__ sden,
                             float* __restrict__ ebuf)
{
  int e = blockIdx.x * blockDim.x + threadIdx.x;
  if (e >= En) return;
  int s = ei[e], d = ei[En + e];
  #pragma unroll
  for (int hh = 0; hh < 4; ++hh) {
    float l = sdot[s * 4 + hh] + ddot[d * 4 + hh];
    l = (l > 0.f) ? l : 0.2f * l;
    float ex = expf(fminf(l - fdecode(m[d * 4 + hh]), 0.f));
    ebuf[e * 4 + hh] = ex;
    atomicAdd(&sden[d * 4 + hh], ex);
  }
}

__global__ __launch_bounds__(256)
void edge_scatter(const int* __restrict__ ei, const float* __restrict__ hsrc,
                  const float* __restrict__ ebuf, const float* __restrict__ sden,
                  float* __restrict__ out)
{
  int gid  = blockIdx.x * 256 + threadIdx.x;
  int e    = gid >> 6;
  if (e >= En) return;
  int lane = gid & 63;
  int s = ei[e], d = ei[En + e];
  #pragma unroll
  for (int half = 0; half < 2; ++half) {
    int c  = lane + half * 64;
    int hh = c >> 5;
    float alpha = ebuf[e * 4 + hh] / (sden[d * 4 + hh] + 1e-16f);
    atomicAdd(&out[(size_t)d * HIDn + c], hsrc[(size_t)s * HIDn + c] * alpha);
  }
}

__global__ void relu_k(float* __restrict__ x, int n)
{
  int i = blockIdx.x * blockDim.x + threadIdx.x;
  if (i < n) x[i] = fmaxf(x[i], 0.f);
}

// ---- semantic-attention score via MFMA bf16 -----------------------------
template<int IN16>
__global__ __launch_bounds__(256)
void score_mfma(const void* __restrict__ oA, const void* __restrict__ oB,
                const unsigned short* __restrict__ kWt,
                const float* __restrict__ kb, const float* __restrict__ q,
                int N, float* __restrict__ slots)
{
  __shared__ float partw[4];
  const void* o = blockIdx.y ? oB : oA;
  const int tid = threadIdx.x;
  const int w = tid >> 6, lane = tid & 63;
  const int row0 = (blockIdx.x * 4 + w) * 16;
  const int m = lane & 15, b = lane >> 4;
  const int arow = row0 + m;
  const bool rok = arow < N;

  const bf16x8 zfr = {0, 0, 0, 0, 0, 0, 0, 0};
  bf16x8 afr[4];
  {
    const size_t base = (size_t)arow * 128;
    #pragma unroll
    for (int ks = 0; ks < 4; ++ks) {
      if (rok) afr[ks] = packrow8<0, IN16>(o, nullptr, 0.f, 0.f, base + ks * 32 + b * 8);
      else     afr[ks] = zfr;
    }
  }

  float sum = 0.f;
  #pragma unroll
  for (int t = 0; t < 8; ++t) {
    f32x4 acc = {0.f, 0.f, 0.f, 0.f};
    const int col = t * 16 + m;
    const unsigned short* bp = kWt + (size_t)col * 128 + b * 8;
    #pragma unroll
    for (int ks = 0; ks < 4; ++ks)
      acc = __builtin_amdgcn_mfma_f32_16x16x32_bf16(afr[ks], *(const bf16x8*)(bp + ks * 32), acc, 0, 0, 0);
    const float qc = q[col], kbc = kb[col];
    #pragma unroll
    for (int r = 0; r < 4; ++r) {
      int row = row0 + b * 4 + r;
      if (row < N) sum += qc * tanh_fast(acc[r] + kbc);
    }
  }
  #pragma unroll
  for (int off = 32; off > 0; off >>= 1) sum += __shfl_down(sum, off);
  if (lane == 0) partw[w] = sum;
  __syncthreads();
  if (tid == 0)
    atomicAdd(&slots[blockIdx.y],
              (partw[0] + partw[1] + partw[2] + partw[3]) * (1.f / (float)N));
}

__global__ void softmax2_kernel(float* sb)   // sb[0],sb[1] -> weights sb[2],sb[3]
{
  float s0 = sb[0], s1 = sb[1];
  float mx = fmaxf(s0, s1);
  float e0 = expf(s0 - mx), e1 = expf(s1 - mx);
  float inv = 1.f / (e0 + e1);
  sb[2] = e0 * inv;
  sb[3] = e1 * inv;
}

// ---- merged final projection via MFMA bf16 ------------------------------
// grid (ceil(N/64), 2). y=0: elu(w2*B2+w3*B3) @ pW + pb, L2-norm -> outc.
//                       y=1: elu(B4) @ pW + pb -> outd.
template<int IN16>
__global__ __launch_bounds__(256)
void proj2_mfma(const void* __restrict__ fa, const void* __restrict__ fb,
                const float* __restrict__ wv, const void* __restrict__ fd,
                const unsigned short* __restrict__ pWt, const float* __restrict__ pb,
                float* __restrict__ outc, float* __restrict__ outd, int N)
{
  const bool isC = (blockIdx.y == 0);
  const int tid = threadIdx.x;
  const int w = tid >> 6, lane = tid & 63;
  const int row0 = (blockIdx.x * 4 + w) * 16;
  const int m = lane & 15, b = lane >> 4;
  const int arow = row0 + m;
  const bool rok = arow < N;
  float* out = isC ? outc : outd;

  const bf16x8 zfr = {0, 0, 0, 0, 0, 0, 0, 0};
  bf16x8 afr[4];
  {
    const size_t base = (size_t)arow * 128;
    if (isC) {
      const float w2 = wv[2], w3 = wv[3];
      #pragma unroll
      for (int ks = 0; ks < 4; ++ks) {
        if (rok) afr[ks] = packrow8<2, IN16>(fa, fb, w2, w3, base + ks * 32 + b * 8);
        else     afr[ks] = zfr;
      }
    } else {
      #pragma unroll
      for (int ks = 0; ks < 4; ++ks) {
        if (rok) afr[ks] = packrow8<1, IN16>(fd, nullptr, 0.f, 0.f, base + ks * 32 + b * 8);
        else     afr[ks] = zfr;
      }
    }
  }

  f32x4 accs[4];
  float pbc[4];
  #pragma unroll
  for (int t = 0; t < 4; ++t) {
    f32x4 acc = {0.f, 0.f, 0.f, 0.f};
    const int col = t * 16 + m;
    const unsigned short* bp = pWt + (size_t)col * 128 + b * 8;
    #pragma unroll
    for (int ks = 0; ks < 4; ++ks)
      acc = __builtin_amdgcn_mfma_f32_16x16x32_bf16(afr[ks], *(const bf16x8*)(bp + ks * 32), acc, 0, 0, 0);
    accs[t] = acc;
    pbc[t] = pb[col];
  }

  #pragma unroll
  for (int r = 0; r < 4; ++r) {
    const int row = row0 + b * 4 + r;
    float v[4];
    #pragma unroll
    for (int t = 0; t < 4; ++t) v[t] = accs[t][r] + pbc[t];
    if (isC) {
      float ss = v[0]*v[0] + v[1]*v[1] + v[2]*v[2] + v[3]*v[3];
      ss += __shfl_xor(ss, 1);
      ss += __shfl_xor(ss, 2);
      ss += __shfl_xor(ss, 4);
      ss += __shfl_xor(ss, 8);
      float inv = 1.f / fmaxf(sqrtf(ss), 1e-12f);
      #pragma unroll
      for (int t = 0; t < 4; ++t) v[t] *= inv;
    }
    if (row < N) {
      #pragma unroll
      for (int t = 0; t < 4; ++t)
        out[(size_t)row * OUTn + t * 16 + m] = v[t];
    }
  }
}

// ---- fallback edge-op dispatcher ----------------------------------------
static void run_edge_fb(hipStream_t stream, const int* ei,
                        const float* sdot, const float* ddot, const float* hsrc,
                        float* outb, int Ndst,
                        unsigned* mbuf, float* sden, float* ebuf)
{
  hipMemsetAsync(mbuf, 0, (size_t)Ndst * 4 * sizeof(unsigned), stream);
  edge_logit_max<<<(En + 255) / 256, 256, 0, stream>>>(ei, sdot, ddot, mbuf);
  hipMemsetAsync(sden, 0, (size_t)Ndst * 4 * sizeof(float), stream);
  edge_exp_sum<<<(En + 255) / 256, 256, 0, stream>>>(ei, sdot, ddot, mbuf, sden, ebuf);
  hipMemsetAsync(outb, 0, (size_t)Ndst * HIDn * sizeof(float), stream);
  edge_scatter<<<((size_t)En * 64 + 255) / 256, 256, 0, stream>>>(ei, hsrc, ebuf, sden, outb);
  relu_k<<<((size_t)Ndst * HIDn + 255) / 256, 256, 0, stream>>>(outb, Ndst * HIDn);
}

extern "C" void kernel_launch(void* const* d_in, const int* in_sizes, int n_in,
                              void* d_out, int out_size, void* d_ws, size_t ws_size,
                              hipStream_t stream)
{
  const float* xc    = (const float*)d_in[0];
  const float* xd    = (const float*)d_in[1];
  const int*   ei_cc = (const int*)d_in[2];
  const int*   ei_dc = (const int*)d_in[3];
  const int*   ei_cd = (const int*)d_in[4];
  const float* W1c = (const float*)d_in[5];  const float* b1c = (const float*)d_in[6];
  const float* W1d = (const float*)d_in[7];  const float* b1d = (const float*)d_in[8];
  const float* a1s_cc = (const float*)d_in[9];  const float* a1d_cc = (const float*)d_in[10];
  const float* a1s_dc = (const float*)d_in[11]; const float* a1d_dc = (const float*)d_in[12];
  const float* a1s_cd = (const float*)d_in[13]; const float* a1d_cd = (const float*)d_in[14];
  const float* k1W = (const float*)d_in[15]; const float* k1b = (const float*)d_in[16];
  const float* q1  = (const float*)d_in[17];
  const float* W2c = (const float*)d_in[18]; const float* b2c = (const float*)d_in[19];
  const float* W2d = (const float*)d_in[20]; const float* b2d = (const float*)d_in[21];
  const float* a2s_cc = (const float*)d_in[22]; const float* a2d_cc = (const float*)d_in[23];
  const float* a2s_dc = (const float*)d_in[24]; const float* a2d_dc = (const float*)d_in[25];
  const float* a2s_cd = (const float*)d_in[26]; const float* a2d_cd = (const float*)d_in[27];
  const float* k2W = (const float*)d_in[28]; const float* k2b = (const float*)d_in[29];
  const float* q2  = (const float*)d_in[30];
  const float* pW  = (const float*)d_in[31]; const float* pb  = (const float*)d_in[32];

  // ---------------- workspace layout ----------------
  float* ws = (float*)d_ws;
  const size_t NB = (size_t)NCn * HIDn;
  float* B0 = ws;            // node buffers (fp16 in CSR mode, fp32 fallback)
  float* B1 = ws + NB;
  float* B2 = ws + 2 * NB;
  float* B3 = ws + 3 * NB;
  float* B4 = ws + 4 * NB;
  float* sml = ws + 5 * NB;
  float* scc = sml;
  float* dcc = sml + 200000;
  float* ddc = sml + 400000;
  float* scd = sml + 600000;
  float* sdc = sml + 800000;
  float* dcd = sml + 1000000;
  float* scoreB = sml + 1200000;
  float* R0 = sml + 1200016;
  int*  R0i = (int*)R0;
  int*  offsBase  = R0i;                   // 150,004 ints (global offs)
  int*  elistBase = R0i + 150004;          // 1,200,000 ints (combined)
  int*  degBase   = R0i + 1350004;         // 150,000
  int*  cursorBase= R0i + 1500004;         // 150,000 (adjacent -> single memset)
  int*  inclBase  = R0i + 1650004;         // 150,000
  int*  bsumBase  = R0i + 1800004;         // 1,024
  unsigned short* kW1t = (unsigned short*)(R0i + 1801028);
  unsigned short* kW2t = (unsigned short*)(R0i + 1809220);
  unsigned short* pWt  = (unsigned short*)(R0i + 1817412);
  unsigned short* W1cH = (unsigned short*)(R0i + 1821508);
  unsigned short* W1cL = (unsigned short*)(R0i + 1837892);
  unsigned short* W1dH = (unsigned short*)(R0i + 1854276);
  unsigned short* W1dL = (unsigned short*)(R0i + 1870660);
  unsigned short* W2cH = (unsigned short*)(R0i + 1887044);
  unsigned short* W2cL = (unsigned short*)(R0i + 1895236);
  unsigned short* W2dH = (unsigned short*)(R0i + 1903428);
  unsigned short* W2dL = (unsigned short*)(R0i + 1911620);  // end 1,919,812 ints
  // fallback temps overlay (over CSR region)
  unsigned* mbuf = (unsigned*)R0;
  float*    sden = R0 + 200000;
  float*    ebuf = R0 + 400000;

  const size_t REQ_FLOATS = 5 * NB + 1200016 + 1919812;     // 35,119,828 fl = 140.5 MB
  const bool useCsr = ws_size >= REQ_FLOATS * sizeof(float);

  if (useCsr) {
    hipMemsetAsync(degBase, 0, 300000 * sizeof(int), stream);   // deg + cursor
    hist3<<<(3 * En + 255) / 256, 256, 0, stream>>>(ei_cc, ei_dc, ei_cd, degBase);
    scan_pass1<<<SCAN_NB, SCAN_BLK, 0, stream>>>(degBase, inclBase, bsumBase);
    scan_pass2<<<1, SCAN_BLK, 0, stream>>>(bsumBase, SCAN_NB);
    scan_pass3<<<SCAN_NB, SCAN_BLK, 0, stream>>>(inclBase, bsumBase, offsBase);
    fill3<<<(3 * En + 255) / 256, 256, 0, stream>>>(ei_cc, ei_dc, ei_cd,
                                                    offsBase, cursorBase, elistBase);
  }
  wprep<<<(139264 + 255) / 256, 256, 0, stream>>>(k1W, k2W, pW, W1c, W1d, W2c, W2d,
                                                  kW1t, kW2t, pWt,
                                                  W1cH, W1cL, W1dH, W1dL,
                                                  W2cH, W2cL, W2dH, W2dL);

  hipMemsetAsync(scoreB, 0, 8 * sizeof(float), stream);

  const int NT64 = (NCn + 63) / 64;
  const int* offs0 = offsBase;
  const int* offs1 = offsBase + 50000;
  const int* offs2 = offsBase + 100000;

  auto edge_layer = [&](void* hc, void* hd, void* oCC, void* oDC, void* oCD) {
    if (useCsr) {
      EdgeOp o0{offs0, elistBase, scc, dcc, (const __half*)hc, (__half*)oCC};
      EdgeOp o1{offs1, elistBase, sdc, ddc, (const __half*)hd, (__half*)oDC};
      EdgeOp o2{offs2, elistBase, scd, dcd, (const __half*)hc, (__half*)oCD};
      csr_att3<<<dim3((NCn + 3) / 4, 3), 256, 0, stream>>>(o0, o1, o2, NCn);
    } else {
      run_edge_fb(stream, ei_cc, scc, dcc, (const float*)hc, (float*)oCC, NCn, mbuf, sden, ebuf);
      run_edge_fb(stream, ei_dc, sdc, ddc, (const float*)hd, (float*)oDC, NCn, mbuf, sden, ebuf);
      run_edge_fb(stream, ei_cd, scd, dcd, (const float*)hc, (float*)oCD, NDn, mbuf, sden, ebuf);
    }
  };

  if (useCsr) {
    // ---------------- layer 1 ----------------
    gemm2_mfma<256, 0, 0, 0, 1><<<dim3(NT64, 2), 256, 0, stream>>>(
        xc, nullptr, nullptr, W1cH, W1cL, b1c, B0,
        xd, W1dH, W1dL, b1d, B1, NCn,
        a1s_cc, a1d_cc, a1d_dc, a1s_cd, a1s_dc, a1d_cd,
        scc, dcc, ddc, scd, sdc, dcd);
    edge_layer(B0, B1, B2, B3, B4);
    score_mfma<1><<<dim3(NT64, 2), 256, 0, stream>>>(B2, B3, kW1t, k1b, q1, NCn, scoreB);
    softmax2_kernel<<<1, 1, 0, stream>>>(scoreB);

    // ---------------- layer 2 ----------------
    gemm2_mfma<128, 2, 1, 1, 1><<<dim3(NT64, 2), 256, 0, stream>>>(
        B2, B3, scoreB, W2cH, W2cL, b2c, B0,
        B4, W2dH, W2dL, b2d, B1, NCn,
        a2s_cc, a2d_cc, a2d_dc, a2s_cd, a2s_dc, a2d_cd,
        scc, dcc, ddc, scd, sdc, dcd);
    edge_layer(B0, B1, B2, B3, B4);
    score_mfma<1><<<dim3(NT64, 2), 256, 0, stream>>>(B2, B3, kW2t, k2b, q2, NCn, scoreB + 4);
    softmax2_kernel<<<1, 1, 0, stream>>>(scoreB + 4);

    // ---------------- projection (merged) ----------------
    proj2_mfma<1><<<dim3(NT64, 2), 256, 0, stream>>>(B2, B3, scoreB + 4, B4, pWt, pb,
                                                     (float*)d_out,
                                                     (float*)d_out + (size_t)NCn * OUTn, NCn);
  } else {
    // ---------------- fp32 fallback ----------------
    gemm2_mfma<256, 0, 0, 0, 0><<<dim3(NT64, 2), 256, 0, stream>>>(
        xc, nullptr, nullptr, W1cH, W1cL, b1c, B0,
        xd, W1dH, W1dL, b1d, B1, NCn,
        a1s_cc, a1d_cc, a1d_dc, a1s_cd, a1s_dc, a1d_cd,
        scc, dcc, ddc, scd, sdc, dcd);
    edge_layer(B0, B1, B2, B3, B4);
    score_mfma<0><<<dim3(NT64, 2), 256, 0, stream>>>(B2, B3, kW1t, k1b, q1, NCn, scoreB);
    softmax2_kernel<<<1, 1, 0, stream>>>(scoreB);

    gemm2_mfma<128, 2, 1, 0, 0><<<dim3(NT64, 2), 256, 0, stream>>>(
        B2, B3, scoreB, W2cH, W2cL, b2c, B0,
        B4, W2dH, W2dL, b2d, B1, NCn,
        a2s_cc, a2d_cc, a2d_dc, a2s_cd, a2s_dc, a2d_cd,
        scc, dcc, ddc, scd, sdc, dcd);
    edge_layer(B0, B1, B2, B3, B4);
    score_mfma<0><<<dim3(NT64, 2), 256, 0, stream>>>(B2, B3, kW2t, k2b, q2, NCn, scoreB + 4);
    softmax2_kernel<<<1, 1, 0, stream>>>(scoreB + 4);

    proj2_mfma<0><<<dim3(NT64, 2), 256, 0, stream>>>(B2, B3, scoreB + 4, B4, pWt, pb,
                                                     (float*)d_out,
                                                     (float*)d_out + (size_t)NCn * OUTn, NCn);
  }
}

// Round 20
// 486.814 us; speedup vs baseline: 1.5013x; 1.0395x over previous
//
#include <hip/hip_runtime.h>
#include <hip/hip_fp16.h>
#include <cmath>

#define DEVI static __device__ __forceinline__

constexpr int HIDn = 128, OUTn = 64;
constexpr int NCn = 50000, NDn = 50000, En = 400000;
constexpr int SCAN_N = 150000, SCAN_BLK = 1024;
constexpr int SCAN_NB = (SCAN_N + SCAN_BLK - 1) / SCAN_BLK;   // 147

typedef __attribute__((ext_vector_type(8))) short bf16x8;
typedef __attribute__((ext_vector_type(4))) float f32x4;

// monotonic float->uint mapping for atomicMax on floats (handles signs)
DEVI unsigned fmap(float f) {
  int i = __float_as_int(f);
  return (i < 0) ? ~((unsigned)i) : (((unsigned)i) | 0x80000000u);
}
DEVI float fdecode(unsigned u) {
  int i = (u & 0x80000000u) ? (int)(u & 0x7fffffffu) : (int)(~u);
  return __int_as_float(i);
}

DEVI float tanh_fast(float x) {           // 1 - 2/(e^{2x}+1); saturates correctly
  float e = __expf(2.f * x);
  return 1.f - __fdividef(2.f, e + 1.f);
}

DEVI unsigned short f2bf(float x) {       // fp32 -> bf16 RNE
  unsigned u = __float_as_uint(x);
  return (unsigned short)((u + 0x7FFFu + ((u >> 16) & 1u)) >> 16);
}
DEVI float bf2f(unsigned short h) {
  unsigned u = ((unsigned)h) << 16;
  return __uint_as_float(u);
}

// ---- vectorized 8-wide A-row load + fused transform (value-based) -------
// MODE: 0=plain, 1=elu(x), 2=elu(w2*a+w3*b). HALF: input dtype fp16.
template<int MODE, int HALF>
DEVI void loadrow8(float* __restrict__ tmp,
                   const void* __restrict__ A, const void* __restrict__ A2,
                   float w2, float w3, size_t base)
{
  float v[8];
  if (HALF) {
    float4 raw = *(const float4*)((const __half*)A + base);
    const __half2* h2 = (const __half2*)&raw;
    #pragma unroll
    for (int j = 0; j < 4; ++j) {
      float2 f = __half22float2(h2[j]);
      v[2 * j] = f.x; v[2 * j + 1] = f.y;
    }
  } else {
    const float4* p = (const float4*)((const float*)A + base);
    float4 u0 = p[0], u1 = p[1];
    v[0] = u0.x; v[1] = u0.y; v[2] = u0.z; v[3] = u0.w;
    v[4] = u1.x; v[5] = u1.y; v[6] = u1.z; v[7] = u1.w;
  }
  if (MODE == 2) {
    float vb[8];
    if (HALF) {
      float4 raw = *(const float4*)((const __half*)A2 + base);
      const __half2* h2 = (const __half2*)&raw;
      #pragma unroll
      for (int j = 0; j < 4; ++j) {
        float2 f = __half22float2(h2[j]);
        vb[2 * j] = f.x; vb[2 * j + 1] = f.y;
      }
    } else {
      const float4* q = (const float4*)((const float*)A2 + base);
      float4 t0 = q[0], t1 = q[1];
      vb[0] = t0.x; vb[1] = t0.y; vb[2] = t0.z; vb[3] = t0.w;
      vb[4] = t1.x; vb[5] = t1.y; vb[6] = t1.z; vb[7] = t1.w;
    }
    #pragma unroll
    for (int i = 0; i < 8; ++i) v[i] = w2 * v[i] + w3 * vb[i];
  }
  if (MODE >= 1) {
    #pragma unroll
    for (int i = 0; i < 8; ++i) v[i] = (v[i] > 0.f) ? v[i] : (__expf(v[i]) - 1.f);
  }
  #pragma unroll
  for (int i = 0; i < 8; ++i) tmp[i] = v[i];
}

template<int MODE, int HALF>
DEVI bf16x8 packrow8(const void* __restrict__ A, const void* __restrict__ A2,
                     float w2, float w3, size_t base)
{
  float t[8];
  loadrow8<MODE, HALF>(t, A, A2, w2, w3, base);
  bf16x8 r;
  #pragma unroll
  for (int i = 0; i < 8; ++i) r[i] = (short)f2bf(t[i]);
  return r;
}

// ====== merged MFMA GEMM (c & d paths) + fused attention dots ============
// grid (ceil(N/64), 2). Register-prefetch pipeline: next chunk's global
// loads issue right after the first barrier, hiding latency under MFMA.
template<int KI, int MODEc, int MODEd, int IN16, int OUT16>
__global__ __launch_bounds__(256)
void gemm2_mfma(const void* __restrict__ Ac, const void* __restrict__ Ac2,
                const float* __restrict__ wv,
                const unsigned short* __restrict__ WcH, const unsigned short* __restrict__ WcL,
                const float* __restrict__ bc, void* __restrict__ Cc,
                const void* __restrict__ Ad,
                const unsigned short* __restrict__ WdH, const unsigned short* __restrict__ WdL,
                const float* __restrict__ bd, void* __restrict__ Cd,
                int N,
                const float* __restrict__ avc0, const float* __restrict__ avc1,
                const float* __restrict__ avc2, const float* __restrict__ avc3,
                const float* __restrict__ avd0, const float* __restrict__ avd1,
                float* __restrict__ doc0, float* __restrict__ doc1,
                float* __restrict__ doc2, float* __restrict__ doc3,
                float* __restrict__ dod0, float* __restrict__ dod1)
{
  __shared__ float As[64][36];
  __shared__ unsigned short Bh[128][40];
  __shared__ unsigned short Bl[128][40];
  constexpr int NC = KI / 32;
  const bool isC = (blockIdx.y == 0);
  const void* A  = isC ? Ac : Ad;
  const void* A2 = isC ? Ac2 : nullptr;
  const unsigned short* Wh = isC ? WcH : WdH;
  const unsigned short* Wl = isC ? WcL : WdL;
  const float* bias = isC ? bc : bd;
  void* Cv = isC ? Cc : Cd;
  float w2 = 0.f, w3 = 0.f;
  if (MODEc == 2) { if (isC) { w2 = wv[2]; w3 = wv[3]; } }

  const int tid = threadIdx.x;
  const int w = tid >> 6, lane = tid & 63;
  const int m = lane & 15, b4 = lane >> 4;
  const int row0 = blockIdx.x * 64;
  const int row0w = row0 + w * 16;

  // staging thread roles
  const int rA = tid >> 2, kqA = (tid & 3) << 3;
  const int rowA = row0 + rA;
  const int cB = tid >> 1, kqB = (tid & 1) << 4;

  f32x4 acc[8];
  #pragma unroll
  for (int t = 0; t < 8; ++t) acc[t] = (f32x4){0.f, 0.f, 0.f, 0.f};

  float tA[8];
  float4 bh0, bh1, bl0, bl1;

  auto loadA = [&](int k0) {
    if (rowA < N) {
      if (isC) loadrow8<MODEc, IN16>(tA, A, A2, w2, w3, (size_t)rowA * KI + k0 + kqA);
      else     loadrow8<MODEd, IN16>(tA, A, nullptr, 0.f, 0.f, (size_t)rowA * KI + k0 + kqA);
    } else {
      #pragma unroll
      for (int i = 0; i < 8; ++i) tA[i] = 0.f;
    }
  };
  auto loadB = [&](int k0) {
    const float4* ph = (const float4*)(Wh + (size_t)cB * KI + k0 + kqB);
    const float4* pl = (const float4*)(Wl + (size_t)cB * KI + k0 + kqB);
    bh0 = ph[0]; bh1 = ph[1]; bl0 = pl[0]; bl1 = pl[1];
  };

  loadA(0);
  loadB(0);

  for (int c = 0; c < NC; ++c) {
    // write staged regs to LDS
    *(float4*)&As[rA][kqA]     = make_float4(tA[0], tA[1], tA[2], tA[3]);
    *(float4*)&As[rA][kqA + 4] = make_float4(tA[4], tA[5], tA[6], tA[7]);
    *(float4*)&Bh[cB][kqB]     = bh0;
    *(float4*)&Bh[cB][kqB + 8] = bh1;
    *(float4*)&Bl[cB][kqB]     = bl0;
    *(float4*)&Bl[cB][kqB + 8] = bl1;
    __syncthreads();

    // prefetch next chunk while computing this one
    if (c + 1 < NC) {
      loadA((c + 1) * 32);
      loadB((c + 1) * 32);
    }

    bf16x8 ah, al;
    {
      const float* ap = &As[w * 16 + m][b4 * 8];
      float4 u0 = *(const float4*)ap;
      float4 u1 = *(const float4*)(ap + 4);
      float t8[8] = {u0.x, u0.y, u0.z, u0.w, u1.x, u1.y, u1.z, u1.w};
      #pragma unroll
      for (int i = 0; i < 8; ++i) {
        unsigned short h = f2bf(t8[i]);
        ah[i] = (short)h;
        al[i] = (short)f2bf(t8[i] - bf2f(h));
      }
    }
    #pragma unroll
    for (int t = 0; t < 8; ++t) {
      const int col = t * 16 + m;
      bf16x8 bh = *(const bf16x8*)&Bh[col][b4 * 8];
      bf16x8 bl = *(const bf16x8*)&Bl[col][b4 * 8];
      acc[t] = __builtin_amdgcn_mfma_f32_16x16x32_bf16(ah, bh, acc[t], 0, 0, 0);
      acc[t] = __builtin_amdgcn_mfma_f32_16x16x32_bf16(al, bh, acc[t], 0, 0, 0);
      acc[t] = __builtin_amdgcn_mfma_f32_16x16x32_bf16(ah, bl, acc[t], 0, 0, 0);
    }
    __syncthreads();
  }

  // ---- epilogue: bias + C store ----
  float bt[8];
  #pragma unroll
  for (int t = 0; t < 8; ++t) bt[t] = bias[t * 16 + m];

  #pragma unroll
  for (int t = 0; t < 8; ++t) {
    const int col = t * 16 + m;
    #pragma unroll
    for (int r = 0; r < 4; ++r) {
      const int row = row0w + b4 * 4 + r;
      if (row < N) {
        float v = acc[t][r] + bt[t];
        if (OUT16) ((__half*)Cv)[(size_t)row * 128 + col] = __float2half(v);
        else       ((float*)Cv)[(size_t)row * 128 + col] = v;
      }
    }
  }

  // ---- fused attention dots: per (row, head) reduce over 16 m-lanes ----
  const float* avp[4];
  float* dop[4];
  int nv;
  if (isC) {
    avp[0] = avc0; avp[1] = avc1; avp[2] = avc2; avp[3] = avc3;
    dop[0] = doc0; dop[1] = doc1; dop[2] = doc2; dop[3] = doc3; nv = 4;
  } else {
    avp[0] = avd0; avp[1] = avd1; avp[2] = avd0; avp[3] = avd1;
    dop[0] = dod0; dop[1] = dod1; dop[2] = dod0; dop[3] = dod1; nv = 2;
  }
  float avv[4][8];
  #pragma unroll
  for (int v = 0; v < 4; ++v) {
    if (v < nv) {
      #pragma unroll
      for (int t = 0; t < 8; ++t) avv[v][t] = avp[v][t * 16 + m];
    }
  }
  #pragma unroll
  for (int h = 0; h < 4; ++h) {
    #pragma unroll
    for (int v = 0; v < 4; ++v) {
      if (v < nv) {
        #pragma unroll
        for (int r = 0; r < 4; ++r) {
          float p = (acc[2 * h][r] + bt[2 * h]) * avv[v][2 * h]
                  + (acc[2 * h + 1][r] + bt[2 * h + 1]) * avv[v][2 * h + 1];
          p += __shfl_xor(p, 1);
          p += __shfl_xor(p, 2);
          p += __shfl_xor(p, 4);
          p += __shfl_xor(p, 8);
          if (m == 0) {
            const int row = row0w + b4 * 4 + r;
            if (row < N) dop[v][(size_t)row * 4 + h] = p;
          }
        }
      }
    }
  }
}

// ================= CSR build: hist + 3-pass scan + fill ==================
__global__ void hist3(const int* __restrict__ ei0, const int* __restrict__ ei1,
                      const int* __restrict__ ei2, int* __restrict__ deg)
{
  int gid = blockIdx.x * blockDim.x + threadIdx.x;
  if (gid >= 3 * En) return;
  int g = gid / En, e = gid - g * En;
  const int* ei = (g == 0) ? ei0 : (g == 1) ? ei1 : ei2;
  atomicAdd(&deg[g * 50000 + ei[En + e]], 1);
}

__global__ void scan_pass1(const int* __restrict__ deg, int* __restrict__ incl,
                           int* __restrict__ bsum)
{
  __shared__ int wsum[16];
  int tid = threadIdx.x;
  int gid = blockIdx.x * SCAN_BLK + tid;
  int v = (gid < SCAN_N) ? deg[gid] : 0;
  int lane = tid & 63, w = tid >> 6;
  int x = v;
  #pragma unroll
  for (int off = 1; off < 64; off <<= 1) {
    int y = __shfl_up(x, off);
    if (lane >= off) x += y;
  }
  if (lane == 63) wsum[w] = x;
  __syncthreads();
  if (tid == 0) {
    int s = 0;
    #pragma unroll
    for (int ww = 0; ww < 16; ++ww) { int t = wsum[ww]; wsum[ww] = s; s += t; }
    bsum[blockIdx.x] = s;
  }
  __syncthreads();
  x += wsum[w];
  if (gid < SCAN_N) incl[gid] = x;
}

__global__ void scan_pass2(int* __restrict__ bsum, int nb)
{
  __shared__ int wsum[16];
  int tid = threadIdx.x;
  int v = (tid < nb) ? bsum[tid] : 0;
  int lane = tid & 63, w = tid >> 6;
  int x = v;
  #pragma unroll
  for (int off = 1; off < 64; off <<= 1) {
    int y = __shfl_up(x, off);
    if (lane >= off) x += y;
  }
  if (lane == 63) wsum[w] = x;
  __syncthreads();
  if (tid == 0) {
    int s = 0;
    #pragma unroll
    for (int ww = 0; ww < 16; ++ww) { int t = wsum[ww]; wsum[ww] = s; s += t; }
  }
  __syncthreads();
  x += wsum[w];
  if (tid < nb) bsum[tid] = x - v;
}

__global__ void scan_pass3(const int* __restrict__ incl, const int* __restrict__ bsum,
                           int* __restrict__ offs)
{
  int gid = blockIdx.x * SCAN_BLK + threadIdx.x;
  if (gid == 0) offs[0] = 0;
  if (gid < SCAN_N) offs[gid + 1] = incl[gid] + bsum[gid / SCAN_BLK];
}

__global__ void fill3(const int* __restrict__ ei0, const int* __restrict__ ei1,
                      const int* __restrict__ ei2, const int* __restrict__ offs,
                      int* __restrict__ cursor, int* __restrict__ elist)
{
  int gid = blockIdx.x * blockDim.x + threadIdx.x;
  if (gid >= 3 * En) return;
  int g = gid / En, e = gid - g * En;
  const int* ei = (g == 0) ? ei0 : (g == 1) ? ei1 : ei2;
  int s = ei[e], d = g * 50000 + ei[En + e];
  int p = atomicAdd(&cursor[d], 1);
  elist[offs[d] + p] = s;
}

// ---- single weight-prep kernel: all transposes/casts/splits -------------
__global__ void wprep(const float* __restrict__ k1W, const float* __restrict__ k2W,
                      const float* __restrict__ pW,
                      const float* __restrict__ W1c, const float* __restrict__ W1d,
                      const float* __restrict__ W2c, const float* __restrict__ W2d,
                      unsigned short* kW1t, unsigned short* kW2t, unsigned short* pWt,
                      unsigned short* W1cH, unsigned short* W1cL,
                      unsigned short* W1dH, unsigned short* W1dL,
                      unsigned short* W2cH, unsigned short* W2cL,
                      unsigned short* W2dH, unsigned short* W2dL)
{
  int gid = blockIdx.x * 256 + threadIdx.x;
  if (gid < 16384) {
    int k = gid >> 7, c = gid & 127;
    kW1t[(size_t)c * 128 + k] = f2bf(k1W[gid]);
  } else if (gid < 32768) {
    int i = gid - 16384, k = i >> 7, c = i & 127;
    kW2t[(size_t)c * 128 + k] = f2bf(k2W[i]);
  } else if (gid < 40960) {
    int i = gid - 32768, k = i / 64, c = i - k * 64;
    pWt[(size_t)c * 128 + k] = f2bf(pW[i]);
  } else if (gid < 73728) {
    int i = gid - 40960, k = i >> 7, c = i & 127;
    float v = W1c[i]; unsigned short h = f2bf(v);
    W1cH[(size_t)c * 256 + k] = h;
    W1cL[(size_t)c * 256 + k] = f2bf(v - bf2f(h));
  } else if (gid < 106496) {
    int i = gid - 73728, k = i >> 7, c = i & 127;
    float v = W1d[i]; unsigned short h = f2bf(v);
    W1dH[(size_t)c * 256 + k] = h;
    W1dL[(size_t)c * 256 + k] = f2bf(v - bf2f(h));
  } else if (gid < 122880) {
    int i = gid - 106496, k = i >> 7, c = i & 127;
    float v = W2c[i]; unsigned short h = f2bf(v);
    W2cH[(size_t)c * 128 + k] = h;
    W2cL[(size_t)c * 128 + k] = f2bf(v - bf2f(h));
  } else if (gid < 139264) {
    int i = gid - 122880, k = i >> 7, c = i & 127;
    float v = W2d[i]; unsigned short h = f2bf(v);
    W2dH[(size_t)c * 128 + k] = h;
    W2dL[(size_t)c * 128 + k] = f2bf(v - bf2f(h));
  }
}

// ==== FUSED edge attention (CSR, fp16 h, lane-specialized softmax) =======
struct EdgeOp {
  const int* offs; const int* elist;
  const float* sdot; const float* ddot;
  const __half* hsrc; __half* out;
};

DEVI void csr_att_body(const EdgeOp& op, int dst, int lane)
{
  const int i0 = op.offs[dst], i1 = op.offs[dst + 1];
  const int hB = lane >> 4;
  const float ddv = op.ddot[dst * 4 + hB];
  const __half* hsrc = op.hsrc;
  const float* sdot = op.sdot;
  const int* el = op.elist;
  const int wsel = lane & 48;
  float den = 0.f, a0 = 0.f, a1 = 0.f;

  for (int base = i0; base < i1; base += 16) {
    int i = base + (lane & 15);
    int s_ = 0;
    float w = 0.f;
    if (i < i1) {
      s_ = el[i];
      float lv = sdot[s_ * 4 + hB] + ddv;
      lv = fminf(fmaxf(lv, 0.2f * lv), 80.f);
      w = __expf(lv);
    }
    float g = w;
    g += __shfl_xor(g, 1);
    g += __shfl_xor(g, 2);
    g += __shfl_xor(g, 4);
    g += __shfl_xor(g, 8);
    den += g;

    const int rem = min(16, i1 - base);
    int j = 0;
    for (; j + 2 <= rem; j += 2) {
      int sA = __shfl(s_, j);
      int sB = __shfl(s_, j + 1);
      float wA = __shfl(w, wsel | j);
      float wB = __shfl(w, wsel | (j + 1));
      float2 hA = __half22float2(*(const __half2*)(hsrc + (size_t)sA * HIDn + lane * 2));
      float2 hBv = __half22float2(*(const __half2*)(hsrc + (size_t)sB * HIDn + lane * 2));
      a0 += hA.x * wA + hBv.x * wB;
      a1 += hA.y * wA + hBv.y * wB;
    }
    if (j < rem) {
      int sA = __shfl(s_, j);
      float wA = __shfl(w, wsel | j);
      float2 hA = __half22float2(*(const __half2*)(hsrc + (size_t)sA * HIDn + lane * 2));
      a0 += hA.x * wA;
      a1 += hA.y * wA;
    }
  }
  float dinv = __fdividef(1.f, den + 1e-16f);
  __half2 o2 = __floats2half2_rn(fmaxf(a0 * dinv, 0.f), fmaxf(a1 * dinv, 0.f));
  *(__half2*)(op.out + (size_t)dst * HIDn + lane * 2) = o2;
}

__global__ __launch_bounds__(256)
void csr_att3(EdgeOp op0, EdgeOp op1, EdgeOp op2, int Ndst)
{
  int wave = (blockIdx.x * 256 + threadIdx.x) >> 6;
  if (wave >= Ndst) return;
  const int lane = threadIdx.x & 63;
  if (blockIdx.y == 0)      csr_att_body(op0, wave, lane);
  else if (blockIdx.y == 1) csr_att_body(op1, wave, lane);
  else                      csr_att_body(op2, wave, lane);
}

// ---- fallback path (atomic scatter, fp32 h), used only if ws too small --
__global__ void edge_logit_max(const int* __restrict__ ei,
                               const float* __restrict__ sdot,
                               const float* __restrict__ ddot,
                               unsigned* __restrict__ m)
{
  int e = blockIdx.x * blockDim.x + threadIdx.x;
  if (e >= En) return;
  int s = ei[e], d = ei[En + e];
  #pragma unroll
  for (int hh = 0; hh < 4; ++hh) {
    float l = sdot[s * 4 + hh] + ddot[d * 4 + hh];
    l = (l > 0.f) ? l : 0.2f * l;
    atomicMax(&m[d * 4 + hh], fmap(l));
  }
}

__global__ void edge_exp_sum(const int* __restrict__ ei,
                             const float* __restrict__ sdot,
                             const float* __restrict__ ddot,
                             const unsigned* __restrict__ m,
                             float* __restrict__ sden,
                             float* __restrict__ ebuf)
{
  int e = blockIdx.x * blockDim.x + threadIdx.x;
  if (e >= En) return;
  int s = ei[e], d = ei[En + e];
  #pragma unroll
  for (int hh = 0; hh < 4; ++hh) {
    float l = sdot[s * 4 + hh] + ddot[d * 4 + hh];
    l = (l > 0.f) ? l : 0.2f * l;
    float ex = expf(fminf(l - fdecode(m[d * 4 + hh]), 0.f));
    ebuf[e * 4 + hh] = ex;
    atomicAdd(&sden[d * 4 + hh], ex);
  }
}

__global__ __launch_bounds__(256)
void edge_scatter(const int* __restrict__ ei, const float* __restrict__ hsrc,
                  const float* __restrict__ ebuf, const float* __restrict__ sden,
                  float* __restrict__ out)
{
  int gid  = blockIdx.x * 256 + threadIdx.x;
  int e    = gid >> 6;
  if (e >= En) return;
  int lane = gid & 63;
  int s = ei[e], d = ei[En + e];
  #pragma unroll
  for (int half = 0; half < 2; ++half) {
    int c  = lane + half * 64;
    int hh = c >> 5;
    float alpha = ebuf[e * 4 + hh] / (sden[d * 4 + hh] + 1e-16f);
    atomicAdd(&out[(size_t)d * HIDn + c], hsrc[(size_t)s * HIDn + c] * alpha);
  }
}

__global__ void relu_k(float* __restrict__ x, int n)
{
  int i = blockIdx.x * blockDim.x + threadIdx.x;
  if (i < n) x[i] = fmaxf(x[i], 0.f);
}

// ---- semantic-attention score via MFMA bf16 -----------------------------
template<int IN16>
__global__ __launch_bounds__(256)
void score_mfma(const void* __restrict__ oA, const void* __restrict__ oB,
                const unsigned short* __restrict__ kWt,
                const float* __restrict__ kb, const float* __restrict__ q,
                int N, float* __restrict__ slots)
{
  __shared__ float partw[4];
  const void* o = blockIdx.y ? oB : oA;
  const int tid = threadIdx.x;
  const int w = tid >> 6, lane = tid & 63;
  const int row0 = (blockIdx.x * 4 + w) * 16;
  const int m = lane & 15, b = lane >> 4;
  const int arow = row0 + m;
  const bool rok = arow < N;

  const bf16x8 zfr = {0, 0, 0, 0, 0, 0, 0, 0};
  bf16x8 afr[4];
  {
    const size_t base = (size_t)arow * 128;
    #pragma unroll
    for (int ks = 0; ks < 4; ++ks) {
      if (rok) afr[ks] = packrow8<0, IN16>(o, nullptr, 0.f, 0.f, base + ks * 32 + b * 8);
      else     afr[ks] = zfr;
    }
  }

  float sum = 0.f;
  #pragma unroll
  for (int t = 0; t < 8; ++t) {
    f32x4 acc = {0.f, 0.f, 0.f, 0.f};
    const int col = t * 16 + m;
    const unsigned short* bp = kWt + (size_t)col * 128 + b * 8;
    #pragma unroll
    for (int ks = 0; ks < 4; ++ks)
      acc = __builtin_amdgcn_mfma_f32_16x16x32_bf16(afr[ks], *(const bf16x8*)(bp + ks * 32), acc, 0, 0, 0);
    const float qc = q[col], kbc = kb[col];
    #pragma unroll
    for (int r = 0; r < 4; ++r) {
      int row = row0 + b * 4 + r;
      if (row < N) sum += qc * tanh_fast(acc[r] + kbc);
    }
  }
  #pragma unroll
  for (int off = 32; off > 0; off >>= 1) sum += __shfl_down(sum, off);
  if (lane == 0) partw[w] = sum;
  __syncthreads();
  if (tid == 0)
    atomicAdd(&slots[blockIdx.y],
              (partw[0] + partw[1] + partw[2] + partw[3]) * (1.f / (float)N));
}

__global__ void softmax2_kernel(float* sb)   // sb[0],sb[1] -> weights sb[2],sb[3]
{
  float s0 = sb[0], s1 = sb[1];
  float mx = fmaxf(s0, s1);
  float e0 = expf(s0 - mx), e1 = expf(s1 - mx);
  float inv = 1.f / (e0 + e1);
  sb[2] = e0 * inv;
  sb[3] = e1 * inv;
}

// ---- merged final projection via MFMA bf16 ------------------------------
template<int IN16>
__global__ __launch_bounds__(256)
void proj2_mfma(const void* __restrict__ fa, const void* __restrict__ fb,
                const float* __restrict__ wv, const void* __restrict__ fd,
                const unsigned short* __restrict__ pWt, const float* __restrict__ pb,
                float* __restrict__ outc, float* __restrict__ outd, int N)
{
  const bool isC = (blockIdx.y == 0);
  const int tid = threadIdx.x;
  const int w = tid >> 6, lane = tid & 63;
  const int row0 = (blockIdx.x * 4 + w) * 16;
  const int m = lane & 15, b = lane >> 4;
  const int arow = row0 + m;
  const bool rok = arow < N;
  float* out = isC ? outc : outd;

  const bf16x8 zfr = {0, 0, 0, 0, 0, 0, 0, 0};
  bf16x8 afr[4];
  {
    const size_t base = (size_t)arow * 128;
    if (isC) {
      const float w2 = wv[2], w3 = wv[3];
      #pragma unroll
      for (int ks = 0; ks < 4; ++ks) {
        if (rok) afr[ks] = packrow8<2, IN16>(fa, fb, w2, w3, base + ks * 32 + b * 8);
        else     afr[ks] = zfr;
      }
    } else {
      #pragma unroll
      for (int ks = 0; ks < 4; ++ks) {
        if (rok) afr[ks] = packrow8<1, IN16>(fd, nullptr, 0.f, 0.f, base + ks * 32 + b * 8);
        else     afr[ks] = zfr;
      }
    }
  }

  f32x4 accs[4];
  float pbc[4];
  #pragma unroll
  for (int t = 0; t < 4; ++t) {
    f32x4 acc = {0.f, 0.f, 0.f, 0.f};
    const int col = t * 16 + m;
    const unsigned short* bp = pWt + (size_t)col * 128 + b * 8;
    #pragma unroll
    for (int ks = 0; ks < 4; ++ks)
      acc = __builtin_amdgcn_mfma_f32_16x16x32_bf16(afr[ks], *(const bf16x8*)(bp + ks * 32), acc, 0, 0, 0);
    accs[t] = acc;
    pbc[t] = pb[col];
  }

  #pragma unroll
  for (int r = 0; r < 4; ++r) {
    const int row = row0 + b * 4 + r;
    float v[4];
    #pragma unroll
    for (int t = 0; t < 4; ++t) v[t] = accs[t][r] + pbc[t];
    if (isC) {
      float ss = v[0]*v[0] + v[1]*v[1] + v[2]*v[2] + v[3]*v[3];
      ss += __shfl_xor(ss, 1);
      ss += __shfl_xor(ss, 2);
      ss += __shfl_xor(ss, 4);
      ss += __shfl_xor(ss, 8);
      float inv = 1.f / fmaxf(sqrtf(ss), 1e-12f);
      #pragma unroll
      for (int t = 0; t < 4; ++t) v[t] *= inv;
    }
    if (row < N) {
      #pragma unroll
      for (int t = 0; t < 4; ++t)
        out[(size_t)row * OUTn + t * 16 + m] = v[t];
    }
  }
}

// ---- fallback edge-op dispatcher ----------------------------------------
static void run_edge_fb(hipStream_t stream, const int* ei,
                        const float* sdot, const float* ddot, const float* hsrc,
                        float* outb, int Ndst,
                        unsigned* mbuf, float* sden, float* ebuf)
{
  hipMemsetAsync(mbuf, 0, (size_t)Ndst * 4 * sizeof(unsigned), stream);
  edge_logit_max<<<(En + 255) / 256, 256, 0, stream>>>(ei, sdot, ddot, mbuf);
  hipMemsetAsync(sden, 0, (size_t)Ndst * 4 * sizeof(float), stream);
  edge_exp_sum<<<(En + 255) / 256, 256, 0, stream>>>(ei, sdot, ddot, mbuf, sden, ebuf);
  hipMemsetAsync(outb, 0, (size_t)Ndst * HIDn * sizeof(float), stream);
  edge_scatter<<<((size_t)En * 64 + 255) / 256, 256, 0, stream>>>(ei, hsrc, ebuf, sden, outb);
  relu_k<<<((size_t)Ndst * HIDn + 255) / 256, 256, 0, stream>>>(outb, Ndst * HIDn);
}

extern "C" void kernel_launch(void* const* d_in, const int* in_sizes, int n_in,
                              void* d_out, int out_size, void* d_ws, size_t ws_size,
                              hipStream_t stream)
{
  const float* xc    = (const float*)d_in[0];
  const float* xd    = (const float*)d_in[1];
  const int*   ei_cc = (const int*)d_in[2];
  const int*   ei_dc = (const int*)d_in[3];
  const int*   ei_cd = (const int*)d_in[4];
  const float* W1c = (const float*)d_in[5];  const float* b1c = (const float*)d_in[6];
  const float* W1d = (const float*)d_in[7];  const float* b1d = (const float*)d_in[8];
  const float* a1s_cc = (const float*)d_in[9];  const float* a1d_cc = (const float*)d_in[10];
  const float* a1s_dc = (const float*)d_in[11]; const float* a1d_dc = (const float*)d_in[12];
  const float* a1s_cd = (const float*)d_in[13]; const float* a1d_cd = (const float*)d_in[14];
  const float* k1W = (const float*)d_in[15]; const float* k1b = (const float*)d_in[16];
  const float* q1  = (const float*)d_in[17];
  const float* W2c = (const float*)d_in[18]; const float* b2c = (const float*)d_in[19];
  const float* W2d = (const float*)d_in[20]; const float* b2d = (const float*)d_in[21];
  const float* a2s_cc = (const float*)d_in[22]; const float* a2d_cc = (const float*)d_in[23];
  const float* a2s_dc = (const float*)d_in[24]; const float* a2d_dc = (const float*)d_in[25];
  const float* a2s_cd = (const float*)d_in[26]; const float* a2d_cd = (const float*)d_in[27];
  const float* k2W = (const float*)d_in[28]; const float* k2b = (const float*)d_in[29];
  const float* q2  = (const float*)d_in[30];
  const float* pW  = (const float*)d_in[31]; const float* pb  = (const float*)d_in[32];

  // ---------------- workspace layout ----------------
  float* ws = (float*)d_ws;
  const size_t NB = (size_t)NCn * HIDn;
  float* B0 = ws;            // node buffers (fp16 in CSR mode, fp32 fallback)
  float* B1 = ws + NB;
  float* B2 = ws + 2 * NB;
  float* B3 = ws + 3 * NB;
  float* B4 = ws + 4 * NB;
  float* sml = ws + 5 * NB;
  float* scc = sml;
  float* dcc = sml + 200000;
  float* ddc = sml + 400000;
  float* scd = sml + 600000;
  float* sdc = sml + 800000;
  float* dcd = sml + 1000000;
  float* scoreB = sml + 1200000;
  float* R0 = sml + 1200016;
  int*  R0i = (int*)R0;
  int*  offsBase  = R0i;                   // 150,004 ints (global offs)
  int*  elistBase = R0i + 150004;          // 1,200,000 ints (combined)
  int*  degBase   = R0i + 1350004;         // 150,000
  int*  cursorBase= R0i + 1500004;         // 150,000 (adjacent -> single memset)
  int*  inclBase  = R0i + 1650004;         // 150,000
  int*  bsumBase  = R0i + 1800004;         // 1,024
  unsigned short* kW1t = (unsigned short*)(R0i + 1801028);
  unsigned short* kW2t = (unsigned short*)(R0i + 1809220);
  unsigned short* pWt  = (unsigned short*)(R0i + 1817412);
  unsigned short* W1cH = (unsigned short*)(R0i + 1821508);
  unsigned short* W1cL = (unsigned short*)(R0i + 1837892);
  unsigned short* W1dH = (unsigned short*)(R0i + 1854276);
  unsigned short* W1dL = (unsigned short*)(R0i + 1870660);
  unsigned short* W2cH = (unsigned short*)(R0i + 1887044);
  unsigned short* W2cL = (unsigned short*)(R0i + 1895236);
  unsigned short* W2dH = (unsigned short*)(R0i + 1903428);
  unsigned short* W2dL = (unsigned short*)(R0i + 1911620);  // end 1,919,812 ints
  // fallback temps overlay (over CSR region)
  unsigned* mbuf = (unsigned*)R0;
  float*    sden = R0 + 200000;
  float*    ebuf = R0 + 400000;

  const size_t REQ_FLOATS = 5 * NB + 1200016 + 1919812;     // 35,119,828 fl = 140.5 MB
  const bool useCsr = ws_size >= REQ_FLOATS * sizeof(float);

  if (useCsr) {
    hipMemsetAsync(degBase, 0, 300000 * sizeof(int), stream);   // deg + cursor
    hist3<<<(3 * En + 255) / 256, 256, 0, stream>>>(ei_cc, ei_dc, ei_cd, degBase);
    scan_pass1<<<SCAN_NB, SCAN_BLK, 0, stream>>>(degBase, inclBase, bsumBase);
    scan_pass2<<<1, SCAN_BLK, 0, stream>>>(bsumBase, SCAN_NB);
    scan_pass3<<<SCAN_NB, SCAN_BLK, 0, stream>>>(inclBase, bsumBase, offsBase);
    fill3<<<(3 * En + 255) / 256, 256, 0, stream>>>(ei_cc, ei_dc, ei_cd,
                                                    offsBase, cursorBase, elistBase);
  }
  wprep<<<(139264 + 255) / 256, 256, 0, stream>>>(k1W, k2W, pW, W1c, W1d, W2c, W2d,
                                                  kW1t, kW2t, pWt,
                                                  W1cH, W1cL, W1dH, W1dL,
                                                  W2cH, W2cL, W2dH, W2dL);

  hipMemsetAsync(scoreB, 0, 8 * sizeof(float), stream);

  const int NT64 = (NCn + 63) / 64;
  const int* offs0 = offsBase;
  const int* offs1 = offsBase + 50000;
  const int* offs2 = offsBase + 100000;

  auto edge_layer = [&](void* hc, void* hd, void* oCC, void* oDC, void* oCD) {
    if (useCsr) {
      EdgeOp o0{offs0, elistBase, scc, dcc, (const __half*)hc, (__half*)oCC};
      EdgeOp o1{offs1, elistBase, sdc, ddc, (const __half*)hd, (__half*)oDC};
      EdgeOp o2{offs2, elistBase, scd, dcd, (const __half*)hc, (__half*)oCD};
      csr_att3<<<dim3((NCn + 3) / 4, 3), 256, 0, stream>>>(o0, o1, o2, NCn);
    } else {
      run_edge_fb(stream, ei_cc, scc, dcc, (const float*)hc, (float*)oCC, NCn, mbuf, sden, ebuf);
      run_edge_fb(stream, ei_dc, sdc, ddc, (const float*)hd, (float*)oDC, NCn, mbuf, sden, ebuf);
      run_edge_fb(stream, ei_cd, scd, dcd, (const float*)hc, (float*)oCD, NDn, mbuf, sden, ebuf);
    }
  };

  if (useCsr) {
    // ---------------- layer 1 ----------------
    gemm2_mfma<256, 0, 0, 0, 1><<<dim3(NT64, 2), 256, 0, stream>>>(
        xc, nullptr, nullptr, W1cH, W1cL, b1c, B0,
        xd, W1dH, W1dL, b1d, B1, NCn,
        a1s_cc, a1d_cc, a1d_dc, a1s_cd, a1s_dc, a1d_cd,
        scc, dcc, ddc, scd, sdc, dcd);
    edge_layer(B0, B1, B2, B3, B4);
    score_mfma<1><<<dim3(NT64, 2), 256, 0, stream>>>(B2, B3, kW1t, k1b, q1, NCn, scoreB);
    softmax2_kernel<<<1, 1, 0, stream>>>(scoreB);

    // ---------------- layer 2 ----------------
    gemm2_mfma<128, 2, 1, 1, 1><<<dim3(NT64, 2), 256, 0, stream>>>(
        B2, B3, scoreB, W2cH, W2cL, b2c, B0,
        B4, W2dH, W2dL, b2d, B1, NCn,
        a2s_cc, a2d_cc, a2d_dc, a2s_cd, a2s_dc, a2d_cd,
        scc, dcc, ddc, scd, sdc, dcd);
    edge_layer(B0, B1, B2, B3, B4);
    score_mfma<1><<<dim3(NT64, 2), 256, 0, stream>>>(B2, B3, kW2t, k2b, q2, NCn, scoreB + 4);
    softmax2_kernel<<<1, 1, 0, stream>>>(scoreB + 4);

    // ---------------- projection (merged) ----------------
    proj2_mfma<1><<<dim3(NT64, 2), 256, 0, stream>>>(B2, B3, scoreB + 4, B4, pWt, pb,
                                                     (float*)d_out,
                                                     (float*)d_out + (size_t)NCn * OUTn, NCn);
  } else {
    // ---------------- fp32 fallback ----------------
    gemm2_mfma<256, 0, 0, 0, 0><<<dim3(NT64, 2), 256, 0, stream>>>(
        xc, nullptr, nullptr, W1cH, W1cL, b1c, B0,
        xd, W1dH, W1dL, b1d, B1, NCn,
        a1s_cc, a1d_cc, a1d_dc, a1s_cd, a1s_dc, a1d_cd,
        scc, dcc, ddc, scd, sdc, dcd);
    edge_layer(B0, B1, B2, B3, B4);
    score_mfma<0><<<dim3(NT64, 2), 256, 0, stream>>>(B2, B3, kW1t, k1b, q1, NCn, scoreB);
    softmax2_kernel<<<1, 1, 0, stream>>>(scoreB);

    gemm2_mfma<128, 2, 1, 0, 0><<<dim3(NT64, 2), 256, 0, stream>>>(
        B2, B3, scoreB, W2cH, W2cL, b2c, B0,
        B4, W2dH, W2dL, b2d, B1, NCn,
        a2s_cc, a2d_cc, a2d_dc, a2s_cd, a2s_dc, a2d_cd,
        scc, dcc, ddc, scd, sdc, dcd);
    edge_layer(B0, B1, B2, B3, B4);
    score_mfma<0><<<dim3(NT64, 2), 256, 0, stream>>>(B2, B3, kW2t, k2b, q2, NCn, scoreB + 4);
    softmax2_kernel<<<1, 1, 0, stream>>>(scoreB + 4);

    proj2_mfma<0><<<dim3(NT64, 2), 256, 0, stream>>>(B2, B3, scoreB + 4, B4, pWt, pb,
                                                     (float*)d_out,
                                                     (float*)d_out + (size_t)NCn * OUTn, NCn);
  }
}

// Round 21
// 469.518 us; speedup vs baseline: 1.5566x; 1.0368x over previous
//
#include <hip/hip_runtime.h>
#include <hip/hip_fp16.h>
#include <cmath>

#define DEVI static __device__ __forceinline__

constexpr int HIDn = 128, OUTn = 64;
constexpr int NCn = 50000, NDn = 50000, En = 400000;
constexpr int SCAN_N = 150000, SCAN_BLK = 1024;
constexpr int SCAN_NB = (SCAN_N + SCAN_BLK - 1) / SCAN_BLK;   // 147

typedef __attribute__((ext_vector_type(8))) short bf16x8;
typedef __attribute__((ext_vector_type(4))) float f32x4;

// monotonic float->uint mapping for atomicMax on floats (handles signs)
DEVI unsigned fmap(float f) {
  int i = __float_as_int(f);
  return (i < 0) ? ~((unsigned)i) : (((unsigned)i) | 0x80000000u);
}
DEVI float fdecode(unsigned u) {
  int i = (u & 0x80000000u) ? (int)(u & 0x7fffffffu) : (int)(~u);
  return __int_as_float(i);
}

DEVI float tanh_fast(float x) {           // 1 - 2/(e^{2x}+1); saturates correctly
  float e = __expf(2.f * x);
  return 1.f - __fdividef(2.f, e + 1.f);
}

DEVI unsigned short f2bf(float x) {       // fp32 -> bf16 RNE
  unsigned u = __float_as_uint(x);
  return (unsigned short)((u + 0x7FFFu + ((u >> 16) & 1u)) >> 16);
}
DEVI float bf2f(unsigned short h) {
  unsigned u = ((unsigned)h) << 16;
  return __uint_as_float(u);
}

// ---- vectorized 8-wide A-row load + fused transform (value-based) -------
// MODE: 0=plain, 1=elu(x), 2=elu(w2*a+w3*b). HALF: input dtype fp16.
template<int MODE, int HALF>
DEVI void loadrow8(float* __restrict__ tmp,
                   const void* __restrict__ A, const void* __restrict__ A2,
                   float w2, float w3, size_t base)
{
  float v[8];
  if (HALF) {
    float4 raw = *(const float4*)((const __half*)A + base);
    const __half2* h2 = (const __half2*)&raw;
    #pragma unroll
    for (int j = 0; j < 4; ++j) {
      float2 f = __half22float2(h2[j]);
      v[2 * j] = f.x; v[2 * j + 1] = f.y;
    }
  } else {
    const float4* p = (const float4*)((const float*)A + base);
    float4 u0 = p[0], u1 = p[1];
    v[0] = u0.x; v[1] = u0.y; v[2] = u0.z; v[3] = u0.w;
    v[4] = u1.x; v[5] = u1.y; v[6] = u1.z; v[7] = u1.w;
  }
  if (MODE == 2) {
    float vb[8];
    if (HALF) {
      float4 raw = *(const float4*)((const __half*)A2 + base);
      const __half2* h2 = (const __half2*)&raw;
      #pragma unroll
      for (int j = 0; j < 4; ++j) {
        float2 f = __half22float2(h2[j]);
        vb[2 * j] = f.x; vb[2 * j + 1] = f.y;
      }
    } else {
      const float4* q = (const float4*)((const float*)A2 + base);
      float4 t0 = q[0], t1 = q[1];
      vb[0] = t0.x; vb[1] = t0.y; vb[2] = t0.z; vb[3] = t0.w;
      vb[4] = t1.x; vb[5] = t1.y; vb[6] = t1.z; vb[7] = t1.w;
    }
    #pragma unroll
    for (int i = 0; i < 8; ++i) v[i] = w2 * v[i] + w3 * vb[i];
  }
  if (MODE >= 1) {
    #pragma unroll
    for (int i = 0; i < 8; ++i) v[i] = (v[i] > 0.f) ? v[i] : (__expf(v[i]) - 1.f);
  }
  #pragma unroll
  for (int i = 0; i < 8; ++i) tmp[i] = v[i];
}

template<int MODE, int HALF>
DEVI bf16x8 packrow8(const void* __restrict__ A, const void* __restrict__ A2,
                     float w2, float w3, size_t base)
{
  float t[8];
  loadrow8<MODE, HALF>(t, A, A2, w2, w3, base);
  bf16x8 r;
  #pragma unroll
  for (int i = 0; i < 8; ++i) r[i] = (short)f2bf(t[i]);
  return r;
}

// ====== merged MFMA GEMM (c & d paths) + fused attention dots ============
// B operands pre-arranged in FRAGMENT ORDER: frag index (c*8+t)*64+lane,
// so every wave's B load is 1KB contiguous from the L2-resident table.
// No B LDS, no bank conflicts; only A staged in LDS (9KB).
template<int KI, int MODEc, int MODEd, int IN16, int OUT16>
__global__ __launch_bounds__(256)
void gemm2_mfma(const void* __restrict__ Ac, const void* __restrict__ Ac2,
                const float* __restrict__ wv,
                const unsigned short* __restrict__ WcH, const unsigned short* __restrict__ WcL,
                const float* __restrict__ bc, void* __restrict__ Cc,
                const void* __restrict__ Ad,
                const unsigned short* __restrict__ WdH, const unsigned short* __restrict__ WdL,
                const float* __restrict__ bd, void* __restrict__ Cd,
                int N,
                const float* __restrict__ avc0, const float* __restrict__ avc1,
                const float* __restrict__ avc2, const float* __restrict__ avc3,
                const float* __restrict__ avd0, const float* __restrict__ avd1,
                float* __restrict__ doc0, float* __restrict__ doc1,
                float* __restrict__ doc2, float* __restrict__ doc3,
                float* __restrict__ dod0, float* __restrict__ dod1)
{
  __shared__ float As[64][36];
  constexpr int NC = KI / 32;
  const bool isC = (blockIdx.y == 0);
  const void* A  = isC ? Ac : Ad;
  const void* A2 = isC ? Ac2 : nullptr;
  const bf16x8* WH = (const bf16x8*)(isC ? WcH : WdH);
  const bf16x8* WL = (const bf16x8*)(isC ? WcL : WdL);
  const float* bias = isC ? bc : bd;
  void* Cv = isC ? Cc : Cd;
  float w2 = 0.f, w3 = 0.f;
  if (MODEc == 2) { if (isC) { w2 = wv[2]; w3 = wv[3]; } }

  const int tid = threadIdx.x;
  const int w = tid >> 6, lane = tid & 63;
  const int m = lane & 15, b4 = lane >> 4;
  const int row0 = blockIdx.x * 64;
  const int row0w = row0 + w * 16;

  // staging thread roles (A only)
  const int rA = tid >> 2, kqA = (tid & 3) << 3;
  const int rowA = row0 + rA;

  f32x4 acc[8];
  #pragma unroll
  for (int t = 0; t < 8; ++t) acc[t] = (f32x4){0.f, 0.f, 0.f, 0.f};

  float tA[8];
  auto loadA = [&](int k0) {
    if (rowA < N) {
      if (isC) loadrow8<MODEc, IN16>(tA, A, A2, w2, w3, (size_t)rowA * KI + k0 + kqA);
      else     loadrow8<MODEd, IN16>(tA, A, nullptr, 0.f, 0.f, (size_t)rowA * KI + k0 + kqA);
    } else {
      #pragma unroll
      for (int i = 0; i < 8; ++i) tA[i] = 0.f;
    }
  };

  loadA(0);

  for (int c = 0; c < NC; ++c) {
    *(float4*)&As[rA][kqA]     = make_float4(tA[0], tA[1], tA[2], tA[3]);
    *(float4*)&As[rA][kqA + 4] = make_float4(tA[4], tA[5], tA[6], tA[7]);
    __syncthreads();

    if (c + 1 < NC) loadA((c + 1) * 32);

    bf16x8 ah, al;
    {
      const float* ap = &As[w * 16 + m][b4 * 8];
      float4 u0 = *(const float4*)ap;
      float4 u1 = *(const float4*)(ap + 4);
      float t8[8] = {u0.x, u0.y, u0.z, u0.w, u1.x, u1.y, u1.z, u1.w};
      #pragma unroll
      for (int i = 0; i < 8; ++i) {
        unsigned short h = f2bf(t8[i]);
        ah[i] = (short)h;
        al[i] = (short)f2bf(t8[i] - bf2f(h));
      }
    }
    #pragma unroll
    for (int t = 0; t < 8; ++t) {
      const int fi = (c * 8 + t) * 64 + lane;
      bf16x8 bh = WH[fi];
      bf16x8 bl = WL[fi];
      acc[t] = __builtin_amdgcn_mfma_f32_16x16x32_bf16(ah, bh, acc[t], 0, 0, 0);
      acc[t] = __builtin_amdgcn_mfma_f32_16x16x32_bf16(al, bh, acc[t], 0, 0, 0);
      acc[t] = __builtin_amdgcn_mfma_f32_16x16x32_bf16(ah, bl, acc[t], 0, 0, 0);
    }
    __syncthreads();
  }

  // ---- epilogue: bias + C store ----
  float bt[8];
  #pragma unroll
  for (int t = 0; t < 8; ++t) bt[t] = bias[t * 16 + m];

  #pragma unroll
  for (int t = 0; t < 8; ++t) {
    const int col = t * 16 + m;
    #pragma unroll
    for (int r = 0; r < 4; ++r) {
      const int row = row0w + b4 * 4 + r;
      if (row < N) {
        float v = acc[t][r] + bt[t];
        if (OUT16) ((__half*)Cv)[(size_t)row * 128 + col] = __float2half(v);
        else       ((float*)Cv)[(size_t)row * 128 + col] = v;
      }
    }
  }

  // ---- fused attention dots: per (row, head) reduce over 16 m-lanes ----
  const float* avp[4];
  float* dop[4];
  int nv;
  if (isC) {
    avp[0] = avc0; avp[1] = avc1; avp[2] = avc2; avp[3] = avc3;
    dop[0] = doc0; dop[1] = doc1; dop[2] = doc2; dop[3] = doc3; nv = 4;
  } else {
    avp[0] = avd0; avp[1] = avd1; avp[2] = avd0; avp[3] = avd1;
    dop[0] = dod0; dop[1] = dod1; dop[2] = dod0; dop[3] = dod1; nv = 2;
  }
  float avv[4][8];
  #pragma unroll
  for (int v = 0; v < 4; ++v) {
    if (v < nv) {
      #pragma unroll
      for (int t = 0; t < 8; ++t) avv[v][t] = avp[v][t * 16 + m];
    }
  }
  #pragma unroll
  for (int h = 0; h < 4; ++h) {
    #pragma unroll
    for (int v = 0; v < 4; ++v) {
      if (v < nv) {
        #pragma unroll
        for (int r = 0; r < 4; ++r) {
          float p = (acc[2 * h][r] + bt[2 * h]) * avv[v][2 * h]
                  + (acc[2 * h + 1][r] + bt[2 * h + 1]) * avv[v][2 * h + 1];
          p += __shfl_xor(p, 1);
          p += __shfl_xor(p, 2);
          p += __shfl_xor(p, 4);
          p += __shfl_xor(p, 8);
          if (m == 0) {
            const int row = row0w + b4 * 4 + r;
            if (row < N) dop[v][(size_t)row * 4 + h] = p;
          }
        }
      }
    }
  }
}

// ================= CSR build: hist + 3-pass scan + fill ==================
__global__ void hist3(const int* __restrict__ ei0, const int* __restrict__ ei1,
                      const int* __restrict__ ei2, int* __restrict__ deg)
{
  int gid = blockIdx.x * blockDim.x + threadIdx.x;
  if (gid >= 3 * En) return;
  int g = gid / En, e = gid - g * En;
  const int* ei = (g == 0) ? ei0 : (g == 1) ? ei1 : ei2;
  atomicAdd(&deg[g * 50000 + ei[En + e]], 1);
}

__global__ void scan_pass1(const int* __restrict__ deg, int* __restrict__ incl,
                           int* __restrict__ bsum)
{
  __shared__ int wsum[16];
  int tid = threadIdx.x;
  int gid = blockIdx.x * SCAN_BLK + tid;
  int v = (gid < SCAN_N) ? deg[gid] : 0;
  int lane = tid & 63, w = tid >> 6;
  int x = v;
  #pragma unroll
  for (int off = 1; off < 64; off <<= 1) {
    int y = __shfl_up(x, off);
    if (lane >= off) x += y;
  }
  if (lane == 63) wsum[w] = x;
  __syncthreads();
  if (tid == 0) {
    int s = 0;
    #pragma unroll
    for (int ww = 0; ww < 16; ++ww) { int t = wsum[ww]; wsum[ww] = s; s += t; }
    bsum[blockIdx.x] = s;
  }
  __syncthreads();
  x += wsum[w];
  if (gid < SCAN_N) incl[gid] = x;
}

__global__ void scan_pass2(int* __restrict__ bsum, int nb)
{
  __shared__ int wsum[16];
  int tid = threadIdx.x;
  int v = (tid < nb) ? bsum[tid] : 0;
  int lane = tid & 63, w = tid >> 6;
  int x = v;
  #pragma unroll
  for (int off = 1; off < 64; off <<= 1) {
    int y = __shfl_up(x, off);
    if (lane >= off) x += y;
  }
  if (lane == 63) wsum[w] = x;
  __syncthreads();
  if (tid == 0) {
    int s = 0;
    #pragma unroll
    for (int ww = 0; ww < 16; ++ww) { int t = wsum[ww]; wsum[ww] = s; s += t; }
  }
  __syncthreads();
  x += wsum[w];
  if (tid < nb) bsum[tid] = x - v;
}

__global__ void scan_pass3(const int* __restrict__ incl, const int* __restrict__ bsum,
                           int* __restrict__ offs)
{
  int gid = blockIdx.x * SCAN_BLK + threadIdx.x;
  if (gid == 0) offs[0] = 0;
  if (gid < SCAN_N) offs[gid + 1] = incl[gid] + bsum[gid / SCAN_BLK];
}

__global__ void fill3(const int* __restrict__ ei0, const int* __restrict__ ei1,
                      const int* __restrict__ ei2, const int* __restrict__ offs,
                      int* __restrict__ cursor, int* __restrict__ elist)
{
  int gid = blockIdx.x * blockDim.x + threadIdx.x;
  if (gid >= 3 * En) return;
  int g = gid / En, e = gid - g * En;
  const int* ei = (g == 0) ? ei0 : (g == 1) ? ei1 : ei2;
  int s = ei[e], d = g * 50000 + ei[En + e];
  int p = atomicAdd(&cursor[d], 1);
  elist[offs[d] + p] = s;
}

// ---- weight prep: all B operands in MFMA fragment order -----------------
// gemm W (KI x 128): f = ((c*8+t)*64 + m+16*b4)*8 + j,
//   c=k>>5, b4=(k>>3)&3, j=k&7, t=col>>4, m=col&15.   (hi+lo planes)
// score kW (128x128): f = ((t*4+ks)*64 + m+16*b4)*8 + j, ks=k>>5.
// proj pW (128x64):  same as score with t<4.
__global__ void wprep(const float* __restrict__ k1W, const float* __restrict__ k2W,
                      const float* __restrict__ pW,
                      const float* __restrict__ W1c, const float* __restrict__ W1d,
                      const float* __restrict__ W2c, const float* __restrict__ W2d,
                      unsigned short* kW1t, unsigned short* kW2t, unsigned short* pWt,
                      unsigned short* W1cH, unsigned short* W1cL,
                      unsigned short* W1dH, unsigned short* W1dL,
                      unsigned short* W2cH, unsigned short* W2cL,
                      unsigned short* W2dH, unsigned short* W2dL)
{
  int gid = blockIdx.x * 256 + threadIdx.x;
  if (gid < 16384) {                       // k1W: 128x128
    int i = gid, k = i >> 7, col = i & 127;
    int ks = k >> 5, b4 = (k >> 3) & 3, j = k & 7, t = col >> 4, m = col & 15;
    kW1t[(size_t)(((t * 4 + ks) * 64) + m + 16 * b4) * 8 + j] = f2bf(k1W[i]);
  } else if (gid < 32768) {                // k2W: 128x128
    int i = gid - 16384, k = i >> 7, col = i & 127;
    int ks = k >> 5, b4 = (k >> 3) & 3, j = k & 7, t = col >> 4, m = col & 15;
    kW2t[(size_t)(((t * 4 + ks) * 64) + m + 16 * b4) * 8 + j] = f2bf(k2W[i]);
  } else if (gid < 40960) {                // pW: 128x64
    int i = gid - 32768, k = i / 64, col = i - k * 64;
    int ks = k >> 5, b4 = (k >> 3) & 3, j = k & 7, t = col >> 4, m = col & 15;
    pWt[(size_t)(((t * 4 + ks) * 64) + m + 16 * b4) * 8 + j] = f2bf(pW[i]);
  } else if (gid < 73728) {                // W1c: 256x128
    int i = gid - 40960, k = i >> 7, col = i & 127;
    int c = k >> 5, b4 = (k >> 3) & 3, j = k & 7, t = col >> 4, m = col & 15;
    size_t f = (size_t)(((c * 8 + t) * 64) + m + 16 * b4) * 8 + j;
    float v = W1c[i]; unsigned short h = f2bf(v);
    W1cH[f] = h; W1cL[f] = f2bf(v - bf2f(h));
  } else if (gid < 106496) {               // W1d: 256x128
    int i = gid - 73728, k = i >> 7, col = i & 127;
    int c = k >> 5, b4 = (k >> 3) & 3, j = k & 7, t = col >> 4, m = col & 15;
    size_t f = (size_t)(((c * 8 + t) * 64) + m + 16 * b4) * 8 + j;
    float v = W1d[i]; unsigned short h = f2bf(v);
    W1dH[f] = h; W1dL[f] = f2bf(v - bf2f(h));
  } else if (gid < 122880) {               // W2c: 128x128
    int i = gid - 106496, k = i >> 7, col = i & 127;
    int c = k >> 5, b4 = (k >> 3) & 3, j = k & 7, t = col >> 4, m = col & 15;
    size_t f = (size_t)(((c * 8 + t) * 64) + m + 16 * b4) * 8 + j;
    float v = W2c[i]; unsigned short h = f2bf(v);
    W2cH[f] = h; W2cL[f] = f2bf(v - bf2f(h));
  } else if (gid < 139264) {               // W2d: 128x128
    int i = gid - 122880, k = i >> 7, col = i & 127;
    int c = k >> 5, b4 = (k >> 3) & 3, j = k & 7, t = col >> 4, m = col & 15;
    size_t f = (size_t)(((c * 8 + t) * 64) + m + 16 * b4) * 8 + j;
    float v = W2d[i]; unsigned short h = f2bf(v);
    W2dH[f] = h; W2dL[f] = f2bf(v - bf2f(h));
  }
}

// ==== FUSED edge attention (CSR, fp16 h, lane-specialized softmax) =======
struct EdgeOp {
  const int* offs; const int* elist;
  const float* sdot; const float* ddot;
  const __half* hsrc; __half* out;
};

DEVI void csr_att_body(const EdgeOp& op, int dst, int lane)
{
  const int i0 = op.offs[dst], i1 = op.offs[dst + 1];
  const int hB = lane >> 4;
  const float ddv = op.ddot[dst * 4 + hB];
  const __half* hsrc = op.hsrc;
  const float* sdot = op.sdot;
  const int* el = op.elist;
  const int wsel = lane & 48;
  float den = 0.f, a0 = 0.f, a1 = 0.f;

  for (int base = i0; base < i1; base += 16) {
    int i = base + (lane & 15);
    int s_ = 0;
    float w = 0.f;
    if (i < i1) {
      s_ = el[i];
      float lv = sdot[s_ * 4 + hB] + ddv;
      lv = fminf(fmaxf(lv, 0.2f * lv), 80.f);
      w = __expf(lv);
    }
    float g = w;
    g += __shfl_xor(g, 1);
    g += __shfl_xor(g, 2);
    g += __shfl_xor(g, 4);
    g += __shfl_xor(g, 8);
    den += g;

    const int rem = min(16, i1 - base);
    int j = 0;
    for (; j + 2 <= rem; j += 2) {
      int sA = __shfl(s_, j);
      int sB = __shfl(s_, j + 1);
      float wA = __shfl(w, wsel | j);
      float wB = __shfl(w, wsel | (j + 1));
      float2 hA = __half22float2(*(const __half2*)(hsrc + (size_t)sA * HIDn + lane * 2));
      float2 hBv = __half22float2(*(const __half2*)(hsrc + (size_t)sB * HIDn + lane * 2));
      a0 += hA.x * wA + hBv.x * wB;
      a1 += hA.y * wA + hBv.y * wB;
    }
    if (j < rem) {
      int sA = __shfl(s_, j);
      float wA = __shfl(w, wsel | j);
      float2 hA = __half22float2(*(const __half2*)(hsrc + (size_t)sA * HIDn + lane * 2));
      a0 += hA.x * wA;
      a1 += hA.y * wA;
    }
  }
  float dinv = __fdividef(1.f, den + 1e-16f);
  __half2 o2 = __floats2half2_rn(fmaxf(a0 * dinv, 0.f), fmaxf(a1 * dinv, 0.f));
  *(__half2*)(op.out + (size_t)dst * HIDn + lane * 2) = o2;
}

__global__ __launch_bounds__(256)
void csr_att3(EdgeOp op0, EdgeOp op1, EdgeOp op2, int Ndst)
{
  int wave = (blockIdx.x * 256 + threadIdx.x) >> 6;
  if (wave >= Ndst) return;
  const int lane = threadIdx.x & 63;
  if (blockIdx.y == 0)      csr_att_body(op0, wave, lane);
  else if (blockIdx.y == 1) csr_att_body(op1, wave, lane);
  else                      csr_att_body(op2, wave, lane);
}

// ---- fallback path (atomic scatter, fp32 h), used only if ws too small --
__global__ void edge_logit_max(const int* __restrict__ ei,
                               const float* __restrict__ sdot,
                               const float* __restrict__ ddot,
                               unsigned* __restrict__ m)
{
  int e = blockIdx.x * blockDim.x + threadIdx.x;
  if (e >= En) return;
  int s = ei[e], d = ei[En + e];
  #pragma unroll
  for (int hh = 0; hh < 4; ++hh) {
    float l = sdot[s * 4 + hh] + ddot[d * 4 + hh];
    l = (l > 0.f) ? l : 0.2f * l;
    atomicMax(&m[d * 4 + hh], fmap(l));
  }
}

__global__ void edge_exp_sum(const int* __restrict__ ei,
                             const float* __restrict__ sdot,
                             const float* __restrict__ ddot,
                             const unsigned* __restrict__ m,
                             float* __restrict__ sden,
                             float* __restrict__ ebuf)
{
  int e = blockIdx.x * blockDim.x + threadIdx.x;
  if (e >= En) return;
  int s = ei[e], d = ei[En + e];
  #pragma unroll
  for (int hh = 0; hh < 4; ++hh) {
    float l = sdot[s * 4 + hh] + ddot[d * 4 + hh];
    l = (l > 0.f) ? l : 0.2f * l;
    float ex = expf(fminf(l - fdecode(m[d * 4 + hh]), 0.f));
    ebuf[e * 4 + hh] = ex;
    atomicAdd(&sden[d * 4 + hh], ex);
  }
}

__global__ __launch_bounds__(256)
void edge_scatter(const int* __restrict__ ei, const float* __restrict__ hsrc,
                  const float* __restrict__ ebuf, const float* __restrict__ sden,
                  float* __restrict__ out)
{
  int gid  = blockIdx.x * 256 + threadIdx.x;
  int e    = gid >> 6;
  if (e >= En) return;
  int lane = gid & 63;
  int s = ei[e], d = ei[En + e];
  #pragma unroll
  for (int half = 0; half < 2; ++half) {
    int c  = lane + half * 64;
    int hh = c >> 5;
    float alpha = ebuf[e * 4 + hh] / (sden[d * 4 + hh] + 1e-16f);
    atomicAdd(&out[(size_t)d * HIDn + c], hsrc[(size_t)s * HIDn + c] * alpha);
  }
}

__global__ void relu_k(float* __restrict__ x, int n)
{
  int i = blockIdx.x * blockDim.x + threadIdx.x;
  if (i < n) x[i] = fmaxf(x[i], 0.f);
}

// ---- semantic-attention score via MFMA bf16 (fragment-ordered kWt) ------
template<int IN16>
__global__ __launch_bounds__(256)
void score_mfma(const void* __restrict__ oA, const void* __restrict__ oB,
                const unsigned short* __restrict__ kWt,
                const float* __restrict__ kb, const float* __restrict__ q,
                int N, float* __restrict__ slots)
{
  __shared__ float partw[4];
  const void* o = blockIdx.y ? oB : oA;
  const int tid = threadIdx.x;
  const int w = tid >> 6, lane = tid & 63;
  const int row0 = (blockIdx.x * 4 + w) * 16;
  const int m = lane & 15, b = lane >> 4;
  const int arow = row0 + m;
  const bool rok = arow < N;
  const bf16x8* WT = (const bf16x8*)kWt;

  const bf16x8 zfr = {0, 0, 0, 0, 0, 0, 0, 0};
  bf16x8 afr[4];
  {
    const size_t base = (size_t)arow * 128;
    #pragma unroll
    for (int ks = 0; ks < 4; ++ks) {
      if (rok) afr[ks] = packrow8<0, IN16>(o, nullptr, 0.f, 0.f, base + ks * 32 + b * 8);
      else     afr[ks] = zfr;
    }
  }

  float sum = 0.f;
  #pragma unroll
  for (int t = 0; t < 8; ++t) {
    f32x4 acc = {0.f, 0.f, 0.f, 0.f};
    const int col = t * 16 + m;
    #pragma unroll
    for (int ks = 0; ks < 4; ++ks)
      acc = __builtin_amdgcn_mfma_f32_16x16x32_bf16(afr[ks], WT[(t * 4 + ks) * 64 + lane], acc, 0, 0, 0);
    const float qc = q[col], kbc = kb[col];
    #pragma unroll
    for (int r = 0; r < 4; ++r) {
      int row = row0 + b * 4 + r;
      if (row < N) sum += qc * tanh_fast(acc[r] + kbc);
    }
  }
  #pragma unroll
  for (int off = 32; off > 0; off >>= 1) sum += __shfl_down(sum, off);
  if (lane == 0) partw[w] = sum;
  __syncthreads();
  if (tid == 0)
    atomicAdd(&slots[blockIdx.y],
              (partw[0] + partw[1] + partw[2] + partw[3]) * (1.f / (float)N));
}

__global__ void softmax2_kernel(float* sb)   // sb[0],sb[1] -> weights sb[2],sb[3]
{
  float s0 = sb[0], s1 = sb[1];
  float mx = fmaxf(s0, s1);
  float e0 = expf(s0 - mx), e1 = expf(s1 - mx);
  float inv = 1.f / (e0 + e1);
  sb[2] = e0 * inv;
  sb[3] = e1 * inv;
}

// ---- merged final projection via MFMA bf16 (fragment-ordered pWt) -------
template<int IN16>
__global__ __launch_bounds__(256)
void proj2_mfma(const void* __restrict__ fa, const void* __restrict__ fb,
                const float* __restrict__ wv, const void* __restrict__ fd,
                const unsigned short* __restrict__ pWt, const float* __restrict__ pb,
                float* __restrict__ outc, float* __restrict__ outd, int N)
{
  const bool isC = (blockIdx.y == 0);
  const int tid = threadIdx.x;
  const int w = tid >> 6, lane = tid & 63;
  const int row0 = (blockIdx.x * 4 + w) * 16;
  const int m = lane & 15, b = lane >> 4;
  const int arow = row0 + m;
  const bool rok = arow < N;
  float* out = isC ? outc : outd;
  const bf16x8* WT = (const bf16x8*)pWt;

  const bf16x8 zfr = {0, 0, 0, 0, 0, 0, 0, 0};
  bf16x8 afr[4];
  {
    const size_t base = (size_t)arow * 128;
    if (isC) {
      const float w2 = wv[2], w3 = wv[3];
      #pragma unroll
      for (int ks = 0; ks < 4; ++ks) {
        if (rok) afr[ks] = packrow8<2, IN16>(fa, fb, w2, w3, base + ks * 32 + b * 8);
        else     afr[ks] = zfr;
      }
    } else {
      #pragma unroll
      for (int ks = 0; ks < 4; ++ks) {
        if (rok) afr[ks] = packrow8<1, IN16>(fd, nullptr, 0.f, 0.f, base + ks * 32 + b * 8);
        else     afr[ks] = zfr;
      }
    }
  }

  f32x4 accs[4];
  float pbc[4];
  #pragma unroll
  for (int t = 0; t < 4; ++t) {
    f32x4 acc = {0.f, 0.f, 0.f, 0.f};
    const int col = t * 16 + m;
    #pragma unroll
    for (int ks = 0; ks < 4; ++ks)
      acc = __builtin_amdgcn_mfma_f32_16x16x32_bf16(afr[ks], WT[(t * 4 + ks) * 64 + lane], acc, 0, 0, 0);
    accs[t] = acc;
    pbc[t] = pb[col];
  }

  #pragma unroll
  for (int r = 0; r < 4; ++r) {
    const int row = row0 + b * 4 + r;
    float v[4];
    #pragma unroll
    for (int t = 0; t < 4; ++t) v[t] = accs[t][r] + pbc[t];
    if (isC) {
      float ss = v[0]*v[0] + v[1]*v[1] + v[2]*v[2] + v[3]*v[3];
      ss += __shfl_xor(ss, 1);
      ss += __shfl_xor(ss, 2);
      ss += __shfl_xor(ss, 4);
      ss += __shfl_xor(ss, 8);
      float inv = 1.f / fmaxf(sqrtf(ss), 1e-12f);
      #pragma unroll
      for (int t = 0; t < 4; ++t) v[t] *= inv;
    }
    if (row < N) {
      #pragma unroll
      for (int t = 0; t < 4; ++t)
        out[(size_t)row * OUTn + t * 16 + m] = v[t];
    }
  }
}

// ---- fallback edge-op dispatcher ----------------------------------------
static void run_edge_fb(hipStream_t stream, const int* ei,
                        const float* sdot, const float* ddot, const float* hsrc,
                        float* outb, int Ndst,
                        unsigned* mbuf, float* sden, float* ebuf)
{
  hipMemsetAsync(mbuf, 0, (size_t)Ndst * 4 * sizeof(unsigned), stream);
  edge_logit_max<<<(En + 255) / 256, 256, 0, stream>>>(ei, sdot, ddot, mbuf);
  hipMemsetAsync(sden, 0, (size_t)Ndst * 4 * sizeof(float), stream);
  edge_exp_sum<<<(En + 255) / 256, 256, 0, stream>>>(ei, sdot, ddot, mbuf, sden, ebuf);
  hipMemsetAsync(outb, 0, (size_t)Ndst * HIDn * sizeof(float), stream);
  edge_scatter<<<((size_t)En * 64 + 255) / 256, 256, 0, stream>>>(ei, hsrc, ebuf, sden, outb);
  relu_k<<<((size_t)Ndst * HIDn + 255) / 256, 256, 0, stream>>>(outb, Ndst * HIDn);
}

extern "C" void kernel_launch(void* const* d_in, const int* in_sizes, int n_in,
                              void* d_out, int out_size, void* d_ws, size_t ws_size,
                              hipStream_t stream)
{
  const float* xc    = (const float*)d_in[0];
  const float* xd    = (const float*)d_in[1];
  const int*   ei_cc = (const int*)d_in[2];
  const int*   ei_dc = (const int*)d_in[3];
  const int*   ei_cd = (const int*)d_in[4];
  const float* W1c = (const float*)d_in[5];  const float* b1c = (const float*)d_in[6];
  const float* W1d = (const float*)d_in[7];  const float* b1d = (const float*)d_in[8];
  const float* a1s_cc = (const float*)d_in[9];  const float* a1d_cc = (const float*)d_in[10];
  const float* a1s_dc = (const float*)d_in[11]; const float* a1d_dc = (const float*)d_in[12];
  const float* a1s_cd = (const float*)d_in[13]; const float* a1d_cd = (const float*)d_in[14];
  const float* k1W = (const float*)d_in[15]; const float* k1b = (const float*)d_in[16];
  const float* q1  = (const float*)d_in[17];
  const float* W2c = (const float*)d_in[18]; const float* b2c = (const float*)d_in[19];
  const float* W2d = (const float*)d_in[20]; const float* b2d = (const float*)d_in[21];
  const float* a2s_cc = (const float*)d_in[22]; const float* a2d_cc = (const float*)d_in[23];
  const float* a2s_dc = (const float*)d_in[24]; const float* a2d_dc = (const float*)d_in[25];
  const float* a2s_cd = (const float*)d_in[26]; const float* a2d_cd = (const float*)d_in[27];
  const float* k2W = (const float*)d_in[28]; const float* k2b = (const float*)d_in[29];
  const float* q2  = (const float*)d_in[30];
  const float* pW  = (const float*)d_in[31]; const float* pb  = (const float*)d_in[32];

  // ---------------- workspace layout ----------------
  float* ws = (float*)d_ws;
  const size_t NB = (size_t)NCn * HIDn;
  float* B0 = ws;            // node buffers (fp16 in CSR mode, fp32 fallback)
  float* B1 = ws + NB;
  float* B2 = ws + 2 * NB;
  float* B3 = ws + 3 * NB;
  float* B4 = ws + 4 * NB;
  float* sml = ws + 5 * NB;
  float* scc = sml;
  float* dcc = sml + 200000;
  float* ddc = sml + 400000;
  float* scd = sml + 600000;
  float* sdc = sml + 800000;
  float* dcd = sml + 1000000;
  float* scoreB = sml + 1200000;
  float* R0 = sml + 1200016;
  int*  R0i = (int*)R0;
  int*  offsBase  = R0i;                   // 150,004 ints (global offs)
  int*  elistBase = R0i + 150004;          // 1,200,000 ints (combined)
  int*  degBase   = R0i + 1350004;         // 150,000
  int*  cursorBase= R0i + 1500004;         // 150,000 (adjacent -> single memset)
  int*  inclBase  = R0i + 1650004;         // 150,000
  int*  bsumBase  = R0i + 1800004;         // 1,024
  unsigned short* kW1t = (unsigned short*)(R0i + 1801028);
  unsigned short* kW2t = (unsigned short*)(R0i + 1809220);
  unsigned short* pWt  = (unsigned short*)(R0i + 1817412);
  unsigned short* W1cH = (unsigned short*)(R0i + 1821508);
  unsigned short* W1cL = (unsigned short*)(R0i + 1837892);
  unsigned short* W1dH = (unsigned short*)(R0i + 1854276);
  unsigned short* W1dL = (unsigned short*)(R0i + 1870660);
  unsigned short* W2cH = (unsigned short*)(R0i + 1887044);
  unsigned short* W2cL = (unsigned short*)(R0i + 1895236);
  unsigned short* W2dH = (unsigned short*)(R0i + 1903428);
  unsigned short* W2dL = (unsigned short*)(R0i + 1911620);  // end 1,919,812 ints
  // fallback temps overlay (over CSR region)
  unsigned* mbuf = (unsigned*)R0;
  float*    sden = R0 + 200000;
  float*    ebuf = R0 + 400000;

  const size_t REQ_FLOATS = 5 * NB + 1200016 + 1919812;     // 35,119,828 fl = 140.5 MB
  const bool useCsr = ws_size >= REQ_FLOATS * sizeof(float);

  if (useCsr) {
    hipMemsetAsync(degBase, 0, 300000 * sizeof(int), stream);   // deg + cursor
    hist3<<<(3 * En + 255) / 256, 256, 0, stream>>>(ei_cc, ei_dc, ei_cd, degBase);
    scan_pass1<<<SCAN_NB, SCAN_BLK, 0, stream>>>(degBase, inclBase, bsumBase);
    scan_pass2<<<1, SCAN_BLK, 0, stream>>>(bsumBase, SCAN_NB);
    scan_pass3<<<SCAN_NB, SCAN_BLK, 0, stream>>>(inclBase, bsumBase, offsBase);
    fill3<<<(3 * En + 255) / 256, 256, 0, stream>>>(ei_cc, ei_dc, ei_cd,
                                                    offsBase, cursorBase, elistBase);
  }
  wprep<<<(139264 + 255) / 256, 256, 0, stream>>>(k1W, k2W, pW, W1c, W1d, W2c, W2d,
                                                  kW1t, kW2t, pWt,
                                                  W1cH, W1cL, W1dH, W1dL,
                                                  W2cH, W2cL, W2dH, W2dL);

  hipMemsetAsync(scoreB, 0, 8 * sizeof(float), stream);

  const int NT64 = (NCn + 63) / 64;
  const int* offs0 = offsBase;
  const int* offs1 = offsBase + 50000;
  const int* offs2 = offsBase + 100000;

  auto edge_layer = [&](void* hc, void* hd, void* oCC, void* oDC, void* oCD) {
    if (useCsr) {
      EdgeOp o0{offs0, elistBase, scc, dcc, (const __half*)hc, (__half*)oCC};
      EdgeOp o1{offs1, elistBase, sdc, ddc, (const __half*)hd, (__half*)oDC};
      EdgeOp o2{offs2, elistBase, scd, dcd, (const __half*)hc, (__half*)oCD};
      csr_att3<<<dim3((NCn + 3) / 4, 3), 256, 0, stream>>>(o0, o1, o2, NCn);
    } else {
      run_edge_fb(stream, ei_cc, scc, dcc, (const float*)hc, (float*)oCC, NCn, mbuf, sden, ebuf);
      run_edge_fb(stream, ei_dc, sdc, ddc, (const float*)hd, (float*)oDC, NCn, mbuf, sden, ebuf);
      run_edge_fb(stream, ei_cd, scd, dcd, (const float*)hc, (float*)oCD, NDn, mbuf, sden, ebuf);
    }
  };

  if (useCsr) {
    // ---------------- layer 1 ----------------
    gemm2_mfma<256, 0, 0, 0, 1><<<dim3(NT64, 2), 256, 0, stream>>>(
        xc, nullptr, nullptr, W1cH, W1cL, b1c, B0,
        xd, W1dH, W1dL, b1d, B1, NCn,
        a1s_cc, a1d_cc, a1d_dc, a1s_cd, a1s_dc, a1d_cd,
        scc, dcc, ddc, scd, sdc, dcd);
    edge_layer(B0, B1, B2, B3, B4);
    score_mfma<1><<<dim3(NT64, 2), 256, 0, stream>>>(B2, B3, kW1t, k1b, q1, NCn, scoreB);
    softmax2_kernel<<<1, 1, 0, stream>>>(scoreB);

    // ---------------- layer 2 ----------------
    gemm2_mfma<128, 2, 1, 1, 1><<<dim3(NT64, 2), 256, 0, stream>>>(
        B2, B3, scoreB, W2cH, W2cL, b2c, B0,
        B4, W2dH, W2dL, b2d, B1, NCn,
        a2s_cc, a2d_cc, a2d_dc, a2s_cd, a2s_dc, a2d_cd,
        scc, dcc, ddc, scd, sdc, dcd);
    edge_layer(B0, B1, B2, B3, B4);
    score_mfma<1><<<dim3(NT64, 2), 256, 0, stream>>>(B2, B3, kW2t, k2b, q2, NCn, scoreB + 4);
    softmax2_kernel<<<1, 1, 0, stream>>>(scoreB + 4);

    // ---------------- projection (merged) ----------------
    proj2_mfma<1><<<dim3(NT64, 2), 256, 0, stream>>>(B2, B3, scoreB + 4, B4, pWt, pb,
                                                     (float*)d_out,
                                                     (float*)d_out + (size_t)NCn * OUTn, NCn);
  } else {
    // ---------------- fp32 fallback ----------------
    gemm2_mfma<256, 0, 0, 0, 0><<<dim3(NT64, 2), 256, 0, stream>>>(
        xc, nullptr, nullptr, W1cH, W1cL, b1c, B0,
        xd, W1dH, W1dL, b1d, B1, NCn,
        a1s_cc, a1d_cc, a1d_dc, a1s_cd, a1s_dc, a1d_cd,
        scc, dcc, ddc, scd, sdc, dcd);
    edge_layer(B0, B1, B2, B3, B4);
    score_mfma<0><<<dim3(NT64, 2), 256, 0, stream>>>(B2, B3, kW1t, k1b, q1, NCn, scoreB);
    softmax2_kernel<<<1, 1, 0, stream>>>(scoreB);

    gemm2_mfma<128, 2, 1, 0, 0><<<dim3(NT64, 2), 256, 0, stream>>>(
        B2, B3, scoreB, W2cH, W2cL, b2c, B0,
        B4, W2dH, W2dL, b2d, B1, NCn,
        a2s_cc, a2d_cc, a2d_dc, a2s_cd, a2s_dc, a2d_cd,
        scc, dcc, ddc, scd, sdc, dcd);
    edge_layer(B0, B1, B2, B3, B4);
    score_mfma<0><<<dim3(NT64, 2), 256, 0, stream>>>(B2, B3, kW2t, k2b, q2, NCn, scoreB + 4);
    softmax2_kernel<<<1, 1, 0, stream>>>(scoreB + 4);

    proj2_mfma<0><<<dim3(NT64, 2), 256, 0, stream>>>(B2, B3, scoreB + 4, B4, pWt, pb,
                                                     (float*)d_out,
                                                     (float*)d_out + (size_t)NCn * OUTn, NCn);
  }
}

// Round 22
// 443.402 us; speedup vs baseline: 1.6483x; 1.0589x over previous
//
#include <hip/hip_runtime.h>
#include <hip/hip_fp16.h>
#include <cmath>

#define DEVI static __device__ __forceinline__

constexpr int HIDn = 128, OUTn = 64;
constexpr int NCn = 50000, NDn = 50000, En = 400000;
constexpr int SCAN_N = 150000, SCAN_BLK = 1024;
constexpr int SCAN_NB = (SCAN_N + SCAN_BLK - 1) / SCAN_BLK;   // 147

typedef __attribute__((ext_vector_type(8))) short bf16x8;
typedef __attribute__((ext_vector_type(4))) float f32x4;

// monotonic float->uint mapping for atomicMax on floats (handles signs)
DEVI unsigned fmap(float f) {
  int i = __float_as_int(f);
  return (i < 0) ? ~((unsigned)i) : (((unsigned)i) | 0x80000000u);
}
DEVI float fdecode(unsigned u) {
  int i = (u & 0x80000000u) ? (int)(u & 0x7fffffffu) : (int)(~u);
  return __int_as_float(i);
}

DEVI float tanh_fast(float x) {           // 1 - 2/(e^{2x}+1); saturates correctly
  float e = __expf(2.f * x);
  return 1.f - __fdividef(2.f, e + 1.f);
}

DEVI unsigned short f2bf(float x) {       // fp32 -> bf16 RNE
  unsigned u = __float_as_uint(x);
  return (unsigned short)((u + 0x7FFFu + ((u >> 16) & 1u)) >> 16);
}
DEVI float bf2f(unsigned short h) {
  unsigned u = ((unsigned)h) << 16;
  return __uint_as_float(u);
}

// ---- vectorized 8-wide A-row load + fused transform (value-based) -------
// MODE: 0=plain, 1=elu(x), 2=elu(w2*a+w3*b). HALF: input dtype fp16.
template<int MODE, int HALF>
DEVI void loadrow8(float* __restrict__ tmp,
                   const void* __restrict__ A, const void* __restrict__ A2,
                   float w2, float w3, size_t base)
{
  float v[8];
  if (HALF) {
    float4 raw = *(const float4*)((const __half*)A + base);
    const __half2* h2 = (const __half2*)&raw;
    #pragma unroll
    for (int j = 0; j < 4; ++j) {
      float2 f = __half22float2(h2[j]);
      v[2 * j] = f.x; v[2 * j + 1] = f.y;
    }
  } else {
    const float4* p = (const float4*)((const float*)A + base);
    float4 u0 = p[0], u1 = p[1];
    v[0] = u0.x; v[1] = u0.y; v[2] = u0.z; v[3] = u0.w;
    v[4] = u1.x; v[5] = u1.y; v[6] = u1.z; v[7] = u1.w;
  }
  if (MODE == 2) {
    float vb[8];
    if (HALF) {
      float4 raw = *(const float4*)((const __half*)A2 + base);
      const __half2* h2 = (const __half2*)&raw;
      #pragma unroll
      for (int j = 0; j < 4; ++j) {
        float2 f = __half22float2(h2[j]);
        vb[2 * j] = f.x; vb[2 * j + 1] = f.y;
      }
    } else {
      const float4* q = (const float4*)((const float*)A2 + base);
      float4 t0 = q[0], t1 = q[1];
      vb[0] = t0.x; vb[1] = t0.y; vb[2] = t0.z; vb[3] = t0.w;
      vb[4] = t1.x; vb[5] = t1.y; vb[6] = t1.z; vb[7] = t1.w;
    }
    #pragma unroll
    for (int i = 0; i < 8; ++i) v[i] = w2 * v[i] + w3 * vb[i];
  }
  if (MODE >= 1) {
    #pragma unroll
    for (int i = 0; i < 8; ++i) v[i] = (v[i] > 0.f) ? v[i] : (__expf(v[i]) - 1.f);
  }
  #pragma unroll
  for (int i = 0; i < 8; ++i) tmp[i] = v[i];
}

template<int MODE, int HALF>
DEVI bf16x8 packrow8(const void* __restrict__ A, const void* __restrict__ A2,
                     float w2, float w3, size_t base)
{
  float t[8];
  loadrow8<MODE, HALF>(t, A, A2, w2, w3, base);
  bf16x8 r;
  #pragma unroll
  for (int i = 0; i < 8; ++i) r[i] = (short)f2bf(t[i]);
  return r;
}

// ====== merged MFMA GEMM (c & d paths) + fused attention dots ============
// B pre-arranged in FRAGMENT ORDER and staged per-chunk in LDS (linear ->
// coalesced staging, conflict-free ds_read_b128, shared by all 4 waves).
// A staged in LDS; register prefetch for both A and B stage values.
template<int KI, int MODEc, int MODEd, int IN16, int OUT16>
__global__ __launch_bounds__(256)
void gemm2_mfma(const void* __restrict__ Ac, const void* __restrict__ Ac2,
                const float* __restrict__ wv,
                const unsigned short* __restrict__ WcH, const unsigned short* __restrict__ WcL,
                const float* __restrict__ bc, void* __restrict__ Cc,
                const void* __restrict__ Ad,
                const unsigned short* __restrict__ WdH, const unsigned short* __restrict__ WdL,
                const float* __restrict__ bd, void* __restrict__ Cd,
                int N,
                const float* __restrict__ avc0, const float* __restrict__ avc1,
                const float* __restrict__ avc2, const float* __restrict__ avc3,
                const float* __restrict__ avd0, const float* __restrict__ avd1,
                float* __restrict__ doc0, float* __restrict__ doc1,
                float* __restrict__ doc2, float* __restrict__ doc3,
                float* __restrict__ dod0, float* __restrict__ dod1)
{
  __shared__ float As[64][36];                 // 9 KB
  __shared__ unsigned short BhS[4096];         // 8 KB (one chunk, fragment order)
  __shared__ unsigned short BlS[4096];         // 8 KB
  constexpr int NC = KI / 32;
  const bool isC = (blockIdx.y == 0);
  const void* A  = isC ? Ac : Ad;
  const void* A2 = isC ? Ac2 : nullptr;
  const unsigned short* WH = isC ? WcH : WdH;
  const unsigned short* WL = isC ? WcL : WdL;
  const float* bias = isC ? bc : bd;
  void* Cv = isC ? Cc : Cd;
  float w2 = 0.f, w3 = 0.f;
  if (MODEc == 2) { if (isC) { w2 = wv[2]; w3 = wv[3]; } }

  const int tid = threadIdx.x;
  const int w = tid >> 6, lane = tid & 63;
  const int m = lane & 15, b4 = lane >> 4;
  const int row0 = blockIdx.x * 64;
  const int row0w = row0 + w * 16;

  // staging thread roles
  const int rA = tid >> 2, kqA = (tid & 3) << 3;
  const int rowA = row0 + rA;

  f32x4 acc[8];
  #pragma unroll
  for (int t = 0; t < 8; ++t) acc[t] = (f32x4){0.f, 0.f, 0.f, 0.f};

  float tA[8];
  float4 rbh0, rbh1, rbl0, rbl1;   // 16 ushorts per plane per thread

  auto loadA = [&](int k0) {
    if (rowA < N) {
      if (isC) loadrow8<MODEc, IN16>(tA, A, A2, w2, w3, (size_t)rowA * KI + k0 + kqA);
      else     loadrow8<MODEd, IN16>(tA, A, nullptr, 0.f, 0.f, (size_t)rowA * KI + k0 + kqA);
    } else {
      #pragma unroll
      for (int i = 0; i < 8; ++i) tA[i] = 0.f;
    }
  };
  auto loadB = [&](int c) {
    const float4* ph = (const float4*)(WH + (size_t)c * 4096 + tid * 16);
    const float4* pl = (const float4*)(WL + (size_t)c * 4096 + tid * 16);
    rbh0 = ph[0]; rbh1 = ph[1];
    rbl0 = pl[0]; rbl1 = pl[1];
  };

  loadA(0);
  loadB(0);

  for (int c = 0; c < NC; ++c) {
    // write staged regs to LDS (all linear/coalesced)
    *(float4*)&As[rA][kqA]     = make_float4(tA[0], tA[1], tA[2], tA[3]);
    *(float4*)&As[rA][kqA + 4] = make_float4(tA[4], tA[5], tA[6], tA[7]);
    *(float4*)&BhS[tid * 16]     = rbh0;
    *(float4*)&BhS[tid * 16 + 8] = rbh1;
    *(float4*)&BlS[tid * 16]     = rbl0;
    *(float4*)&BlS[tid * 16 + 8] = rbl1;
    __syncthreads();

    if (c + 1 < NC) { loadA((c + 1) * 32); loadB(c + 1); }

    bf16x8 ah, al;
    {
      const float* ap = &As[w * 16 + m][b4 * 8];
      float4 u0 = *(const float4*)ap;
      float4 u1 = *(const float4*)(ap + 4);
      float t8[8] = {u0.x, u0.y, u0.z, u0.w, u1.x, u1.y, u1.z, u1.w};
      #pragma unroll
      for (int i = 0; i < 8; ++i) {
        unsigned short h = f2bf(t8[i]);
        ah[i] = (short)h;
        al[i] = (short)f2bf(t8[i] - bf2f(h));
      }
    }
    #pragma unroll
    for (int t = 0; t < 8; ++t) {
      const int fi = (t * 64 + lane) * 8;
      bf16x8 bh = *(const bf16x8*)&BhS[fi];
      bf16x8 bl = *(const bf16x8*)&BlS[fi];
      acc[t] = __builtin_amdgcn_mfma_f32_16x16x32_bf16(ah, bh, acc[t], 0, 0, 0);
      acc[t] = __builtin_amdgcn_mfma_f32_16x16x32_bf16(al, bh, acc[t], 0, 0, 0);
      acc[t] = __builtin_amdgcn_mfma_f32_16x16x32_bf16(ah, bl, acc[t], 0, 0, 0);
    }
    __syncthreads();
  }

  // ---- epilogue: bias + C store ----
  float bt[8];
  #pragma unroll
  for (int t = 0; t < 8; ++t) bt[t] = bias[t * 16 + m];

  #pragma unroll
  for (int t = 0; t < 8; ++t) {
    const int col = t * 16 + m;
    #pragma unroll
    for (int r = 0; r < 4; ++r) {
      const int row = row0w + b4 * 4 + r;
      if (row < N) {
        float v = acc[t][r] + bt[t];
        if (OUT16) ((__half*)Cv)[(size_t)row * 128 + col] = __float2half(v);
        else       ((float*)Cv)[(size_t)row * 128 + col] = v;
      }
    }
  }

  // ---- fused attention dots: per (row, head) reduce over 16 m-lanes ----
  const float* avp[4];
  float* dop[4];
  int nv;
  if (isC) {
    avp[0] = avc0; avp[1] = avc1; avp[2] = avc2; avp[3] = avc3;
    dop[0] = doc0; dop[1] = doc1; dop[2] = doc2; dop[3] = doc3; nv = 4;
  } else {
    avp[0] = avd0; avp[1] = avd1; avp[2] = avd0; avp[3] = avd1;
    dop[0] = dod0; dop[1] = dod1; dop[2] = dod0; dop[3] = dod1; nv = 2;
  }
  float avv[4][8];
  #pragma unroll
  for (int v = 0; v < 4; ++v) {
    if (v < nv) {
      #pragma unroll
      for (int t = 0; t < 8; ++t) avv[v][t] = avp[v][t * 16 + m];
    }
  }
  #pragma unroll
  for (int h = 0; h < 4; ++h) {
    #pragma unroll
    for (int v = 0; v < 4; ++v) {
      if (v < nv) {
        #pragma unroll
        for (int r = 0; r < 4; ++r) {
          float p = (acc[2 * h][r] + bt[2 * h]) * avv[v][2 * h]
                  + (acc[2 * h + 1][r] + bt[2 * h + 1]) * avv[v][2 * h + 1];
          p += __shfl_xor(p, 1);
          p += __shfl_xor(p, 2);
          p += __shfl_xor(p, 4);
          p += __shfl_xor(p, 8);
          if (m == 0) {
            const int row = row0w + b4 * 4 + r;
            if (row < N) dop[v][(size_t)row * 4 + h] = p;
          }
        }
      }
    }
  }
}

// ================= CSR build: hist + 3-pass scan + fill ==================
__global__ void hist3(const int* __restrict__ ei0, const int* __restrict__ ei1,
                      const int* __restrict__ ei2, int* __restrict__ deg)
{
  int gid = blockIdx.x * blockDim.x + threadIdx.x;
  if (gid >= 3 * En) return;
  int g = gid / En, e = gid - g * En;
  const int* ei = (g == 0) ? ei0 : (g == 1) ? ei1 : ei2;
  atomicAdd(&deg[g * 50000 + ei[En + e]], 1);
}

__global__ void scan_pass1(const int* __restrict__ deg, int* __restrict__ incl,
                           int* __restrict__ bsum)
{
  __shared__ int wsum[16];
  int tid = threadIdx.x;
  int gid = blockIdx.x * SCAN_BLK + tid;
  int v = (gid < SCAN_N) ? deg[gid] : 0;
  int lane = tid & 63, w = tid >> 6;
  int x = v;
  #pragma unroll
  for (int off = 1; off < 64; off <<= 1) {
    int y = __shfl_up(x, off);
    if (lane >= off) x += y;
  }
  if (lane == 63) wsum[w] = x;
  __syncthreads();
  if (tid == 0) {
    int s = 0;
    #pragma unroll
    for (int ww = 0; ww < 16; ++ww) { int t = wsum[ww]; wsum[ww] = s; s += t; }
    bsum[blockIdx.x] = s;
  }
  __syncthreads();
  x += wsum[w];
  if (gid < SCAN_N) incl[gid] = x;
}

__global__ void scan_pass2(int* __restrict__ bsum, int nb)
{
  __shared__ int wsum[16];
  int tid = threadIdx.x;
  int v = (tid < nb) ? bsum[tid] : 0;
  int lane = tid & 63, w = tid >> 6;
  int x = v;
  #pragma unroll
  for (int off = 1; off < 64; off <<= 1) {
    int y = __shfl_up(x, off);
    if (lane >= off) x += y;
  }
  if (lane == 63) wsum[w] = x;
  __syncthreads();
  if (tid == 0) {
    int s = 0;
    #pragma unroll
    for (int ww = 0; ww < 16; ++ww) { int t = wsum[ww]; wsum[ww] = s; s += t; }
  }
  __syncthreads();
  x += wsum[w];
  if (tid < nb) bsum[tid] = x - v;
}

__global__ void scan_pass3(const int* __restrict__ incl, const int* __restrict__ bsum,
                           int* __restrict__ offs)
{
  int gid = blockIdx.x * SCAN_BLK + threadIdx.x;
  if (gid == 0) offs[0] = 0;
  if (gid < SCAN_N) offs[gid + 1] = incl[gid] + bsum[gid / SCAN_BLK];
}

__global__ void fill3(const int* __restrict__ ei0, const int* __restrict__ ei1,
                      const int* __restrict__ ei2, const int* __restrict__ offs,
                      int* __restrict__ cursor, int* __restrict__ elist)
{
  int gid = blockIdx.x * blockDim.x + threadIdx.x;
  if (gid >= 3 * En) return;
  int g = gid / En, e = gid - g * En;
  const int* ei = (g == 0) ? ei0 : (g == 1) ? ei1 : ei2;
  int s = ei[e], d = g * 50000 + ei[En + e];
  int p = atomicAdd(&cursor[d], 1);
  elist[offs[d] + p] = s;
}

// ---- weight prep: all B operands in MFMA fragment order -----------------
__global__ void wprep(const float* __restrict__ k1W, const float* __restrict__ k2W,
                      const float* __restrict__ pW,
                      const float* __restrict__ W1c, const float* __restrict__ W1d,
                      const float* __restrict__ W2c, const float* __restrict__ W2d,
                      unsigned short* kW1t, unsigned short* kW2t, unsigned short* pWt,
                      unsigned short* W1cH, unsigned short* W1cL,
                      unsigned short* W1dH, unsigned short* W1dL,
                      unsigned short* W2cH, unsigned short* W2cL,
                      unsigned short* W2dH, unsigned short* W2dL)
{
  int gid = blockIdx.x * 256 + threadIdx.x;
  if (gid < 16384) {                       // k1W: 128x128
    int i = gid, k = i >> 7, col = i & 127;
    int ks = k >> 5, b4 = (k >> 3) & 3, j = k & 7, t = col >> 4, m = col & 15;
    kW1t[(size_t)(((t * 4 + ks) * 64) + m + 16 * b4) * 8 + j] = f2bf(k1W[i]);
  } else if (gid < 32768) {                // k2W: 128x128
    int i = gid - 16384, k = i >> 7, col = i & 127;
    int ks = k >> 5, b4 = (k >> 3) & 3, j = k & 7, t = col >> 4, m = col & 15;
    kW2t[(size_t)(((t * 4 + ks) * 64) + m + 16 * b4) * 8 + j] = f2bf(k2W[i]);
  } else if (gid < 40960) {                // pW: 128x64
    int i = gid - 32768, k = i / 64, col = i - k * 64;
    int ks = k >> 5, b4 = (k >> 3) & 3, j = k & 7, t = col >> 4, m = col & 15;
    pWt[(size_t)(((t * 4 + ks) * 64) + m + 16 * b4) * 8 + j] = f2bf(pW[i]);
  } else if (gid < 73728) {                // W1c: 256x128
    int i = gid - 40960, k = i >> 7, col = i & 127;
    int c = k >> 5, b4 = (k >> 3) & 3, j = k & 7, t = col >> 4, m = col & 15;
    size_t f = (size_t)(((c * 8 + t) * 64) + m + 16 * b4) * 8 + j;
    float v = W1c[i]; unsigned short h = f2bf(v);
    W1cH[f] = h; W1cL[f] = f2bf(v - bf2f(h));
  } else if (gid < 106496) {               // W1d: 256x128
    int i = gid - 73728, k = i >> 7, col = i & 127;
    int c = k >> 5, b4 = (k >> 3) & 3, j = k & 7, t = col >> 4, m = col & 15;
    size_t f = (size_t)(((c * 8 + t) * 64) + m + 16 * b4) * 8 + j;
    float v = W1d[i]; unsigned short h = f2bf(v);
    W1dH[f] = h; W1dL[f] = f2bf(v - bf2f(h));
  } else if (gid < 122880) {               // W2c: 128x128
    int i = gid - 106496, k = i >> 7, col = i & 127;
    int c = k >> 5, b4 = (k >> 3) & 3, j = k & 7, t = col >> 4, m = col & 15;
    size_t f = (size_t)(((c * 8 + t) * 64) + m + 16 * b4) * 8 + j;
    float v = W2c[i]; unsigned short h = f2bf(v);
    W2cH[f] = h; W2cL[f] = f2bf(v - bf2f(h));
  } else if (gid < 139264) {               // W2d: 128x128
    int i = gid - 122880, k = i >> 7, col = i & 127;
    int c = k >> 5, b4 = (k >> 3) & 3, j = k & 7, t = col >> 4, m = col & 15;
    size_t f = (size_t)(((c * 8 + t) * 64) + m + 16 * b4) * 8 + j;
    float v = W2d[i]; unsigned short h = f2bf(v);
    W2dH[f] = h; W2dL[f] = f2bf(v - bf2f(h));
  }
}

// ==== FUSED edge attention (CSR, fp16 h, lane-specialized softmax) =======
struct EdgeOp {
  const int* offs; const int* elist;
  const float* sdot; const float* ddot;
  const __half* hsrc; __half* out;
};

DEVI void csr_att_body(const EdgeOp& op, int dst, int lane)
{
  const int i0 = op.offs[dst], i1 = op.offs[dst + 1];
  const int hB = lane >> 4;
  const float ddv = op.ddot[dst * 4 + hB];
  const __half* hsrc = op.hsrc;
  const float* sdot = op.sdot;
  const int* el = op.elist;
  const int wsel = lane & 48;
  float den = 0.f, a0 = 0.f, a1 = 0.f;

  for (int base = i0; base < i1; base += 16) {
    int i = base + (lane & 15);
    int s_ = 0;
    float w = 0.f;
    if (i < i1) {
      s_ = el[i];
      float lv = sdot[s_ * 4 + hB] + ddv;
      lv = fminf(fmaxf(lv, 0.2f * lv), 80.f);
      w = __expf(lv);
    }
    float g = w;
    g += __shfl_xor(g, 1);
    g += __shfl_xor(g, 2);
    g += __shfl_xor(g, 4);
    g += __shfl_xor(g, 8);
    den += g;

    const int rem = min(16, i1 - base);
    int j = 0;
    for (; j + 2 <= rem; j += 2) {
      int sA = __shfl(s_, j);
      int sB = __shfl(s_, j + 1);
      float wA = __shfl(w, wsel | j);
      float wB = __shfl(w, wsel | (j + 1));
      float2 hA = __half22float2(*(const __half2*)(hsrc + (size_t)sA * HIDn + lane * 2));
      float2 hBv = __half22float2(*(const __half2*)(hsrc + (size_t)sB * HIDn + lane * 2));
      a0 += hA.x * wA + hBv.x * wB;
      a1 += hA.y * wA + hBv.y * wB;
    }
    if (j < rem) {
      int sA = __shfl(s_, j);
      float wA = __shfl(w, wsel | j);
      float2 hA = __half22float2(*(const __half2*)(hsrc + (size_t)sA * HIDn + lane * 2));
      a0 += hA.x * wA;
      a1 += hA.y * wA;
    }
  }
  float dinv = __fdividef(1.f, den + 1e-16f);
  __half2 o2 = __floats2half2_rn(fmaxf(a0 * dinv, 0.f), fmaxf(a1 * dinv, 0.f));
  *(__half2*)(op.out + (size_t)dst * HIDn + lane * 2) = o2;
}

__global__ __launch_bounds__(256)
void csr_att3(EdgeOp op0, EdgeOp op1, EdgeOp op2, int Ndst)
{
  int wave = (blockIdx.x * 256 + threadIdx.x) >> 6;
  if (wave >= Ndst) return;
  const int lane = threadIdx.x & 63;
  if (blockIdx.y == 0)      csr_att_body(op0, wave, lane);
  else if (blockIdx.y == 1) csr_att_body(op1, wave, lane);
  else                      csr_att_body(op2, wave, lane);
}

// ---- fallback path (atomic scatter, fp32 h), used only if ws too small --
__global__ void edge_logit_max(const int* __restrict__ ei,
                               const float* __restrict__ sdot,
                               const float* __restrict__ ddot,
                               unsigned* __restrict__ m)
{
  int e = blockIdx.x * blockDim.x + threadIdx.x;
  if (e >= En) return;
  int s = ei[e], d = ei[En + e];
  #pragma unroll
  for (int hh = 0; hh < 4; ++hh) {
    float l = sdot[s * 4 + hh] + ddot[d * 4 + hh];
    l = (l > 0.f) ? l : 0.2f * l;
    atomicMax(&m[d * 4 + hh], fmap(l));
  }
}

__global__ void edge_exp_sum(const int* __restrict__ ei,
                             const float* __restrict__ sdot,
                             const float* __restrict__ ddot,
                             const unsigned* __restrict__ m,
                             float* __restrict__ sden,
                             float* __restrict__ ebuf)
{
  int e = blockIdx.x * blockDim.x + threadIdx.x;
  if (e >= En) return;
  int s = ei[e], d = ei[En + e];
  #pragma unroll
  for (int hh = 0; hh < 4; ++hh) {
    float l = sdot[s * 4 + hh] + ddot[d * 4 + hh];
    l = (l > 0.f) ? l : 0.2f * l;
    float ex = expf(fminf(l - fdecode(m[d * 4 + hh]), 0.f));
    ebuf[e * 4 + hh] = ex;
    atomicAdd(&sden[d * 4 + hh], ex);
  }
}

__global__ __launch_bounds__(256)
void edge_scatter(const int* __restrict__ ei, const float* __restrict__ hsrc,
                  const float* __restrict__ ebuf, const float* __restrict__ sden,
                  float* __restrict__ out)
{
  int gid  = blockIdx.x * 256 + threadIdx.x;
  int e    = gid >> 6;
  if (e >= En) return;
  int lane = gid & 63;
  int s = ei[e], d = ei[En + e];
  #pragma unroll
  for (int half = 0; half < 2; ++half) {
    int c  = lane + half * 64;
    int hh = c >> 5;
    float alpha = ebuf[e * 4 + hh] / (sden[d * 4 + hh] + 1e-16f);
    atomicAdd(&out[(size_t)d * HIDn + c], hsrc[(size_t)s * HIDn + c] * alpha);
  }
}

__global__ void relu_k(float* __restrict__ x, int n)
{
  int i = blockIdx.x * blockDim.x + threadIdx.x;
  if (i < n) x[i] = fmaxf(x[i], 0.f);
}

// ---- semantic-attention score via MFMA bf16 (fragment-ordered kWt) ------
template<int IN16>
__global__ __launch_bounds__(256)
void score_mfma(const void* __restrict__ oA, const void* __restrict__ oB,
                const unsigned short* __restrict__ kWt,
                const float* __restrict__ kb, const float* __restrict__ q,
                int N, float* __restrict__ slots)
{
  __shared__ float partw[4];
  const void* o = blockIdx.y ? oB : oA;
  const int tid = threadIdx.x;
  const int w = tid >> 6, lane = tid & 63;
  const int row0 = (blockIdx.x * 4 + w) * 16;
  const int m = lane & 15, b = lane >> 4;
  const int arow = row0 + m;
  const bool rok = arow < N;
  const bf16x8* WT = (const bf16x8*)kWt;

  const bf16x8 zfr = {0, 0, 0, 0, 0, 0, 0, 0};
  bf16x8 afr[4];
  {
    const size_t base = (size_t)arow * 128;
    #pragma unroll
    for (int ks = 0; ks < 4; ++ks) {
      if (rok) afr[ks] = packrow8<0, IN16>(o, nullptr, 0.f, 0.f, base + ks * 32 + b * 8);
      else     afr[ks] = zfr;
    }
  }

  float sum = 0.f;
  #pragma unroll
  for (int t = 0; t < 8; ++t) {
    f32x4 acc = {0.f, 0.f, 0.f, 0.f};
    const int col = t * 16 + m;
    #pragma unroll
    for (int ks = 0; ks < 4; ++ks)
      acc = __builtin_amdgcn_mfma_f32_16x16x32_bf16(afr[ks], WT[(t * 4 + ks) * 64 + lane], acc, 0, 0, 0);
    const float qc = q[col], kbc = kb[col];
    #pragma unroll
    for (int r = 0; r < 4; ++r) {
      int row = row0 + b * 4 + r;
      if (row < N) sum += qc * tanh_fast(acc[r] + kbc);
    }
  }
  #pragma unroll
  for (int off = 32; off > 0; off >>= 1) sum += __shfl_down(sum, off);
  if (lane == 0) partw[w] = sum;
  __syncthreads();
  if (tid == 0)
    atomicAdd(&slots[blockIdx.y],
              (partw[0] + partw[1] + partw[2] + partw[3]) * (1.f / (float)N));
}

__global__ void softmax2_kernel(float* sb)   // sb[0],sb[1] -> weights sb[2],sb[3]
{
  float s0 = sb[0], s1 = sb[1];
  float mx = fmaxf(s0, s1);
  float e0 = expf(s0 - mx), e1 = expf(s1 - mx);
  float inv = 1.f / (e0 + e1);
  sb[2] = e0 * inv;
  sb[3] = e1 * inv;
}

// ---- merged final projection via MFMA bf16 (fragment-ordered pWt) -------
template<int IN16>
__global__ __launch_bounds__(256)
void proj2_mfma(const void* __restrict__ fa, const void* __restrict__ fb,
                const float* __restrict__ wv, const void* __restrict__ fd,
                const unsigned short* __restrict__ pWt, const float* __restrict__ pb,
                float* __restrict__ outc, float* __restrict__ outd, int N)
{
  const bool isC = (blockIdx.y == 0);
  const int tid = threadIdx.x;
  const int w = tid >> 6, lane = tid & 63;
  const int row0 = (blockIdx.x * 4 + w) * 16;
  const int m = lane & 15, b = lane >> 4;
  const int arow = row0 + m;
  const bool rok = arow < N;
  float* out = isC ? outc : outd;
  const bf16x8* WT = (const bf16x8*)pWt;

  const bf16x8 zfr = {0, 0, 0, 0, 0, 0, 0, 0};
  bf16x8 afr[4];
  {
    const size_t base = (size_t)arow * 128;
    if (isC) {
      const float w2 = wv[2], w3 = wv[3];
      #pragma unroll
      for (int ks = 0; ks < 4; ++ks) {
        if (rok) afr[ks] = packrow8<2, IN16>(fa, fb, w2, w3, base + ks * 32 + b * 8);
        else     afr[ks] = zfr;
      }
    } else {
      #pragma unroll
      for (int ks = 0; ks < 4; ++ks) {
        if (rok) afr[ks] = packrow8<1, IN16>(fd, nullptr, 0.f, 0.f, base + ks * 32 + b * 8);
        else     afr[ks] = zfr;
      }
    }
  }

  f32x4 accs[4];
  float pbc[4];
  #pragma unroll
  for (int t = 0; t < 4; ++t) {
    f32x4 acc = {0.f, 0.f, 0.f, 0.f};
    const int col = t * 16 + m;
    #pragma unroll
    for (int ks = 0; ks < 4; ++ks)
      acc = __builtin_amdgcn_mfma_f32_16x16x32_bf16(afr[ks], WT[(t * 4 + ks) * 64 + lane], acc, 0, 0, 0);
    accs[t] = acc;
    pbc[t] = pb[col];
  }

  #pragma unroll
  for (int r = 0; r < 4; ++r) {
    const int row = row0 + b * 4 + r;
    float v[4];
    #pragma unroll
    for (int t = 0; t < 4; ++t) v[t] = accs[t][r] + pbc[t];
    if (isC) {
      float ss = v[0]*v[0] + v[1]*v[1] + v[2]*v[2] + v[3]*v[3];
      ss += __shfl_xor(ss, 1);
      ss += __shfl_xor(ss, 2);
      ss += __shfl_xor(ss, 4);
      ss += __shfl_xor(ss, 8);
      float inv = 1.f / fmaxf(sqrtf(ss), 1e-12f);
      #pragma unroll
      for (int t = 0; t < 4; ++t) v[t] *= inv;
    }
    if (row < N) {
      #pragma unroll
      for (int t = 0; t < 4; ++t)
        out[(size_t)row * OUTn + t * 16 + m] = v[t];
    }
  }
}

// ---- fallback edge-op dispatcher ----------------------------------------
static void run_edge_fb(hipStream_t stream, const int* ei,
                        const float* sdot, const float* ddot, const float* hsrc,
                        float* outb, int Ndst,
                        unsigned* mbuf, float* sden, float* ebuf)
{
  hipMemsetAsync(mbuf, 0, (size_t)Ndst * 4 * sizeof(unsigned), stream);
  edge_logit_max<<<(En + 255) / 256, 256, 0, stream>>>(ei, sdot, ddot, mbuf);
  hipMemsetAsync(sden, 0, (size_t)Ndst * 4 * sizeof(float), stream);
  edge_exp_sum<<<(En + 255) / 256, 256, 0, stream>>>(ei, sdot, ddot, mbuf, sden, ebuf);
  hipMemsetAsync(outb, 0, (size_t)Ndst * HIDn * sizeof(float), stream);
  edge_scatter<<<((size_t)En * 64 + 255) / 256, 256, 0, stream>>>(ei, hsrc, ebuf, sden, outb);
  relu_k<<<((size_t)Ndst * HIDn + 255) / 256, 256, 0, stream>>>(outb, Ndst * HIDn);
}

extern "C" void kernel_launch(void* const* d_in, const int* in_sizes, int n_in,
                              void* d_out, int out_size, void* d_ws, size_t ws_size,
                              hipStream_t stream)
{
  const float* xc    = (const float*)d_in[0];
  const float* xd    = (const float*)d_in[1];
  const int*   ei_cc = (const int*)d_in[2];
  const int*   ei_dc = (const int*)d_in[3];
  const int*   ei_cd = (const int*)d_in[4];
  const float* W1c = (const float*)d_in[5];  const float* b1c = (const float*)d_in[6];
  const float* W1d = (const float*)d_in[7];  const float* b1d = (const float*)d_in[8];
  const float* a1s_cc = (const float*)d_in[9];  const float* a1d_cc = (const float*)d_in[10];
  const float* a1s_dc = (const float*)d_in[11]; const float* a1d_dc = (const float*)d_in[12];
  const float* a1s_cd = (const float*)d_in[13]; const float* a1d_cd = (const float*)d_in[14];
  const float* k1W = (const float*)d_in[15]; const float* k1b = (const float*)d_in[16];
  const float* q1  = (const float*)d_in[17];
  const float* W2c = (const float*)d_in[18]; const float* b2c = (const float*)d_in[19];
  const float* W2d = (const float*)d_in[20]; const float* b2d = (const float*)d_in[21];
  const float* a2s_cc = (const float*)d_in[22]; const float* a2d_cc = (const float*)d_in[23];
  const float* a2s_dc = (const float*)d_in[24]; const float* a2d_dc = (const float*)d_in[25];
  const float* a2s_cd = (const float*)d_in[26]; const float* a2d_cd = (const float*)d_in[27];
  const float* k2W = (const float*)d_in[28]; const float* k2b = (const float*)d_in[29];
  const float* q2  = (const float*)d_in[30];
  const float* pW  = (const float*)d_in[31]; const float* pb  = (const float*)d_in[32];

  // ---------------- workspace layout ----------------
  float* ws = (float*)d_ws;
  const size_t NB = (size_t)NCn * HIDn;
  float* B0 = ws;            // node buffers (fp16 in CSR mode, fp32 fallback)
  float* B1 = ws + NB;
  float* B2 = ws + 2 * NB;
  float* B3 = ws + 3 * NB;
  float* B4 = ws + 4 * NB;
  float* sml = ws + 5 * NB;
  float* scc = sml;
  float* dcc = sml + 200000;
  float* ddc = sml + 400000;
  float* scd = sml + 600000;
  float* sdc = sml + 800000;
  float* dcd = sml + 1000000;
  float* scoreB = sml + 1200000;
  float* R0 = sml + 1200016;
  int*  R0i = (int*)R0;
  int*  offsBase  = R0i;                   // 150,004 ints (global offs)
  int*  elistBase = R0i + 150004;          // 1,200,000 ints (combined)
  int*  degBase   = R0i + 1350004;         // 150,000
  int*  cursorBase= R0i + 1500004;         // 150,000 (adjacent -> single memset)
  int*  inclBase  = R0i + 1650004;         // 150,000
  int*  bsumBase  = R0i + 1800004;         // 1,024
  unsigned short* kW1t = (unsigned short*)(R0i + 1801028);
  unsigned short* kW2t = (unsigned short*)(R0i + 1809220);
  unsigned short* pWt  = (unsigned short*)(R0i + 1817412);
  unsigned short* W1cH = (unsigned short*)(R0i + 1821508);
  unsigned short* W1cL = (unsigned short*)(R0i + 1837892);
  unsigned short* W1dH = (unsigned short*)(R0i + 1854276);
  unsigned short* W1dL = (unsigned short*)(R0i + 1870660);
  unsigned short* W2cH = (unsigned short*)(R0i + 1887044);
  unsigned short* W2cL = (unsigned short*)(R0i + 1895236);
  unsigned short* W2dH = (unsigned short*)(R0i + 1903428);
  unsigned short* W2dL = (unsigned short*)(R0i + 1911620);  // end 1,919,812 ints
  // fallback temps overlay (over CSR region)
  unsigned* mbuf = (unsigned*)R0;
  float*    sden = R0 + 200000;
  float*    ebuf = R0 + 400000;

  const size_t REQ_FLOATS = 5 * NB + 1200016 + 1919812;     // 35,119,828 fl = 140.5 MB
  const bool useCsr = ws_size >= REQ_FLOATS * sizeof(float);

  if (useCsr) {
    hipMemsetAsync(degBase, 0, 300000 * sizeof(int), stream);   // deg + cursor
    hist3<<<(3 * En + 255) / 256, 256, 0, stream>>>(ei_cc, ei_dc, ei_cd, degBase);
    scan_pass1<<<SCAN_NB, SCAN_BLK, 0, stream>>>(degBase, inclBase, bsumBase);
    scan_pass2<<<1, SCAN_BLK, 0, stream>>>(bsumBase, SCAN_NB);
    scan_pass3<<<SCAN_NB, SCAN_BLK, 0, stream>>>(inclBase, bsumBase, offsBase);
    fill3<<<(3 * En + 255) / 256, 256, 0, stream>>>(ei_cc, ei_dc, ei_cd,
                                                    offsBase, cursorBase, elistBase);
  }
  wprep<<<(139264 + 255) / 256, 256, 0, stream>>>(k1W, k2W, pW, W1c, W1d, W2c, W2d,
                                                  kW1t, kW2t, pWt,
                                                  W1cH, W1cL, W1dH, W1dL,
                                                  W2cH, W2cL, W2dH, W2dL);

  hipMemsetAsync(scoreB, 0, 8 * sizeof(float), stream);

  const int NT64 = (NCn + 63) / 64;
  const int* offs0 = offsBase;
  const int* offs1 = offsBase + 50000;
  const int* offs2 = offsBase + 100000;

  auto edge_layer = [&](void* hc, void* hd, void* oCC, void* oDC, void* oCD) {
    if (useCsr) {
      EdgeOp o0{offs0, elistBase, scc, dcc, (const __half*)hc, (__half*)oCC};
      EdgeOp o1{offs1, elistBase, sdc, ddc, (const __half*)hd, (__half*)oDC};
      EdgeOp o2{offs2, elistBase, scd, dcd, (const __half*)hc, (__half*)oCD};
      csr_att3<<<dim3((NCn + 3) / 4, 3), 256, 0, stream>>>(o0, o1, o2, NCn);
    } else {
      run_edge_fb(stream, ei_cc, scc, dcc, (const float*)hc, (float*)oCC, NCn, mbuf, sden, ebuf);
      run_edge_fb(stream, ei_dc, sdc, ddc, (const float*)hd, (float*)oDC, NCn, mbuf, sden, ebuf);
      run_edge_fb(stream, ei_cd, scd, dcd, (const float*)hc, (float*)oCD, NDn, mbuf, sden, ebuf);
    }
  };

  if (useCsr) {
    // ---------------- layer 1 ----------------
    gemm2_mfma<256, 0, 0, 0, 1><<<dim3(NT64, 2), 256, 0, stream>>>(
        xc, nullptr, nullptr, W1cH, W1cL, b1c, B0,
        xd, W1dH, W1dL, b1d, B1, NCn,
        a1s_cc, a1d_cc, a1d_dc, a1s_cd, a1s_dc, a1d_cd,
        scc, dcc, ddc, scd, sdc, dcd);
    edge_layer(B0, B1, B2, B3, B4);
    score_mfma<1><<<dim3(NT64, 2), 256, 0, stream>>>(B2, B3, kW1t, k1b, q1, NCn, scoreB);
    softmax2_kernel<<<1, 1, 0, stream>>>(scoreB);

    // ---------------- layer 2 ----------------
    gemm2_mfma<128, 2, 1, 1, 1><<<dim3(NT64, 2), 256, 0, stream>>>(
        B2, B3, scoreB, W2cH, W2cL, b2c, B0,
        B4, W2dH, W2dL, b2d, B1, NCn,
        a2s_cc, a2d_cc, a2d_dc, a2s_cd, a2s_dc, a2d_cd,
        scc, dcc, ddc, scd, sdc, dcd);
    edge_layer(B0, B1, B2, B3, B4);
    score_mfma<1><<<dim3(NT64, 2), 256, 0, stream>>>(B2, B3, kW2t, k2b, q2, NCn, scoreB + 4);
    softmax2_kernel<<<1, 1, 0, stream>>>(scoreB + 4);

    // ---------------- projection (merged) ----------------
    proj2_mfma<1><<<dim3(NT64, 2), 256, 0, stream>>>(B2, B3, scoreB + 4, B4, pWt, pb,
                                                     (float*)d_out,
                                                     (float*)d_out + (size_t)NCn * OUTn, NCn);
  } else {
    // ---------------- fp32 fallback ----------------
    gemm2_mfma<256, 0, 0, 0, 0><<<dim3(NT64, 2), 256, 0, stream>>>(
        xc, nullptr, nullptr, W1cH, W1cL, b1c, B0,
        xd, W1dH, W1dL, b1d, B1, NCn,
        a1s_cc, a1d_cc, a1d_dc, a1s_cd, a1s_dc, a1d_cd,
        scc, dcc, ddc, scd, sdc, dcd);
    edge_layer(B0, B1, B2, B3, B4);
    score_mfma<0><<<dim3(NT64, 2), 256, 0, stream>>>(B2, B3, kW1t, k1b, q1, NCn, scoreB);
    softmax2_kernel<<<1, 1, 0, stream>>>(scoreB);

    gemm2_mfma<128, 2, 1, 0, 0><<<dim3(NT64, 2), 256, 0, stream>>>(
        B2, B3, scoreB, W2cH, W2cL, b2c, B0,
        B4, W2dH, W2dL, b2d, B1, NCn,
        a2s_cc, a2d_cc, a2d_dc, a2s_cd, a2s_dc, a2d_cd,
        scc, dcc, ddc, scd, sdc, dcd);
    edge_layer(B0, B1, B2, B3, B4);
    score_mfma<0><<<dim3(NT64, 2), 256, 0, stream>>>(B2, B3, kW2t, k2b, q2, NCn, scoreB + 4);
    softmax2_kernel<<<1, 1, 0, stream>>>(scoreB + 4);

    proj2_mfma<0><<<dim3(NT64, 2), 256, 0, stream>>>(B2, B3, scoreB + 4, B4, pWt, pb,
                                                     (float*)d_out,
                                                     (float*)d_out + (size_t)NCn * OUTn, NCn);
  }
}

// Round 23
// 442.977 us; speedup vs baseline: 1.6499x; 1.0010x over previous
//
#include <hip/hip_runtime.h>
#include <hip/hip_fp16.h>
#include <cmath>

#define DEVI static __device__ __forceinline__

constexpr int HIDn = 128, OUTn = 64;
constexpr int NCn = 50000, NDn = 50000, En = 400000;
constexpr int SCAN_N = 150000, SCAN_BLK = 1024;
constexpr int SCAN_NB = (SCAN_N + SCAN_BLK - 1) / SCAN_BLK;   // 147

typedef __attribute__((ext_vector_type(8))) short bf16x8;
typedef __attribute__((ext_vector_type(4))) float f32x4;

// monotonic float->uint mapping for atomicMax on floats (handles signs)
DEVI unsigned fmap(float f) {
  int i = __float_as_int(f);
  return (i < 0) ? ~((unsigned)i) : (((unsigned)i) | 0x80000000u);
}
DEVI float fdecode(unsigned u) {
  int i = (u & 0x80000000u) ? (int)(u & 0x7fffffffu) : (int)(~u);
  return __int_as_float(i);
}

DEVI float tanh_fast(float x) {           // 1 - 2/(e^{2x}+1); saturates correctly
  float e = __expf(2.f * x);
  return 1.f - __fdividef(2.f, e + 1.f);
}

DEVI unsigned short f2bf(float x) {       // fp32 -> bf16 RNE
  unsigned u = __float_as_uint(x);
  return (unsigned short)((u + 0x7FFFu + ((u >> 16) & 1u)) >> 16);
}
DEVI float bf2f(unsigned short h) {
  unsigned u = ((unsigned)h) << 16;
  return __uint_as_float(u);
}

// ---- vectorized 8-wide A-row load + fused transform (value-based) -------
// MODE: 0=plain, 1=elu(x), 2=elu(w2*a+w3*b). HALF: input dtype fp16.
template<int MODE, int HALF>
DEVI void loadrow8(float* __restrict__ tmp,
                   const void* __restrict__ A, const void* __restrict__ A2,
                   float w2, float w3, size_t base)
{
  float v[8];
  if (HALF) {
    float4 raw = *(const float4*)((const __half*)A + base);
    const __half2* h2 = (const __half2*)&raw;
    #pragma unroll
    for (int j = 0; j < 4; ++j) {
      float2 f = __half22float2(h2[j]);
      v[2 * j] = f.x; v[2 * j + 1] = f.y;
    }
  } else {
    const float4* p = (const float4*)((const float*)A + base);
    float4 u0 = p[0], u1 = p[1];
    v[0] = u0.x; v[1] = u0.y; v[2] = u0.z; v[3] = u0.w;
    v[4] = u1.x; v[5] = u1.y; v[6] = u1.z; v[7] = u1.w;
  }
  if (MODE == 2) {
    float vb[8];
    if (HALF) {
      float4 raw = *(const float4*)((const __half*)A2 + base);
      const __half2* h2 = (const __half2*)&raw;
      #pragma unroll
      for (int j = 0; j < 4; ++j) {
        float2 f = __half22float2(h2[j]);
        vb[2 * j] = f.x; vb[2 * j + 1] = f.y;
      }
    } else {
      const float4* q = (const float4*)((const float*)A2 + base);
      float4 t0 = q[0], t1 = q[1];
      vb[0] = t0.x; vb[1] = t0.y; vb[2] = t0.z; vb[3] = t0.w;
      vb[4] = t1.x; vb[5] = t1.y; vb[6] = t1.z; vb[7] = t1.w;
    }
    #pragma unroll
    for (int i = 0; i < 8; ++i) v[i] = w2 * v[i] + w3 * vb[i];
  }
  if (MODE >= 1) {
    #pragma unroll
    for (int i = 0; i < 8; ++i) v[i] = (v[i] > 0.f) ? v[i] : (__expf(v[i]) - 1.f);
  }
  #pragma unroll
  for (int i = 0; i < 8; ++i) tmp[i] = v[i];
}

template<int MODE, int HALF>
DEVI bf16x8 packrow8(const void* __restrict__ A, const void* __restrict__ A2,
                     float w2, float w3, size_t base)
{
  float t[8];
  loadrow8<MODE, HALF>(t, A, A2, w2, w3, base);
  bf16x8 r;
  #pragma unroll
  for (int i = 0; i < 8; ++i) r[i] = (short)f2bf(t[i]);
  return r;
}

// ====== merged MFMA GEMM (c & d paths) + fused attention dots ============
// B pre-arranged in FRAGMENT ORDER and staged per-chunk in LDS (linear ->
// coalesced staging, conflict-free ds_read_b128, shared by all 4 waves).
// A staged in LDS with pad 44 (2-way banks = free); prefetch issued BEFORE
// the barrier so HBM latency hides under the other waves' compute.
template<int KI, int MODEc, int MODEd, int IN16, int OUT16>
__global__ __launch_bounds__(256)
void gemm2_mfma(const void* __restrict__ Ac, const void* __restrict__ Ac2,
                const float* __restrict__ wv,
                const unsigned short* __restrict__ WcH, const unsigned short* __restrict__ WcL,
                const float* __restrict__ bc, void* __restrict__ Cc,
                const void* __restrict__ Ad,
                const unsigned short* __restrict__ WdH, const unsigned short* __restrict__ WdL,
                const float* __restrict__ bd, void* __restrict__ Cd,
                int N,
                const float* __restrict__ avc0, const float* __restrict__ avc1,
                const float* __restrict__ avc2, const float* __restrict__ avc3,
                const float* __restrict__ avd0, const float* __restrict__ avd1,
                float* __restrict__ doc0, float* __restrict__ doc1,
                float* __restrict__ doc2, float* __restrict__ doc3,
                float* __restrict__ dod0, float* __restrict__ dod1)
{
  __shared__ float As[64][44];                 // 11.3 KB, stride 44 -> 2-way banks
  __shared__ unsigned short BhS[4096];         // 8 KB (one chunk, fragment order)
  __shared__ unsigned short BlS[4096];         // 8 KB
  constexpr int NC = KI / 32;
  const bool isC = (blockIdx.y == 0);
  const void* A  = isC ? Ac : Ad;
  const void* A2 = isC ? Ac2 : nullptr;
  const unsigned short* WH = isC ? WcH : WdH;
  const unsigned short* WL = isC ? WcL : WdL;
  const float* bias = isC ? bc : bd;
  void* Cv = isC ? Cc : Cd;
  float w2 = 0.f, w3 = 0.f;
  if (MODEc == 2) { if (isC) { w2 = wv[2]; w3 = wv[3]; } }

  const int tid = threadIdx.x;
  const int w = tid >> 6, lane = tid & 63;
  const int m = lane & 15, b4 = lane >> 4;
  const int row0 = blockIdx.x * 64;
  const int row0w = row0 + w * 16;

  // staging thread roles
  const int rA = tid >> 2, kqA = (tid & 3) << 3;
  const int rowA = row0 + rA;

  f32x4 acc[8];
  #pragma unroll
  for (int t = 0; t < 8; ++t) acc[t] = (f32x4){0.f, 0.f, 0.f, 0.f};

  float tA[8];
  float4 rbh0, rbh1, rbl0, rbl1;   // 16 ushorts per plane per thread

  auto loadA = [&](int k0) {
    if (rowA < N) {
      if (isC) loadrow8<MODEc, IN16>(tA, A, A2, w2, w3, (size_t)rowA * KI + k0 + kqA);
      else     loadrow8<MODEd, IN16>(tA, A, nullptr, 0.f, 0.f, (size_t)rowA * KI + k0 + kqA);
    } else {
      #pragma unroll
      for (int i = 0; i < 8; ++i) tA[i] = 0.f;
    }
  };
  auto loadB = [&](int c) {
    const float4* ph = (const float4*)(WH + (size_t)c * 4096 + tid * 16);
    const float4* pl = (const float4*)(WL + (size_t)c * 4096 + tid * 16);
    rbh0 = ph[0]; rbh1 = ph[1];
    rbl0 = pl[0]; rbl1 = pl[1];
  };

  loadA(0);
  loadB(0);

  for (int c = 0; c < NC; ++c) {
    // write staged regs to LDS (all linear/coalesced)
    *(float4*)&As[rA][kqA]     = make_float4(tA[0], tA[1], tA[2], tA[3]);
    *(float4*)&As[rA][kqA + 4] = make_float4(tA[4], tA[5], tA[6], tA[7]);
    *(float4*)&BhS[tid * 16]     = rbh0;
    *(float4*)&BhS[tid * 16 + 8] = rbh1;
    *(float4*)&BlS[tid * 16]     = rbl0;
    *(float4*)&BlS[tid * 16 + 8] = rbl1;

    // prefetch next chunk BEFORE the barrier (regs already consumed)
    if (c + 1 < NC) { loadA((c + 1) * 32); loadB(c + 1); }
    __syncthreads();

    bf16x8 ah, al;
    {
      const float* ap = &As[w * 16 + m][b4 * 8];
      float4 u0 = *(const float4*)ap;
      float4 u1 = *(const float4*)(ap + 4);
      float t8[8] = {u0.x, u0.y, u0.z, u0.w, u1.x, u1.y, u1.z, u1.w};
      #pragma unroll
      for (int i = 0; i < 8; ++i) {
        unsigned short h = f2bf(t8[i]);
        ah[i] = (short)h;
        al[i] = (short)f2bf(t8[i] - bf2f(h));
      }
    }
    #pragma unroll
    for (int t = 0; t < 8; ++t) {
      const int fi = (t * 64 + lane) * 8;
      bf16x8 bh = *(const bf16x8*)&BhS[fi];
      bf16x8 bl = *(const bf16x8*)&BlS[fi];
      acc[t] = __builtin_amdgcn_mfma_f32_16x16x32_bf16(ah, bh, acc[t], 0, 0, 0);
      acc[t] = __builtin_amdgcn_mfma_f32_16x16x32_bf16(al, bh, acc[t], 0, 0, 0);
      acc[t] = __builtin_amdgcn_mfma_f32_16x16x32_bf16(ah, bl, acc[t], 0, 0, 0);
    }
    __syncthreads();
  }

  // ---- epilogue: bias + C store ----
  float bt[8];
  #pragma unroll
  for (int t = 0; t < 8; ++t) bt[t] = bias[t * 16 + m];

  #pragma unroll
  for (int t = 0; t < 8; ++t) {
    const int col = t * 16 + m;
    #pragma unroll
    for (int r = 0; r < 4; ++r) {
      const int row = row0w + b4 * 4 + r;
      if (row < N) {
        float v = acc[t][r] + bt[t];
        if (OUT16) ((__half*)Cv)[(size_t)row * 128 + col] = __float2half(v);
        else       ((float*)Cv)[(size_t)row * 128 + col] = v;
      }
    }
  }

  // ---- fused attention dots: per (row, head) reduce over 16 m-lanes ----
  const float* avp[4];
  float* dop[4];
  int nv;
  if (isC) {
    avp[0] = avc0; avp[1] = avc1; avp[2] = avc2; avp[3] = avc3;
    dop[0] = doc0; dop[1] = doc1; dop[2] = doc2; dop[3] = doc3; nv = 4;
  } else {
    avp[0] = avd0; avp[1] = avd1; avp[2] = avd0; avp[3] = avd1;
    dop[0] = dod0; dop[1] = dod1; dop[2] = dod0; dop[3] = dod1; nv = 2;
  }
  float avv[4][8];
  #pragma unroll
  for (int v = 0; v < 4; ++v) {
    if (v < nv) {
      #pragma unroll
      for (int t = 0; t < 8; ++t) avv[v][t] = avp[v][t * 16 + m];
    }
  }
  #pragma unroll
  for (int h = 0; h < 4; ++h) {
    #pragma unroll
    for (int v = 0; v < 4; ++v) {
      if (v < nv) {
        #pragma unroll
        for (int r = 0; r < 4; ++r) {
          float p = (acc[2 * h][r] + bt[2 * h]) * avv[v][2 * h]
                  + (acc[2 * h + 1][r] + bt[2 * h + 1]) * avv[v][2 * h + 1];
          p += __shfl_xor(p, 1);
          p += __shfl_xor(p, 2);
          p += __shfl_xor(p, 4);
          p += __shfl_xor(p, 8);
          if (m == 0) {
            const int row = row0w + b4 * 4 + r;
            if (row < N) dop[v][(size_t)row * 4 + h] = p;
          }
        }
      }
    }
  }
}

// ================= CSR build: hist + 3-pass scan + fill ==================
__global__ void hist3(const int* __restrict__ ei0, const int* __restrict__ ei1,
                      const int* __restrict__ ei2, int* __restrict__ deg)
{
  int gid = blockIdx.x * blockDim.x + threadIdx.x;
  if (gid >= 3 * En) return;
  int g = gid / En, e = gid - g * En;
  const int* ei = (g == 0) ? ei0 : (g == 1) ? ei1 : ei2;
  atomicAdd(&deg[g * 50000 + ei[En + e]], 1);
}

__global__ void scan_pass1(const int* __restrict__ deg, int* __restrict__ incl,
                           int* __restrict__ bsum)
{
  __shared__ int wsum[16];
  int tid = threadIdx.x;
  int gid = blockIdx.x * SCAN_BLK + tid;
  int v = (gid < SCAN_N) ? deg[gid] : 0;
  int lane = tid & 63, w = tid >> 6;
  int x = v;
  #pragma unroll
  for (int off = 1; off < 64; off <<= 1) {
    int y = __shfl_up(x, off);
    if (lane >= off) x += y;
  }
  if (lane == 63) wsum[w] = x;
  __syncthreads();
  if (tid == 0) {
    int s = 0;
    #pragma unroll
    for (int ww = 0; ww < 16; ++ww) { int t = wsum[ww]; wsum[ww] = s; s += t; }
    bsum[blockIdx.x] = s;
  }
  __syncthreads();
  x += wsum[w];
  if (gid < SCAN_N) incl[gid] = x;
}

__global__ void scan_pass2(int* __restrict__ bsum, int nb)
{
  __shared__ int wsum[16];
  int tid = threadIdx.x;
  int v = (tid < nb) ? bsum[tid] : 0;
  int lane = tid & 63, w = tid >> 6;
  int x = v;
  #pragma unroll
  for (int off = 1; off < 64; off <<= 1) {
    int y = __shfl_up(x, off);
    if (lane >= off) x += y;
  }
  if (lane == 63) wsum[w] = x;
  __syncthreads();
  if (tid == 0) {
    int s = 0;
    #pragma unroll
    for (int ww = 0; ww < 16; ++ww) { int t = wsum[ww]; wsum[ww] = s; s += t; }
  }
  __syncthreads();
  x += wsum[w];
  if (tid < nb) bsum[tid] = x - v;
}

__global__ void scan_pass3(const int* __restrict__ incl, const int* __restrict__ bsum,
                           int* __restrict__ offs)
{
  int gid = blockIdx.x * SCAN_BLK + threadIdx.x;
  if (gid == 0) offs[0] = 0;
  if (gid < SCAN_N) offs[gid + 1] = incl[gid] + bsum[gid / SCAN_BLK];
}

__global__ void fill3(const int* __restrict__ ei0, const int* __restrict__ ei1,
                      const int* __restrict__ ei2, const int* __restrict__ offs,
                      int* __restrict__ cursor, int* __restrict__ elist)
{
  int gid = blockIdx.x * blockDim.x + threadIdx.x;
  if (gid >= 3 * En) return;
  int g = gid / En, e = gid - g * En;
  const int* ei = (g == 0) ? ei0 : (g == 1) ? ei1 : ei2;
  int s = ei[e], d = g * 50000 + ei[En + e];
  int p = atomicAdd(&cursor[d], 1);
  elist[offs[d] + p] = s;
}

// ---- weight prep: all B operands in MFMA fragment order -----------------
__global__ void wprep(const float* __restrict__ k1W, const float* __restrict__ k2W,
                      const float* __restrict__ pW,
                      const float* __restrict__ W1c, const float* __restrict__ W1d,
                      const float* __restrict__ W2c, const float* __restrict__ W2d,
                      unsigned short* kW1t, unsigned short* kW2t, unsigned short* pWt,
                      unsigned short* W1cH, unsigned short* W1cL,
                      unsigned short* W1dH, unsigned short* W1dL,
                      unsigned short* W2cH, unsigned short* W2cL,
                      unsigned short* W2dH, unsigned short* W2dL)
{
  int gid = blockIdx.x * 256 + threadIdx.x;
  if (gid < 16384) {                       // k1W: 128x128
    int i = gid, k = i >> 7, col = i & 127;
    int ks = k >> 5, b4 = (k >> 3) & 3, j = k & 7, t = col >> 4, m = col & 15;
    kW1t[(size_t)(((t * 4 + ks) * 64) + m + 16 * b4) * 8 + j] = f2bf(k1W[i]);
  } else if (gid < 32768) {                // k2W: 128x128
    int i = gid - 16384, k = i >> 7, col = i & 127;
    int ks = k >> 5, b4 = (k >> 3) & 3, j = k & 7, t = col >> 4, m = col & 15;
    kW2t[(size_t)(((t * 4 + ks) * 64) + m + 16 * b4) * 8 + j] = f2bf(k2W[i]);
  } else if (gid < 40960) {                // pW: 128x64
    int i = gid - 32768, k = i / 64, col = i - k * 64;
    int ks = k >> 5, b4 = (k >> 3) & 3, j = k & 7, t = col >> 4, m = col & 15;
    pWt[(size_t)(((t * 4 + ks) * 64) + m + 16 * b4) * 8 + j] = f2bf(pW[i]);
  } else if (gid < 73728) {                // W1c: 256x128
    int i = gid - 40960, k = i >> 7, col = i & 127;
    int c = k >> 5, b4 = (k >> 3) & 3, j = k & 7, t = col >> 4, m = col & 15;
    size_t f = (size_t)(((c * 8 + t) * 64) + m + 16 * b4) * 8 + j;
    float v = W1c[i]; unsigned short h = f2bf(v);
    W1cH[f] = h; W1cL[f] = f2bf(v - bf2f(h));
  } else if (gid < 106496) {               // W1d: 256x128
    int i = gid - 73728, k = i >> 7, col = i & 127;
    int c = k >> 5, b4 = (k >> 3) & 3, j = k & 7, t = col >> 4, m = col & 15;
    size_t f = (size_t)(((c * 8 + t) * 64) + m + 16 * b4) * 8 + j;
    float v = W1d[i]; unsigned short h = f2bf(v);
    W1dH[f] = h; W1dL[f] = f2bf(v - bf2f(h));
  } else if (gid < 122880) {               // W2c: 128x128
    int i = gid - 106496, k = i >> 7, col = i & 127;
    int c = k >> 5, b4 = (k >> 3) & 3, j = k & 7, t = col >> 4, m = col & 15;
    size_t f = (size_t)(((c * 8 + t) * 64) + m + 16 * b4) * 8 + j;
    float v = W2c[i]; unsigned short h = f2bf(v);
    W2cH[f] = h; W2cL[f] = f2bf(v - bf2f(h));
  } else if (gid < 139264) {               // W2d: 128x128
    int i = gid - 122880, k = i >> 7, col = i & 127;
    int c = k >> 5, b4 = (k >> 3) & 3, j = k & 7, t = col >> 4, m = col & 15;
    size_t f = (size_t)(((c * 8 + t) * 64) + m + 16 * b4) * 8 + j;
    float v = W2d[i]; unsigned short h = f2bf(v);
    W2dH[f] = h; W2dL[f] = f2bf(v - bf2f(h));
  }
}

// ==== FUSED edge attention (CSR, fp16 h, lane-specialized softmax) =======
struct EdgeOp {
  const int* offs; const int* elist;
  const float* sdot; const float* ddot;
  const __half* hsrc; __half* out;
};

DEVI void csr_att_body(const EdgeOp& op, int dst, int lane)
{
  const int i0 = op.offs[dst], i1 = op.offs[dst + 1];
  const int hB = lane >> 4;
  const float ddv = op.ddot[dst * 4 + hB];
  const __half* hsrc = op.hsrc;
  const float* sdot = op.sdot;
  const int* el = op.elist;
  const int wsel = lane & 48;
  float den = 0.f, a0 = 0.f, a1 = 0.f;

  for (int base = i0; base < i1; base += 16) {
    int i = base + (lane & 15);
    int s_ = 0;
    float w = 0.f;
    if (i < i1) {
      s_ = el[i];
      float lv = sdot[s_ * 4 + hB] + ddv;
      lv = fminf(fmaxf(lv, 0.2f * lv), 80.f);
      w = __expf(lv);
    }
    float g = w;
    g += __shfl_xor(g, 1);
    g += __shfl_xor(g, 2);
    g += __shfl_xor(g, 4);
    g += __shfl_xor(g, 8);
    den += g;

    const int rem = min(16, i1 - base);
    int j = 0;
    for (; j + 2 <= rem; j += 2) {
      int sA = __shfl(s_, j);
      int sB = __shfl(s_, j + 1);
      float wA = __shfl(w, wsel | j);
      float wB = __shfl(w, wsel | (j + 1));
      float2 hA = __half22float2(*(const __half2*)(hsrc + (size_t)sA * HIDn + lane * 2));
      float2 hBv = __half22float2(*(const __half2*)(hsrc + (size_t)sB * HIDn + lane * 2));
      a0 += hA.x * wA + hBv.x * wB;
      a1 += hA.y * wA + hBv.y * wB;
    }
    if (j < rem) {
      int sA = __shfl(s_, j);
      float wA = __shfl(w, wsel | j);
      float2 hA = __half22float2(*(const __half2*)(hsrc + (size_t)sA * HIDn + lane * 2));
      a0 += hA.x * wA;
      a1 += hA.y * wA;
    }
  }
  float dinv = __fdividef(1.f, den + 1e-16f);
  __half2 o2 = __floats2half2_rn(fmaxf(a0 * dinv, 0.f), fmaxf(a1 * dinv, 0.f));
  *(__half2*)(op.out + (size_t)dst * HIDn + lane * 2) = o2;
}

__global__ __launch_bounds__(256)
void csr_att3(EdgeOp op0, EdgeOp op1, EdgeOp op2, int Ndst)
{
  int wave = (blockIdx.x * 256 + threadIdx.x) >> 6;
  if (wave >= Ndst) return;
  const int lane = threadIdx.x & 63;
  if (blockIdx.y == 0)      csr_att_body(op0, wave, lane);
  else if (blockIdx.y == 1) csr_att_body(op1, wave, lane);
  else                      csr_att_body(op2, wave, lane);
}

// ---- fallback path (atomic scatter, fp32 h), used only if ws too small --
__global__ void edge_logit_max(const int* __restrict__ ei,
                               const float* __restrict__ sdot,
                               const float* __restrict__ ddot,
                               unsigned* __restrict__ m)
{
  int e = blockIdx.x * blockDim.x + threadIdx.x;
  if (e >= En) return;
  int s = ei[e], d = ei[En + e];
  #pragma unroll
  for (int hh = 0; hh < 4; ++hh) {
    float l = sdot[s * 4 + hh] + ddot[d * 4 + hh];
    l = (l > 0.f) ? l : 0.2f * l;
    atomicMax(&m[d * 4 + hh], fmap(l));
  }
}

__global__ void edge_exp_sum(const int* __restrict__ ei,
                             const float* __restrict__ sdot,
                             const float* __restrict__ ddot,
                             const unsigned* __restrict__ m,
                             float* __restrict__ sden,
                             float* __restrict__ ebuf)
{
  int e = blockIdx.x * blockDim.x + threadIdx.x;
  if (e >= En) return;
  int s = ei[e], d = ei[En + e];
  #pragma unroll
  for (int hh = 0; hh < 4; ++hh) {
    float l = sdot[s * 4 + hh] + ddot[d * 4 + hh];
    l = (l > 0.f) ? l : 0.2f * l;
    float ex = expf(fminf(l - fdecode(m[d * 4 + hh]), 0.f));
    ebuf[e * 4 + hh] = ex;
    atomicAdd(&sden[d * 4 + hh], ex);
  }
}

__global__ __launch_bounds__(256)
void edge_scatter(const int* __restrict__ ei, const float* __restrict__ hsrc,
                  const float* __restrict__ ebuf, const float* __restrict__ sden,
                  float* __restrict__ out)
{
  int gid  = blockIdx.x * 256 + threadIdx.x;
  int e    = gid >> 6;
  if (e >= En) return;
  int lane = gid & 63;
  int s = ei[e], d = ei[En + e];
  #pragma unroll
  for (int half = 0; half < 2; ++half) {
    int c  = lane + half * 64;
    int hh = c >> 5;
    float alpha = ebuf[e * 4 + hh] / (sden[d * 4 + hh] + 1e-16f);
    atomicAdd(&out[(size_t)d * HIDn + c], hsrc[(size_t)s * HIDn + c] * alpha);
  }
}

__global__ void relu_k(float* __restrict__ x, int n)
{
  int i = blockIdx.x * blockDim.x + threadIdx.x;
  if (i < n) x[i] = fmaxf(x[i], 0.f);
}

// ---- semantic-attention score via MFMA bf16 (fragment-ordered kWt) ------
template<int IN16>
__global__ __launch_bounds__(256)
void score_mfma(const void* __restrict__ oA, const void* __restrict__ oB,
                const unsigned short* __restrict__ kWt,
                const float* __restrict__ kb, const float* __restrict__ q,
                int N, float* __restrict__ slots)
{
  __shared__ float partw[4];
  const void* o = blockIdx.y ? oB : oA;
  const int tid = threadIdx.x;
  const int w = tid >> 6, lane = tid & 63;
  const int row0 = (blockIdx.x * 4 + w) * 16;
  const int m = lane & 15, b = lane >> 4;
  const int arow = row0 + m;
  const bool rok = arow < N;
  const bf16x8* WT = (const bf16x8*)kWt;

  const bf16x8 zfr = {0, 0, 0, 0, 0, 0, 0, 0};
  bf16x8 afr[4];
  {
    const size_t base = (size_t)arow * 128;
    #pragma unroll
    for (int ks = 0; ks < 4; ++ks) {
      if (rok) afr[ks] = packrow8<0, IN16>(o, nullptr, 0.f, 0.f, base + ks * 32 + b * 8);
      else     afr[ks] = zfr;
    }
  }

  float sum = 0.f;
  #pragma unroll
  for (int t = 0; t < 8; ++t) {
    f32x4 acc = {0.f, 0.f, 0.f, 0.f};
    const int col = t * 16 + m;
    #pragma unroll
    for (int ks = 0; ks < 4; ++ks)
      acc = __builtin_amdgcn_mfma_f32_16x16x32_bf16(afr[ks], WT[(t * 4 + ks) * 64 + lane], acc, 0, 0, 0);
    const float qc = q[col], kbc = kb[col];
    #pragma unroll
    for (int r = 0; r < 4; ++r) {
      int row = row0 + b * 4 + r;
      if (row < N) sum += qc * tanh_fast(acc[r] + kbc);
    }
  }
  #pragma unroll
  for (int off = 32; off > 0; off >>= 1) sum += __shfl_down(sum, off);
  if (lane == 0) partw[w] = sum;
  __syncthreads();
  if (tid == 0)
    atomicAdd(&slots[blockIdx.y],
              (partw[0] + partw[1] + partw[2] + partw[3]) * (1.f / (float)N));
}

__global__ void softmax2_kernel(float* sb)   // sb[0],sb[1] -> weights sb[2],sb[3]
{
  float s0 = sb[0], s1 = sb[1];
  float mx = fmaxf(s0, s1);
  float e0 = expf(s0 - mx), e1 = expf(s1 - mx);
  float inv = 1.f / (e0 + e1);
  sb[2] = e0 * inv;
  sb[3] = e1 * inv;
}

// ---- merged final projection via MFMA bf16 (fragment-ordered pWt) -------
template<int IN16>
__global__ __launch_bounds__(256)
void proj2_mfma(const void* __restrict__ fa, const void* __restrict__ fb,
                const float* __restrict__ wv, const void* __restrict__ fd,
                const unsigned short* __restrict__ pWt, const float* __restrict__ pb,
                float* __restrict__ outc, float* __restrict__ outd, int N)
{
  const bool isC = (blockIdx.y == 0);
  const int tid = threadIdx.x;
  const int w = tid >> 6, lane = tid & 63;
  const int row0 = (blockIdx.x * 4 + w) * 16;
  const int m = lane & 15, b = lane >> 4;
  const int arow = row0 + m;
  const bool rok = arow < N;
  float* out = isC ? outc : outd;
  const bf16x8* WT = (const bf16x8*)pWt;

  const bf16x8 zfr = {0, 0, 0, 0, 0, 0, 0, 0};
  bf16x8 afr[4];
  {
    const size_t base = (size_t)arow * 128;
    if (isC) {
      const float w2 = wv[2], w3 = wv[3];
      #pragma unroll
      for (int ks = 0; ks < 4; ++ks) {
        if (rok) afr[ks] = packrow8<2, IN16>(fa, fb, w2, w3, base + ks * 32 + b * 8);
        else     afr[ks] = zfr;
      }
    } else {
      #pragma unroll
      for (int ks = 0; ks < 4; ++ks) {
        if (rok) afr[ks] = packrow8<1, IN16>(fd, nullptr, 0.f, 0.f, base + ks * 32 + b * 8);
        else     afr[ks] = zfr;
      }
    }
  }

  f32x4 accs[4];
  float pbc[4];
  #pragma unroll
  for (int t = 0; t < 4; ++t) {
    f32x4 acc = {0.f, 0.f, 0.f, 0.f};
    const int col = t * 16 + m;
    #pragma unroll
    for (int ks = 0; ks < 4; ++ks)
      acc = __builtin_amdgcn_mfma_f32_16x16x32_bf16(afr[ks], WT[(t * 4 + ks) * 64 + lane], acc, 0, 0, 0);
    accs[t] = acc;
    pbc[t] = pb[col];
  }

  #pragma unroll
  for (int r = 0; r < 4; ++r) {
    const int row = row0 + b * 4 + r;
    float v[4];
    #pragma unroll
    for (int t = 0; t < 4; ++t) v[t] = accs[t][r] + pbc[t];
    if (isC) {
      float ss = v[0]*v[0] + v[1]*v[1] + v[2]*v[2] + v[3]*v[3];
      ss += __shfl_xor(ss, 1);
      ss += __shfl_xor(ss, 2);
      ss += __shfl_xor(ss, 4);
      ss += __shfl_xor(ss, 8);
      float inv = 1.f / fmaxf(sqrtf(ss), 1e-12f);
      #pragma unroll
      for (int t = 0; t < 4; ++t) v[t] *= inv;
    }
    if (row < N) {
      #pragma unroll
      for (int t = 0; t < 4; ++t)
        out[(size_t)row * OUTn + t * 16 + m] = v[t];
    }
  }
}

// ---- fallback edge-op dispatcher ----------------------------------------
static void run_edge_fb(hipStream_t stream, const int* ei,
                        const float* sdot, const float* ddot, const float* hsrc,
                        float* outb, int Ndst,
                        unsigned* mbuf, float* sden, float* ebuf)
{
  hipMemsetAsync(mbuf, 0, (size_t)Ndst * 4 * sizeof(unsigned), stream);
  edge_logit_max<<<(En + 255) / 256, 256, 0, stream>>>(ei, sdot, ddot, mbuf);
  hipMemsetAsync(sden, 0, (size_t)Ndst * 4 * sizeof(float), stream);
  edge_exp_sum<<<(En + 255) / 256, 256, 0, stream>>>(ei, sdot, ddot, mbuf, sden, ebuf);
  hipMemsetAsync(outb, 0, (size_t)Ndst * HIDn * sizeof(float), stream);
  edge_scatter<<<((size_t)En * 64 + 255) / 256, 256, 0, stream>>>(ei, hsrc, ebuf, sden, outb);
  relu_k<<<((size_t)Ndst * HIDn + 255) / 256, 256, 0, stream>>>(outb, Ndst * HIDn);
}

extern "C" void kernel_launch(void* const* d_in, const int* in_sizes, int n_in,
                              void* d_out, int out_size, void* d_ws, size_t ws_size,
                              hipStream_t stream)
{
  const float* xc    = (const float*)d_in[0];
  const float* xd    = (const float*)d_in[1];
  const int*   ei_cc = (const int*)d_in[2];
  const int*   ei_dc = (const int*)d_in[3];
  const int*   ei_cd = (const int*)d_in[4];
  const float* W1c = (const float*)d_in[5];  const float* b1c = (const float*)d_in[6];
  const float* W1d = (const float*)d_in[7];  const float* b1d = (const float*)d_in[8];
  const float* a1s_cc = (const float*)d_in[9];  const float* a1d_cc = (const float*)d_in[10];
  const float* a1s_dc = (const float*)d_in[11]; const float* a1d_dc = (const float*)d_in[12];
  const float* a1s_cd = (const float*)d_in[13]; const float* a1d_cd = (const float*)d_in[14];
  const float* k1W = (const float*)d_in[15]; const float* k1b = (const float*)d_in[16];
  const float* q1  = (const float*)d_in[17];
  const float* W2c = (const float*)d_in[18]; const float* b2c = (const float*)d_in[19];
  const float* W2d = (const float*)d_in[20]; const float* b2d = (const float*)d_in[21];
  const float* a2s_cc = (const float*)d_in[22]; const float* a2d_cc = (const float*)d_in[23];
  const float* a2s_dc = (const float*)d_in[24]; const float* a2d_dc = (const float*)d_in[25];
  const float* a2s_cd = (const float*)d_in[26]; const float* a2d_cd = (const float*)d_in[27];
  const float* k2W = (const float*)d_in[28]; const float* k2b = (const float*)d_in[29];
  const float* q2  = (const float*)d_in[30];
  const float* pW  = (const float*)d_in[31]; const float* pb  = (const float*)d_in[32];

  // ---------------- workspace layout ----------------
  float* ws = (float*)d_ws;
  const size_t NB = (size_t)NCn * HIDn;
  float* B0 = ws;            // node buffers (fp16 in CSR mode, fp32 fallback)
  float* B1 = ws + NB;
  float* B2 = ws + 2 * NB;
  float* B3 = ws + 3 * NB;
  float* B4 = ws + 4 * NB;
  float* sml = ws + 5 * NB;
  float* scc = sml;
  float* dcc = sml + 200000;
  float* ddc = sml + 400000;
  float* scd = sml + 600000;
  float* sdc = sml + 800000;
  float* dcd = sml + 1000000;
  float* scoreB = sml + 1200000;
  float* R0 = sml + 1200016;
  int*  R0i = (int*)R0;
  int*  offsBase  = R0i;                   // 150,004 ints (global offs)
  int*  elistBase = R0i + 150004;          // 1,200,000 ints (combined)
  int*  degBase   = R0i + 1350004;         // 150,000
  int*  cursorBase= R0i + 1500004;         // 150,000 (adjacent -> single memset)
  int*  inclBase  = R0i + 1650004;         // 150,000
  int*  bsumBase  = R0i + 1800004;         // 1,024
  unsigned short* kW1t = (unsigned short*)(R0i + 1801028);
  unsigned short* kW2t = (unsigned short*)(R0i + 1809220);
  unsigned short* pWt  = (unsigned short*)(R0i + 1817412);
  unsigned short* W1cH = (unsigned short*)(R0i + 1821508);
  unsigned short* W1cL = (unsigned short*)(R0i + 1837892);
  unsigned short* W1dH = (unsigned short*)(R0i + 1854276);
  unsigned short* W1dL = (unsigned short*)(R0i + 1870660);
  unsigned short* W2cH = (unsigned short*)(R0i + 1887044);
  unsigned short* W2cL = (unsigned short*)(R0i + 1895236);
  unsigned short* W2dH = (unsigned short*)(R0i + 1903428);
  unsigned short* W2dL = (unsigned short*)(R0i + 1911620);  // end 1,919,812 ints
  // fallback temps overlay (over CSR region)
  unsigned* mbuf = (unsigned*)R0;
  float*    sden = R0 + 200000;
  float*    ebuf = R0 + 400000;

  const size_t REQ_FLOATS = 5 * NB + 1200016 + 1919812;     // 35,119,828 fl = 140.5 MB
  const bool useCsr = ws_size >= REQ_FLOATS * sizeof(float);

  if (useCsr) {
    hipMemsetAsync(degBase, 0, 300000 * sizeof(int), stream);   // deg + cursor
    hist3<<<(3 * En + 255) / 256, 256, 0, stream>>>(ei_cc, ei_dc, ei_cd, degBase);
    scan_pass1<<<SCAN_NB, SCAN_BLK, 0, stream>>>(degBase, inclBase, bsumBase);
    scan_pass2<<<1, SCAN_BLK, 0, stream>>>(bsumBase, SCAN_NB);
    scan_pass3<<<SCAN_NB, SCAN_BLK, 0, stream>>>(inclBase, bsumBase, offsBase);
    fill3<<<(3 * En + 255) / 256, 256, 0, stream>>>(ei_cc, ei_dc, ei_cd,
                                                    offsBase, cursorBase, elistBase);
  }
  wprep<<<(139264 + 255) / 256, 256, 0, stream>>>(k1W, k2W, pW, W1c, W1d, W2c, W2d,
                                                  kW1t, kW2t, pWt,
                                                  W1cH, W1cL, W1dH, W1dL,
                                                  W2cH, W2cL, W2dH, W2dL);

  hipMemsetAsync(scoreB, 0, 8 * sizeof(float), stream);

  const int NT64 = (NCn + 63) / 64;
  const int* offs0 = offsBase;
  const int* offs1 = offsBase + 50000;
  const int* offs2 = offsBase + 100000;

  auto edge_layer = [&](void* hc, void* hd, void* oCC, void* oDC, void* oCD) {
    if (useCsr) {
      EdgeOp o0{offs0, elistBase, scc, dcc, (const __half*)hc, (__half*)oCC};
      EdgeOp o1{offs1, elistBase, sdc, ddc, (const __half*)hd, (__half*)oDC};
      EdgeOp o2{offs2, elistBase, scd, dcd, (const __half*)hc, (__half*)oCD};
      csr_att3<<<dim3((NCn + 3) / 4, 3), 256, 0, stream>>>(o0, o1, o2, NCn);
    } else {
      run_edge_fb(stream, ei_cc, scc, dcc, (const float*)hc, (float*)oCC, NCn, mbuf, sden, ebuf);
      run_edge_fb(stream, ei_dc, sdc, ddc, (const float*)hd, (float*)oDC, NCn, mbuf, sden, ebuf);
      run_edge_fb(stream, ei_cd, scd, dcd, (const float*)hc, (float*)oCD, NDn, mbuf, sden, ebuf);
    }
  };

  if (useCsr) {
    // ---------------- layer 1 ----------------
    gemm2_mfma<256, 0, 0, 0, 1><<<dim3(NT64, 2), 256, 0, stream>>>(
        xc, nullptr, nullptr, W1cH, W1cL, b1c, B0,
        xd, W1dH, W1dL, b1d, B1, NCn,
        a1s_cc, a1d_cc, a1d_dc, a1s_cd, a1s_dc, a1d_cd,
        scc, dcc, ddc, scd, sdc, dcd);
    edge_layer(B0, B1, B2, B3, B4);
    score_mfma<1><<<dim3(NT64, 2), 256, 0, stream>>>(B2, B3, kW1t, k1b, q1, NCn, scoreB);
    softmax2_kernel<<<1, 1, 0, stream>>>(scoreB);

    // ---------------- layer 2 ----------------
    gemm2_mfma<128, 2, 1, 1, 1><<<dim3(NT64, 2), 256, 0, stream>>>(
        B2, B3, scoreB, W2cH, W2cL, b2c, B0,
        B4, W2dH, W2dL, b2d, B1, NCn,
        a2s_cc, a2d_cc, a2d_dc, a2s_cd, a2s_dc, a2d_cd,
        scc, dcc, ddc, scd, sdc, dcd);
    edge_layer(B0, B1, B2, B3, B4);
    score_mfma<1><<<dim3(NT64, 2), 256, 0, stream>>>(B2, B3, kW2t, k2b, q2, NCn, scoreB + 4);
    softmax2_kernel<<<1, 1, 0, stream>>>(scoreB + 4);

    // ---------------- projection (merged) ----------------
    proj2_mfma<1><<<dim3(NT64, 2), 256, 0, stream>>>(B2, B3, scoreB + 4, B4, pWt, pb,
                                                     (float*)d_out,
                                                     (float*)d_out + (size_t)NCn * OUTn, NCn);
  } else {
    // ---------------- fp32 fallback ----------------
    gemm2_mfma<256, 0, 0, 0, 0><<<dim3(NT64, 2), 256, 0, stream>>>(
        xc, nullptr, nullptr, W1cH, W1cL, b1c, B0,
        xd, W1dH, W1dL, b1d, B1, NCn,
        a1s_cc, a1d_cc, a1d_dc, a1s_cd, a1s_dc, a1d_cd,
        scc, dcc, ddc, scd, sdc, dcd);
    edge_layer(B0, B1, B2, B3, B4);
    score_mfma<0><<<dim3(NT64, 2), 256, 0, stream>>>(B2, B3, kW1t, k1b, q1, NCn, scoreB);
    softmax2_kernel<<<1, 1, 0, stream>>>(scoreB);

    gemm2_mfma<128, 2, 1, 0, 0><<<dim3(NT64, 2), 256, 0, stream>>>(
        B2, B3, scoreB, W2cH, W2cL, b2c, B0,
        B4, W2dH, W2dL, b2d, B1, NCn,
        a2s_cc, a2d_cc, a2d_dc, a2s_cd, a2s_dc, a2d_cd,
        scc, dcc, ddc, scd, sdc, dcd);
    edge_layer(B0, B1, B2, B3, B4);
    score_mfma<0><<<dim3(NT64, 2), 256, 0, stream>>>(B2, B3, kW2t, k2b, q2, NCn, scoreB + 4);
    softmax2_kernel<<<1, 1, 0, stream>>>(scoreB + 4);

    proj2_mfma<0><<<dim3(NT64, 2), 256, 0, stream>>>(B2, B3, scoreB + 4, B4, pWt, pb,
                                                     (float*)d_out,
                                                     (float*)d_out + (size_t)NCn * OUTn, NCn);
  }
}